// Round 4
// baseline (7068.592 us; speedup 1.0000x reference)
//
#include <hip/hip_runtime.h>
#include <math.h>

// ---------------------------------------------------------------------------
// Associator forward. GEMMs: split-fp16 (hi+lo) MFMA, fp32 accumulate.
// Layouts: activations are [C][Ncols] row-major fp32.
//   trk cols: 16384 (track*16+t); GNN combined cols: 5120 = [tr: b*256+n | 1024 + det: b*1024+m]
// Sinkhorn: single persistent kernel, 64 blocks co-resident, global spin barrier.
// ---------------------------------------------------------------------------

#define NCT 16384
#define NCD 4096
#define NCB 5120
#define ZROW 257
#define ZCOL 1025
#define ZBAT (ZROW*ZCOL)   // 263425

#define NORM_C  (-7.1546153569f)   // -log(1280)
#define LOG_NS  (6.9314718056f)    // log(1024)
#define LOG_MS  (5.5451774445f)    // log(256)
#define LOG_TOT (7.1546153569f)    // +log(1280)

typedef _Float16 f16x8 __attribute__((ext_vector_type(8)));
typedef _Float16 f16x4 __attribute__((ext_vector_type(4)));
typedef float f32x4 __attribute__((ext_vector_type(4)));

#define APAD 40   // LDS row stride in halves (80 B: 16B-aligned rows)

// ---------------- GEMM: out = W @ [X0;X1] + bias (+res) (relu?) -----------
// W [O][C] fp32. X rows [0,C0) from X0, [C0,C) from X1 (both stride N).
// out stride No, res stride Nr. O%128==0, N%128==0, C%32==0, C0%32==0.
// Split-fp16: x = hi + lo; acc += Ah*Bh + Ah*Bl + Al*Bh  (fp32-grade inputs).
__global__ __launch_bounds__(256) void gemm_kernel(
    const float* __restrict__ W, const float* __restrict__ X0,
    const float* __restrict__ X1, const float* __restrict__ bias,
    const float* __restrict__ res, float* __restrict__ out,
    int O, int C, int C0, int N, int Nr, int No, int relu)
{
    __shared__ _Float16 Ah[128][APAD], Al[128][APAD];
    __shared__ _Float16 Bh[128][APAD], Bl[128][APAD];
    const int tid = threadIdx.x;
    const int n0 = blockIdx.x * 128, m0 = blockIdx.y * 128;
    const int wave = tid >> 6, lane = tid & 63;
    const int wo = (wave >> 1) * 64, wn = (wave & 1) * 64;
    const int lm = lane & 15, lq = lane >> 4;
    const int ar = tid >> 1, akh = (tid & 1) << 4;   // A stage: row, k-half
    const int bkg = tid & 7, bng = tid >> 3;         // B stage: k-grp, n-grp

    f32x4 acc[4][4] = {};

    for (int kb = 0; kb < C; kb += 32) {
        // ---- global loads (fp32) ----
        float4 av[4];
        const float* wp = W + (size_t)(m0 + ar) * C + kb + akh;
        #pragma unroll
        for (int q = 0; q < 4; ++q) av[q] = *(const float4*)(wp + 4 * q);
        float4 xv[4];
        #pragma unroll
        for (int r = 0; r < 4; ++r) {
            const int krow = kb + bkg * 4 + r;
            const float* xs = (krow < C0) ? X0 + (size_t)krow * N
                                          : X1 + (size_t)(krow - C0) * N;
            xv[r] = *(const float4*)(xs + n0 + bng * 4);
        }
        __syncthreads();   // prior iteration's fragment reads complete
        // ---- A: convert + store (row-major, k contiguous) ----
        {
            _Float16 hbuf[16], lbuf[16];
            #pragma unroll
            for (int q = 0; q < 4; ++q) {
                const float* f = (const float*)&av[q];
                #pragma unroll
                for (int c = 0; c < 4; ++c) {
                    const float x = f[c];
                    const _Float16 h = (_Float16)x;
                    hbuf[q * 4 + c] = h;
                    lbuf[q * 4 + c] = (_Float16)(x - (float)h);
                }
            }
            *(f16x8*)&Ah[ar][akh]     = *(const f16x8*)&hbuf[0];
            *(f16x8*)&Ah[ar][akh + 8] = *(const f16x8*)&hbuf[8];
            *(f16x8*)&Al[ar][akh]     = *(const f16x8*)&lbuf[0];
            *(f16x8*)&Al[ar][akh + 8] = *(const f16x8*)&lbuf[8];
        }
        // ---- B: convert + transposed store (Bs[n][k], k contiguous) ----
        #pragma unroll
        for (int j = 0; j < 4; ++j) {
            _Float16 hb[4], lb[4];
            #pragma unroll
            for (int r = 0; r < 4; ++r) {
                const float x = ((const float*)&xv[r])[j];
                const _Float16 h = (_Float16)x;
                hb[r] = h;
                lb[r] = (_Float16)(x - (float)h);
            }
            *(f16x4*)&Bh[bng * 4 + j][bkg * 4] = *(const f16x4*)&hb[0];
            *(f16x4*)&Bl[bng * 4 + j][bkg * 4] = *(const f16x4*)&lb[0];
        }
        __syncthreads();
        // ---- fragments + MFMA ----
        f16x8 bh[4], bl[4];
        #pragma unroll
        for (int t = 0; t < 4; ++t) {
            bh[t] = *(const f16x8*)&Bh[wn + t * 16 + lm][lq * 8];
            bl[t] = *(const f16x8*)&Bl[wn + t * 16 + lm][lq * 8];
        }
        #pragma unroll
        for (int mt = 0; mt < 4; ++mt) {
            const f16x8 ah = *(const f16x8*)&Ah[wo + mt * 16 + lm][lq * 8];
            const f16x8 al = *(const f16x8*)&Al[wo + mt * 16 + lm][lq * 8];
            #pragma unroll
            for (int nt = 0; nt < 4; ++nt) {
                acc[mt][nt] = __builtin_amdgcn_mfma_f32_16x16x32_f16(ah, bh[nt], acc[mt][nt], 0, 0, 0);
                acc[mt][nt] = __builtin_amdgcn_mfma_f32_16x16x32_f16(ah, bl[nt], acc[mt][nt], 0, 0, 0);
                acc[mt][nt] = __builtin_amdgcn_mfma_f32_16x16x32_f16(al, bh[nt], acc[mt][nt], 0, 0, 0);
            }
        }
    }
    // ---- epilogue: C/D layout col=lane&15, row=quad*4+reg ----
    #pragma unroll
    for (int mt = 0; mt < 4; ++mt) {
        #pragma unroll
        for (int rg = 0; rg < 4; ++rg) {
            const int o = m0 + wo + mt * 16 + lq * 4 + rg;
            const float bs = bias[o];
            #pragma unroll
            for (int nt = 0; nt < 4; ++nt) {
                const int n = n0 + wn + nt * 16 + lm;
                float v = acc[mt][nt][rg] + bs;
                if (res) v += res[(size_t)o * Nr + n];
                if (relu) v = fmaxf(v, 0.f);
                out[(size_t)o * No + n] = v;
            }
        }
    }
}

// ---------------- positional encoding ------------------------------------
__global__ void pe_kernel(const float* __restrict__ src, float* __restrict__ pe,
                          int N, int shift, int cstride)
{
    const int col = blockIdx.x * 256 + threadIdx.x;
    if (col >= N) return;
    const int seg = 1 << shift;
    const float pos = src[(size_t)(col >> shift) * cstride + (col & (seg - 1))];
    #pragma unroll 4
    for (int i = 0; i < 128; ++i) {
        const float div = expf((float)i * -0.07195578415606394f); // -ln(10000)/128
        const float ang = pos * div;
        pe[(size_t)(2*i) * N + col]   = sinf(ang);
        pe[(size_t)(2*i+1) * N + col] = cosf(ang);
    }
}

// ---------------- input repack (drop channel 0) ---------------------------
__global__ void repack_kernel(const float* __restrict__ src, float* __restrict__ dst,
                              int N, int shift, int cstride)
{
    const int col = blockIdx.x * 256 + threadIdx.x;
    const int c = blockIdx.y;
    if (col >= N) return;
    const int seg = 1 << shift;
    dst[(size_t)c * N + col] =
        src[(size_t)(col >> shift) * cstride + (size_t)(c + 1) * seg + (col & (seg - 1))];
}

// ---------------- fuser self-attention over time (n=m=16 per track) -------
__global__ __launch_bounds__(256) void fuser_attn_kernel(
    const float* __restrict__ Qb, const float* __restrict__ Kb,
    const float* __restrict__ Vb, float* __restrict__ Ob)
{
    __shared__ float qs[256][17], ks[256][17], vs[256][17];
    __shared__ float ps[4][16][17];
    const int trk = blockIdx.x, tid = threadIdx.x;
    const int col0 = trk * 16;
    for (int idx = tid; idx < 1024; idx += 256) {
        const int r = idx >> 2, seg = (idx & 3) << 2;
        const float4 q = *(const float4*)&Qb[(size_t)r * NCT + col0 + seg];
        const float4 k = *(const float4*)&Kb[(size_t)r * NCT + col0 + seg];
        const float4 v = *(const float4*)&Vb[(size_t)r * NCT + col0 + seg];
        qs[r][seg]=q.x; qs[r][seg+1]=q.y; qs[r][seg+2]=q.z; qs[r][seg+3]=q.w;
        ks[r][seg]=k.x; ks[r][seg+1]=k.y; ks[r][seg+2]=k.z; ks[r][seg+3]=k.w;
        vs[r][seg]=v.x; vs[r][seg+1]=v.y; vs[r][seg+2]=v.z; vs[r][seg+3]=v.w;
    }
    __syncthreads();
    {   // scores: thread group g=tid>>2 -> (h,n); 4 threads cover m in 4s
        const int g = tid >> 2, h = g >> 4, n = g & 15, mb = (tid & 3) << 2;
        float s[4] = {};
        #pragma unroll 4
        for (int hd = 0; hd < 64; ++hd) {
            const int c = hd*4 + h;
            const float q = qs[c][n];
            #pragma unroll
            for (int j = 0; j < 4; ++j) s[j] = fmaf(q, ks[c][mb + j], s[j]);
        }
        #pragma unroll
        for (int j = 0; j < 4; ++j) ps[h][n][mb + j] = s[j] * 0.125f;
    }
    __syncthreads();
    if (tid < 64) {
        const int hh = tid >> 4, nn = tid & 15;
        float mx = -INFINITY;
        for (int m = 0; m < 16; ++m) mx = fmaxf(mx, ps[hh][nn][m]);
        float sum = 0.f;
        for (int m = 0; m < 16; ++m) { const float p = expf(ps[hh][nn][m] - mx);
                                       ps[hh][nn][m] = p; sum += p; }
        const float inv = 1.f / sum;
        for (int m = 0; m < 16; ++m) ps[hh][nn][m] *= inv;
    }
    __syncthreads();
    {   // message: thread = channel c
        const int c = tid, hc = c & 3;
        float msg[16];
        #pragma unroll
        for (int n = 0; n < 16; ++n) {
            float a = 0.f;
            #pragma unroll
            for (int m = 0; m < 16; ++m) a = fmaf(ps[hc][n][m], vs[c][m], a);
            msg[n] = a;
        }
        __syncthreads();      // everyone done reading qs from scores phase
        #pragma unroll
        for (int n = 0; n < 16; ++n) qs[c][n] = msg[n];
    }
    __syncthreads();
    for (int idx = tid; idx < 1024; idx += 256) {
        const int r = idx >> 2, seg = (idx & 3) << 2;
        *(float4*)&Ob[(size_t)r * NCT + col0 + seg] =
            make_float4(qs[r][seg], qs[r][seg+1], qs[r][seg+2], qs[r][seg+3]);
    }
}

// ---------------- GNN attention, flash-style online softmax ---------------
// grid: (nq/64, H=4, B=4). Channels are hd*4+h. S tile overlaid on K LDS.
__global__ __launch_bounds__(256) void attn_kernel(
    const float* __restrict__ Qb, const float* __restrict__ Kb,
    const float* __restrict__ Vb, float* __restrict__ Ob,
    int nq, int nk, int NQ, int NK)
{
    __shared__ float Qs[64][65];
    __shared__ float KsS[64][65];   // K tile, later overwritten by S/P
    __shared__ float Vs[64][65];
    __shared__ float rmax[64], rsum[64], ralpha[64];
    const int b = blockIdx.z, h = blockIdx.y, nt = blockIdx.x;
    const int tid = threadIdx.x;
    const int qcol = b * nq + nt * 64;
    for (int idx = tid; idx < 1024; idx += 256) {
        const int hd = idx >> 4, seg = (idx & 15) << 2;
        const float4 q = *(const float4*)&Qb[(size_t)(hd*4 + h) * NQ + qcol + seg];
        Qs[hd][seg]=q.x; Qs[hd][seg+1]=q.y; Qs[hd][seg+2]=q.z; Qs[hd][seg+3]=q.w;
    }
    if (tid < 64) { rmax[tid] = -INFINITY; rsum[tid] = 0.f; }
    float acc[4][4] = {};               // [hd][n]
    const int thd = (tid & 15) * 4, tn = (tid >> 4) * 4;
    const int mtiles = nk >> 6;
    for (int mt = 0; mt < mtiles; ++mt) {
        const int kcol = b * nk + mt * 64;
        __syncthreads();                // prior readers of KsS/Vs done
        for (int idx = tid; idx < 1024; idx += 256) {
            const int hd = idx >> 4, seg = (idx & 15) << 2;
            const float4 k4 = *(const float4*)&Kb[(size_t)(hd*4 + h) * NK + kcol + seg];
            KsS[hd][seg]=k4.x; KsS[hd][seg+1]=k4.y; KsS[hd][seg+2]=k4.z; KsS[hd][seg+3]=k4.w;
            const float4 v4 = *(const float4*)&Vb[(size_t)(hd*4 + h) * NK + kcol + seg];
            Vs[hd][seg]=v4.x; Vs[hd][seg+1]=v4.y; Vs[hd][seg+2]=v4.z; Vs[hd][seg+3]=v4.w;
        }
        __syncthreads();
        float s[4][4] = {};
        const int tsm = (tid & 15) * 4, tsn = (tid >> 4) * 4;
        #pragma unroll 4
        for (int hd = 0; hd < 64; ++hd) {
            float qv[4], kv[4];
            #pragma unroll
            for (int i = 0; i < 4; ++i) { qv[i] = Qs[hd][tsn + i]; kv[i] = KsS[hd][tsm + i]; }
            #pragma unroll
            for (int i = 0; i < 4; ++i)
                #pragma unroll
                for (int j = 0; j < 4; ++j) s[i][j] = fmaf(qv[i], kv[j], s[i][j]);
        }
        __syncthreads();                // all threads done reading K
        #pragma unroll
        for (int i = 0; i < 4; ++i)
            #pragma unroll
            for (int j = 0; j < 4; ++j) KsS[tsn + i][tsm + j] = s[i][j] * 0.125f;
        __syncthreads();
        if (tid < 64) {                 // per-row online softmax update
            const float mo = rmax[tid];
            float mx = mo;
            for (int m = 0; m < 64; ++m) mx = fmaxf(mx, KsS[tid][m]);
            const float al = expf(mo - mx);       // first tile: exp(-inf)=0
            float sum = 0.f;
            for (int m = 0; m < 64; ++m) { const float p = expf(KsS[tid][m] - mx);
                                           KsS[tid][m] = p; sum += p; }
            rsum[tid] = rsum[tid] * al + sum;
            rmax[tid] = mx; ralpha[tid] = al;
        }
        __syncthreads();
        float alj[4];
        #pragma unroll
        for (int j = 0; j < 4; ++j) alj[j] = ralpha[tn + j];
        #pragma unroll
        for (int i = 0; i < 4; ++i)
            #pragma unroll
            for (int j = 0; j < 4; ++j) acc[i][j] *= alj[j];
        for (int m = 0; m < 64; ++m) {
            float vv[4], pp[4];
            #pragma unroll
            for (int i = 0; i < 4; ++i) vv[i] = Vs[thd + i][m];
            #pragma unroll
            for (int j = 0; j < 4; ++j) pp[j] = KsS[tn + j][m];
            #pragma unroll
            for (int i = 0; i < 4; ++i)
                #pragma unroll
                for (int j = 0; j < 4; ++j) acc[i][j] = fmaf(vv[i], pp[j], acc[i][j]);
        }
    }
    __syncthreads();
    float rs[4];
    #pragma unroll
    for (int j = 0; j < 4; ++j) rs[j] = 1.f / rsum[tn + j];
    #pragma unroll
    for (int i = 0; i < 4; ++i)
        #pragma unroll
        for (int j = 0; j < 4; ++j)
            Ob[(size_t)((thd + i) * 4 + h) * NQ + qcol + tn + j] = acc[i][j] * rs[j];
}

// ---------------- mean pool over time (into combined cols [0,1024)) -------
__global__ void meanpool_kernel(const float* __restrict__ x, float* __restrict__ tr)
{
    const int trk = blockIdx.x * 256 + threadIdx.x;
    const int d = blockIdx.y;
    const float* p = x + (size_t)d * NCT + (size_t)trk * 16;
    float s = 0.f;
    #pragma unroll
    for (int t = 0; t < 16; ++t) s += p[t];
    tr[(size_t)d * NCB + trk] = s * 0.0625f;
}

// ---------------- scores = m0^T m1 / 16 into Z0 and Z0T -------------------
__global__ __launch_bounds__(256) void scores_kernel(
    const float* __restrict__ M, float* __restrict__ Z0, float* __restrict__ Z0T)
{
    __shared__ float As[8][68];
    __shared__ float Bs[8][68];
    const int bm = blockIdx.x, bn = blockIdx.y, b = blockIdx.z;
    const int tid = threadIdx.x;
    const int n0 = bn * 64, mm0 = bm * 64;
    const int tx = tid & 15, ty = tid >> 4;
    float acc[4][4] = {};
    for (int kb = 0; kb < 256; kb += 8) {
        __syncthreads();
        for (int idx = tid; idx < 512; idx += 256) {
            const int r = idx >> 6, cc = idx & 63;
            As[r][cc] = M[(size_t)(kb + r) * NCB + b * 256 + n0 + cc];
            Bs[r][cc] = M[(size_t)(kb + r) * NCB + 1024 + b * 1024 + mm0 + cc];
        }
        __syncthreads();
        #pragma unroll
        for (int kk = 0; kk < 8; ++kk) {
            float a[4], bv[4];
            #pragma unroll
            for (int i = 0; i < 4; ++i) { a[i] = As[kk][ty*4 + i]; bv[i] = Bs[kk][tx*4 + i]; }
            #pragma unroll
            for (int i = 0; i < 4; ++i)
                #pragma unroll
                for (int j = 0; j < 4; ++j) acc[i][j] = fmaf(a[i], bv[j], acc[i][j]);
        }
    }
    #pragma unroll
    for (int i = 0; i < 4; ++i)
        #pragma unroll
        for (int j = 0; j < 4; ++j) {
            const float s = acc[i][j] * 0.0625f;
            const int rr = n0 + ty*4 + i, cc = mm0 + tx*4 + j;
            Z0 [(size_t)b * ZBAT + (size_t)rr * ZCOL + cc] = s;
            Z0T[(size_t)b * ZBAT + (size_t)cc * ZROW + rr] = s;
        }
}

// ---------------- sinkhorn: init bins + barrier + v ------------------------
__global__ void sink_init_kernel(float* __restrict__ Z0, float* __restrict__ Z0T,
                                 float* __restrict__ v, int* __restrict__ bar,
                                 const float* __restrict__ binp)
{
    const float alpha = binp[0];
    const int idx = blockIdx.x * 256 + threadIdx.x;
    if (idx < 2) bar[idx] = 0;
    if (idx < 4 * ZCOL) v[idx] = 0.f;
    if (idx < 4 * 1281) {
        const int b = idx / 1281, e = idx % 1281;
        if (e < 1025) Z0[(size_t)b * ZBAT + 256 * ZCOL + e] = alpha;
        else          Z0[(size_t)b * ZBAT + (size_t)(e - 1025) * ZCOL + 1024] = alpha;
    }
    if (idx < 4 * 1282) {
        const int b = idx / 1282, e = idx % 1282;
        if (e < 257) Z0T[(size_t)b * ZBAT + 1024 * ZROW + e] = alpha;       // row j=1024
        else         Z0T[(size_t)b * ZBAT + (size_t)(e - 257) * ZROW + 256] = alpha; // col i=256
    }
}

// ---------------- persistent fused sinkhorn --------------------------------
#define SNB 64   // blocks; 64 x 1024 thr -> guaranteed co-resident on 256 CUs

__device__ __forceinline__ void grid_barrier(int* __restrict__ bar)
{
    __syncthreads();
    if (threadIdx.x == 0) {
        __threadfence();
        const int g = __hip_atomic_load(&bar[1], __ATOMIC_RELAXED, __HIP_MEMORY_SCOPE_AGENT);
        if (atomicAdd(&bar[0], 1) == SNB - 1) {
            __hip_atomic_store(&bar[0], 0, __ATOMIC_RELAXED, __HIP_MEMORY_SCOPE_AGENT);
            __hip_atomic_store(&bar[1], g + 1, __ATOMIC_RELEASE, __HIP_MEMORY_SCOPE_AGENT);
        } else {
            while (__hip_atomic_load(&bar[1], __ATOMIC_ACQUIRE, __HIP_MEMORY_SCOPE_AGENT) == g)
                __builtin_amdgcn_s_sleep(2);
        }
        __threadfence();
    }
    __syncthreads();
}

__global__ __launch_bounds__(1024) void sink_fused(
    const float* __restrict__ Z0, const float* __restrict__ Z0T,
    float* __restrict__ u, float* __restrict__ v,
    float* __restrict__ out, int* __restrict__ bar)
{
    const int lane = threadIdx.x & 63;
    const int wave = (blockIdx.x << 4) + (threadIdx.x >> 6);   // 0..1023

    for (int it = 0; it < 100; ++it) {
        // ---- u-phase: rows of Z0 (1028 = 4 x 257) ----
        for (int row = wave; row < 1028; row += 1024) {
            const int b = row / 257, i = row - b * 257;
            const float* z  = Z0 + (size_t)b * ZBAT + (size_t)i * ZCOL;
            const float* vb = v + b * ZCOL;
            float zz[17];
            float mx = -INFINITY;
            #pragma unroll
            for (int k = 0; k < 16; ++k) {
                zz[k] = z[lane + k*64] + vb[lane + k*64];
                mx = fmaxf(mx, zz[k]);
            }
            zz[16] = (lane == 0) ? (z[1024] + vb[1024]) : -INFINITY;
            mx = fmaxf(mx, zz[16]);
            #pragma unroll
            for (int off = 32; off; off >>= 1) mx = fmaxf(mx, __shfl_xor(mx, off));
            float s = 0.f;
            #pragma unroll
            for (int k = 0; k < 17; ++k) s += expf(zz[k] - mx);
            #pragma unroll
            for (int off = 32; off; off >>= 1) s += __shfl_xor(s, off);
            if (lane == 0) {
                const float lmu = (i < 256) ? NORM_C : (LOG_NS + NORM_C);
                u[b * 257 + i] = lmu - (mx + logf(s));
            }
        }
        grid_barrier(bar);
        // ---- v-phase: rows of Z0T (4100 = 4 x 1025) ----
        for (int row = wave; row < 4100; row += 1024) {
            const int b = row / 1025, j = row - b * 1025;
            const float* z  = Z0T + (size_t)b * ZBAT + (size_t)j * ZROW;
            const float* ub = u + b * 257;
            float zz[5];
            float mx = -INFINITY;
            #pragma unroll
            for (int k = 0; k < 4; ++k) {
                zz[k] = z[lane + k*64] + ub[lane + k*64];
                mx = fmaxf(mx, zz[k]);
            }
            zz[4] = (lane == 0) ? (z[256] + ub[256]) : -INFINITY;
            mx = fmaxf(mx, zz[4]);
            #pragma unroll
            for (int off = 32; off; off >>= 1) mx = fmaxf(mx, __shfl_xor(mx, off));
            float s = 0.f;
            #pragma unroll
            for (int k = 0; k < 5; ++k) s += expf(zz[k] - mx);
            #pragma unroll
            for (int off = 32; off; off >>= 1) s += __shfl_xor(s, off);
            if (lane == 0) {
                const float lnu = (j < 1024) ? NORM_C : (LOG_MS + NORM_C);
                v[b * ZCOL + j] = lnu - (mx + logf(s));
            }
        }
        grid_barrier(bar);
    }
    // ---- output: out = Z0 + u + v + log(m+n) ----
    const int gtid = blockIdx.x * 1024 + threadIdx.x;
    for (int idx = gtid; idx < 4 * ZBAT; idx += SNB * 1024) {
        const int b = idx / ZBAT, r = idx - b * ZBAT;
        const int i = r / ZCOL, j = r - i * ZCOL;
        out[idx] = Z0[idx] + u[b * 257 + i] + v[b * ZCOL + j] + LOG_TOT;
    }
}

// ---------------------------------------------------------------------------
static inline void gemm(hipStream_t st, const float* W, const float* X0,
                        const float* X1, int C0, const float* bias,
                        const float* res, int Nr, float* out, int No,
                        int O, int C, int N, int relu)
{
    dim3 g(N / 128, O / 128);
    gemm_kernel<<<g, 256, 0, st>>>(W, X0, X1, bias, res, out, O, C, C0, N, Nr, No, relu);
}

extern "C" void kernel_launch(void* const* d_in, const int* in_sizes, int n_in,
                              void* d_out, int out_size, void* d_ws, size_t ws_size,
                              hipStream_t stream)
{
    (void)in_sizes; (void)n_in; (void)out_size; (void)ws_size;
    const float* det_in = (const float*)d_in[0];
    const float* trk_in = (const float*)d_in[1];
    const float* enc_w1 = (const float*)d_in[2];
    const float* enc_b1 = (const float*)d_in[3];
    const float* enc_w2 = (const float*)d_in[4];
    const float* enc_b2 = (const float*)d_in[5];
    const float* fus_pw = (const float*)d_in[6];
    const float* fus_pb = (const float*)d_in[7];
    const float* fus_mw = (const float*)d_in[8];
    const float* fus_mb = (const float*)d_in[9];
    const float* fus_m1w = (const float*)d_in[10];
    const float* fus_m1b = (const float*)d_in[11];
    const float* fus_m2w = (const float*)d_in[12];
    const float* fus_m2b = (const float*)d_in[13];
    const float* gnn_pw = (const float*)d_in[14];
    const float* gnn_pb = (const float*)d_in[15];
    const float* gnn_mw = (const float*)d_in[16];
    const float* gnn_mb = (const float*)d_in[17];
    const float* gnn_m1w = (const float*)d_in[18];
    const float* gnn_m1b = (const float*)d_in[19];
    const float* gnn_m2w = (const float*)d_in[20];
    const float* gnn_m2b = (const float*)d_in[21];
    const float* final_w = (const float*)d_in[22];
    const float* final_b = (const float*)d_in[23];
    const float* bin_sc  = (const float*)d_in[24];
    float* out = (float*)d_out;

    float* ws = (float*)d_ws;
    float* XF   = ws;                      // 4,194,304  fuser state x [256][16384]
    float* R    = ws + 4194304;            // 16,777,216 temp arena
    float* COMB = ws + 20971520;           // 1,310,720  [256][5120] tr|det state
    float* Z0   = ws + 22282240;           // 1,053,700
    float* U    = ws + 23335940;           //     1,028
    float* V    = ws + 23336968;           //     4,100
    // arena aliases (fuser / det-enc): Q,K,V contiguous so qkv is one O=768 GEMM
    float* Qf = R;
    float* Kf = R + 4194304;
    float* Vf = R + 8388608;
    float* MS = R + 12582912;
    // arena aliases (GNN, combined N=5120):
    float* QKV = R;                       // [768][5120] = 3,932,160
    float* H   = R + 1310720;             // [512][5120] overlays K,V rows
    float* MSG = R + 3932160;             // [256][5120]
    float* M   = R + 5242880;             // [256][5120]
    const float* Qt = QKV;
    const float* Kt = QKV + (size_t)256 * NCB;
    const float* Vt = QKV + (size_t)512 * NCB;
    const float* Qd = Qt + 1024;
    const float* Kd = Kt + 1024;
    const float* Vd = Vt + 1024;
    // arena aliases (sinkhorn; R free except M during scores):
    float* Z0T = R;                       // 1,053,700  [4][1025][257]
    int*   BAR = (int*)(R + 2000000);     // barrier state (cnt, gen)

    // ================= encoder (tracks) + fuser ===========================
    pe_kernel<<<NCT/256, 256, 0, stream>>>(trk_in, MS, NCT, 4, 257*16);
    repack_kernel<<<dim3(NCT/256, 256), 256, 0, stream>>>(trk_in, Qf, NCT, 4, 257*16);
    gemm(stream, enc_w1, Qf, Qf, 256, enc_b1, nullptr, 0, Kf, NCT, 256, 256, NCT, 1);
    gemm(stream, enc_w2, Kf, Kf, 256, enc_b2, MS, NCT, XF, NCT, 256, 256, NCT, 0);

    for (int l = 0; l < 4; ++l) {
        gemm(stream, fus_pw + l*196608, XF, XF, 256, fus_pb + l*768,
             nullptr, 0, Qf, NCT, 768, 256, NCT, 0);
        fuser_attn_kernel<<<1024, 256, 0, stream>>>(Qf, Kf, Vf, MS);
        gemm(stream, fus_mw + l*65536, MS, MS, 256, fus_mb + l*256,
             nullptr, 0, Qf, NCT, 256, 256, NCT, 0);               // M -> Qf
        gemm(stream, fus_m1w + l*262144, XF, Qf, 256, fus_m1b + l*512,
             nullptr, 0, Kf, NCT, 512, 512, NCT, 1);               // H -> Kf..Vf
        gemm(stream, fus_m2w + l*131072, Kf, Kf, 512, fus_m2b + l*256,
             XF, NCT, XF, NCT, 256, 512, NCT, 0);                  // x += ...
    }
    meanpool_kernel<<<dim3(4, 256), 256, 0, stream>>>(XF, COMB);   // tr cols [0,1024)

    // ================= encoder (detections) -> COMB cols [1024,5120) ======
    pe_kernel<<<NCD/256, 256, 0, stream>>>(det_in, MS, NCD, 10, 257*1024);
    repack_kernel<<<dim3(NCD/256, 256), 256, 0, stream>>>(det_in, Qf, NCD, 10, 257*1024);
    gemm(stream, enc_w1, Qf, Qf, 256, enc_b1, nullptr, 0, Kf, NCD, 256, 256, NCD, 1);
    gemm(stream, enc_w2, Kf, Kf, 256, enc_b2, MS, NCD, COMB + 1024, NCB, 256, 256, NCD, 0);

    // ================= GNN (combined tr|det, N=5120) ======================
    for (int l = 0; l < 12; ++l) {
        const float* pw  = gnn_pw + l*196608;
        const float* pb  = gnn_pb + l*768;
        const float* mw  = gnn_mw + l*65536;
        const float* mb  = gnn_mb + l*256;
        const float* m1w = gnn_m1w + l*262144;
        const float* m1b = gnn_m1b + l*512;
        const float* m2w = gnn_m2w + l*131072;
        const float* m2b = gnn_m2b + l*256;
        const bool cross = (l & 1);

        gemm(stream, pw, COMB, COMB, 256, pb, nullptr, 0, QKV, NCB, 768, 256, NCB, 0);

        attn_kernel<<<dim3(4, 4, 4), 256, 0, stream>>>(
            Qt, cross ? Kd : Kt, cross ? Vd : Vt, MSG,
            256, cross ? 1024 : 256, NCB, NCB);
        attn_kernel<<<dim3(16, 4, 4), 256, 0, stream>>>(
            Qd, cross ? Kt : Kd, cross ? Vt : Vd, MSG + 1024,
            1024, cross ? 256 : 1024, NCB, NCB);

        gemm(stream, mw, MSG, MSG, 256, mb, nullptr, 0, M, NCB, 256, 256, NCB, 0);
        gemm(stream, m1w, COMB, M, 256, m1b, nullptr, 0, H, NCB, 512, 512, NCB, 1);
        gemm(stream, m2w, H, H, 512, m2b, COMB, NCB, COMB, NCB, 256, 512, NCB, 0);
    }

    // ================= final projection + scores + sinkhorn ===============
    gemm(stream, final_w, COMB, COMB, 256, final_b, nullptr, 0, M, NCB, 256, 256, NCB, 0);
    scores_kernel<<<dim3(16, 4, 4), 256, 0, stream>>>(M, Z0, Z0T);
    sink_init_kernel<<<21, 256, 0, stream>>>(Z0, Z0T, V, BAR, bin_sc);
    sink_fused<<<SNB, 1024, 0, stream>>>(Z0, Z0T, U, V, out, BAR);
}

// Round 5
// 5239.334 us; speedup vs baseline: 1.3491x; 1.3491x over previous
//
#include <hip/hip_runtime.h>
#include <math.h>

// ---------------------------------------------------------------------------
// Associator forward. GEMMs: split-fp16 (hi+lo) MFMA, fp32 accumulate.
// Layouts: activations are [C][Ncols] row-major fp32.
//   trk cols: 16384 (track*16+t); GNN combined cols: 5120 = [tr: b*256+n | 1024 + det: b*1024+m]
// Sinkhorn: 200 graph-replayed micro-launches (measured cheaper than device-
// scope grid barriers on gfx950: barrier ~7µs vs launch gap ~2-3µs), with
// Z0T materialized so both LSE phases are coalesced wave-per-row.
// GEMM tiles: 128x128 for N=16384 (fuser), 64x128 for GNN/det (occupancy).
// ---------------------------------------------------------------------------

#define NCT 16384
#define NCD 4096
#define NCB 5120
#define ZROW 257
#define ZCOL 1025
#define ZBAT (ZROW*ZCOL)   // 263425

#define NORM_C  (-7.1546153569f)   // -log(1280)
#define LOG_NS  (6.9314718056f)    // log(1024)
#define LOG_MS  (5.5451774445f)    // log(256)
#define LOG_TOT (7.1546153569f)    // +log(1280)

typedef _Float16 f16x8 __attribute__((ext_vector_type(8)));
typedef _Float16 f16x4 __attribute__((ext_vector_type(4)));
typedef float f32x4 __attribute__((ext_vector_type(4)));

#define APAD 40   // LDS row stride in halves (80 B: 16B-aligned rows)

// ---------------- GEMM 128x128: out = W @ [X0;X1] + bias (+res) (relu?) ---
// W [O][C] fp32. X rows [0,C0) from X0, [C0,C) from X1 (both stride N).
// out stride No, res stride Nr. O%128==0, N%128==0, C%32==0, C0%32==0.
// Split-fp16: x = hi + lo; acc += Ah*Bh + Ah*Bl + Al*Bh  (fp32-grade inputs).
__global__ __launch_bounds__(256) void gemm_kernel(
    const float* __restrict__ W, const float* __restrict__ X0,
    const float* __restrict__ X1, const float* __restrict__ bias,
    const float* __restrict__ res, float* __restrict__ out,
    int O, int C, int C0, int N, int Nr, int No, int relu)
{
    __shared__ _Float16 Ah[128][APAD], Al[128][APAD];
    __shared__ _Float16 Bh[128][APAD], Bl[128][APAD];
    const int tid = threadIdx.x;
    const int n0 = blockIdx.x * 128, m0 = blockIdx.y * 128;
    const int wave = tid >> 6, lane = tid & 63;
    const int wo = (wave >> 1) * 64, wn = (wave & 1) * 64;
    const int lm = lane & 15, lq = lane >> 4;
    const int ar = tid >> 1, akh = (tid & 1) << 4;   // A stage: row, k-half
    const int bkg = tid & 7, bng = tid >> 3;         // B stage: k-grp, n-grp

    f32x4 acc[4][4] = {};

    for (int kb = 0; kb < C; kb += 32) {
        float4 av[4];
        const float* wp = W + (size_t)(m0 + ar) * C + kb + akh;
        #pragma unroll
        for (int q = 0; q < 4; ++q) av[q] = *(const float4*)(wp + 4 * q);
        float4 xv[4];
        #pragma unroll
        for (int r = 0; r < 4; ++r) {
            const int krow = kb + bkg * 4 + r;
            const float* xs = (krow < C0) ? X0 + (size_t)krow * N
                                          : X1 + (size_t)(krow - C0) * N;
            xv[r] = *(const float4*)(xs + n0 + bng * 4);
        }
        __syncthreads();
        {
            _Float16 hbuf[16], lbuf[16];
            #pragma unroll
            for (int q = 0; q < 4; ++q) {
                const float* f = (const float*)&av[q];
                #pragma unroll
                for (int c = 0; c < 4; ++c) {
                    const float x = f[c];
                    const _Float16 h = (_Float16)x;
                    hbuf[q * 4 + c] = h;
                    lbuf[q * 4 + c] = (_Float16)(x - (float)h);
                }
            }
            *(f16x8*)&Ah[ar][akh]     = *(const f16x8*)&hbuf[0];
            *(f16x8*)&Ah[ar][akh + 8] = *(const f16x8*)&hbuf[8];
            *(f16x8*)&Al[ar][akh]     = *(const f16x8*)&lbuf[0];
            *(f16x8*)&Al[ar][akh + 8] = *(const f16x8*)&lbuf[8];
        }
        #pragma unroll
        for (int j = 0; j < 4; ++j) {
            _Float16 hb[4], lb[4];
            #pragma unroll
            for (int r = 0; r < 4; ++r) {
                const float x = ((const float*)&xv[r])[j];
                const _Float16 h = (_Float16)x;
                hb[r] = h;
                lb[r] = (_Float16)(x - (float)h);
            }
            *(f16x4*)&Bh[bng * 4 + j][bkg * 4] = *(const f16x4*)&hb[0];
            *(f16x4*)&Bl[bng * 4 + j][bkg * 4] = *(const f16x4*)&lb[0];
        }
        __syncthreads();
        f16x8 bh[4], bl[4];
        #pragma unroll
        for (int t = 0; t < 4; ++t) {
            bh[t] = *(const f16x8*)&Bh[wn + t * 16 + lm][lq * 8];
            bl[t] = *(const f16x8*)&Bl[wn + t * 16 + lm][lq * 8];
        }
        #pragma unroll
        for (int mt = 0; mt < 4; ++mt) {
            const f16x8 ah = *(const f16x8*)&Ah[wo + mt * 16 + lm][lq * 8];
            const f16x8 al = *(const f16x8*)&Al[wo + mt * 16 + lm][lq * 8];
            #pragma unroll
            for (int nt = 0; nt < 4; ++nt) {
                acc[mt][nt] = __builtin_amdgcn_mfma_f32_16x16x32_f16(ah, bh[nt], acc[mt][nt], 0, 0, 0);
                acc[mt][nt] = __builtin_amdgcn_mfma_f32_16x16x32_f16(ah, bl[nt], acc[mt][nt], 0, 0, 0);
                acc[mt][nt] = __builtin_amdgcn_mfma_f32_16x16x32_f16(al, bh[nt], acc[mt][nt], 0, 0, 0);
            }
        }
    }
    #pragma unroll
    for (int mt = 0; mt < 4; ++mt) {
        #pragma unroll
        for (int rg = 0; rg < 4; ++rg) {
            const int o = m0 + wo + mt * 16 + lq * 4 + rg;
            const float bs = bias[o];
            #pragma unroll
            for (int nt = 0; nt < 4; ++nt) {
                const int n = n0 + wn + nt * 16 + lm;
                float v = acc[mt][nt][rg] + bs;
                if (res) v += res[(size_t)o * Nr + n];
                if (relu) v = fmaxf(v, 0.f);
                out[(size_t)o * No + n] = v;
            }
        }
    }
}

// ---------------- GEMM 64x128 tile (for small grids: GNN/det/final) -------
// Same contract; O%64==0. Doubles block count vs 128x128 for occupancy.
__global__ __launch_bounds__(256) void gemm64_kernel(
    const float* __restrict__ W, const float* __restrict__ X0,
    const float* __restrict__ X1, const float* __restrict__ bias,
    const float* __restrict__ res, float* __restrict__ out,
    int O, int C, int C0, int N, int Nr, int No, int relu)
{
    __shared__ _Float16 Ah[64][APAD], Al[64][APAD];
    __shared__ _Float16 Bh[128][APAD], Bl[128][APAD];
    const int tid = threadIdx.x;
    const int n0 = blockIdx.x * 128, m0 = blockIdx.y * 64;
    const int wave = tid >> 6, lane = tid & 63;
    const int wo = (wave >> 1) * 32, wn = (wave & 1) * 64;
    const int lm = lane & 15, lq = lane >> 4;
    const int ar = tid >> 2, ak8 = (tid & 3) << 3;   // A stage: row, k-oct
    const int bkg = tid & 7, bng = tid >> 3;         // B stage: k-grp, n-grp

    f32x4 acc[2][4] = {};

    for (int kb = 0; kb < C; kb += 32) {
        float4 av[2];
        const float* wp = W + (size_t)(m0 + ar) * C + kb + ak8;
        av[0] = *(const float4*)(wp);
        av[1] = *(const float4*)(wp + 4);
        float4 xv[4];
        #pragma unroll
        for (int r = 0; r < 4; ++r) {
            const int krow = kb + bkg * 4 + r;
            const float* xs = (krow < C0) ? X0 + (size_t)krow * N
                                          : X1 + (size_t)(krow - C0) * N;
            xv[r] = *(const float4*)(xs + n0 + bng * 4);
        }
        __syncthreads();
        {
            _Float16 hbuf[8], lbuf[8];
            #pragma unroll
            for (int q = 0; q < 2; ++q) {
                const float* f = (const float*)&av[q];
                #pragma unroll
                for (int c = 0; c < 4; ++c) {
                    const float x = f[c];
                    const _Float16 h = (_Float16)x;
                    hbuf[q * 4 + c] = h;
                    lbuf[q * 4 + c] = (_Float16)(x - (float)h);
                }
            }
            *(f16x8*)&Ah[ar][ak8] = *(const f16x8*)&hbuf[0];
            *(f16x8*)&Al[ar][ak8] = *(const f16x8*)&lbuf[0];
        }
        #pragma unroll
        for (int j = 0; j < 4; ++j) {
            _Float16 hb[4], lb[4];
            #pragma unroll
            for (int r = 0; r < 4; ++r) {
                const float x = ((const float*)&xv[r])[j];
                const _Float16 h = (_Float16)x;
                hb[r] = h;
                lb[r] = (_Float16)(x - (float)h);
            }
            *(f16x4*)&Bh[bng * 4 + j][bkg * 4] = *(const f16x4*)&hb[0];
            *(f16x4*)&Bl[bng * 4 + j][bkg * 4] = *(const f16x4*)&lb[0];
        }
        __syncthreads();
        f16x8 bh[4], bl[4];
        #pragma unroll
        for (int t = 0; t < 4; ++t) {
            bh[t] = *(const f16x8*)&Bh[wn + t * 16 + lm][lq * 8];
            bl[t] = *(const f16x8*)&Bl[wn + t * 16 + lm][lq * 8];
        }
        #pragma unroll
        for (int mt = 0; mt < 2; ++mt) {
            const f16x8 ah = *(const f16x8*)&Ah[wo + mt * 16 + lm][lq * 8];
            const f16x8 al = *(const f16x8*)&Al[wo + mt * 16 + lm][lq * 8];
            #pragma unroll
            for (int nt = 0; nt < 4; ++nt) {
                acc[mt][nt] = __builtin_amdgcn_mfma_f32_16x16x32_f16(ah, bh[nt], acc[mt][nt], 0, 0, 0);
                acc[mt][nt] = __builtin_amdgcn_mfma_f32_16x16x32_f16(ah, bl[nt], acc[mt][nt], 0, 0, 0);
                acc[mt][nt] = __builtin_amdgcn_mfma_f32_16x16x32_f16(al, bh[nt], acc[mt][nt], 0, 0, 0);
            }
        }
    }
    #pragma unroll
    for (int mt = 0; mt < 2; ++mt) {
        #pragma unroll
        for (int rg = 0; rg < 4; ++rg) {
            const int o = m0 + wo + mt * 16 + lq * 4 + rg;
            const float bs = bias[o];
            #pragma unroll
            for (int nt = 0; nt < 4; ++nt) {
                const int n = n0 + wn + nt * 16 + lm;
                float v = acc[mt][nt][rg] + bs;
                if (res) v += res[(size_t)o * Nr + n];
                if (relu) v = fmaxf(v, 0.f);
                out[(size_t)o * No + n] = v;
            }
        }
    }
}

// ---------------- positional encoding ------------------------------------
__global__ void pe_kernel(const float* __restrict__ src, float* __restrict__ pe,
                          int N, int shift, int cstride)
{
    const int col = blockIdx.x * 256 + threadIdx.x;
    if (col >= N) return;
    const int seg = 1 << shift;
    const float pos = src[(size_t)(col >> shift) * cstride + (col & (seg - 1))];
    #pragma unroll 4
    for (int i = 0; i < 128; ++i) {
        const float div = expf((float)i * -0.07195578415606394f); // -ln(10000)/128
        const float ang = pos * div;
        pe[(size_t)(2*i) * N + col]   = sinf(ang);
        pe[(size_t)(2*i+1) * N + col] = cosf(ang);
    }
}

// ---------------- input repack (drop channel 0) ---------------------------
__global__ void repack_kernel(const float* __restrict__ src, float* __restrict__ dst,
                              int N, int shift, int cstride)
{
    const int col = blockIdx.x * 256 + threadIdx.x;
    const int c = blockIdx.y;
    if (col >= N) return;
    const int seg = 1 << shift;
    dst[(size_t)c * N + col] =
        src[(size_t)(col >> shift) * cstride + (size_t)(c + 1) * seg + (col & (seg - 1))];
}

// ---------------- fuser self-attention over time (n=m=16 per track) -------
__global__ __launch_bounds__(256) void fuser_attn_kernel(
    const float* __restrict__ Qb, const float* __restrict__ Kb,
    const float* __restrict__ Vb, float* __restrict__ Ob)
{
    __shared__ float qs[256][17], ks[256][17], vs[256][17];
    __shared__ float ps[4][16][17];
    const int trk = blockIdx.x, tid = threadIdx.x;
    const int col0 = trk * 16;
    for (int idx = tid; idx < 1024; idx += 256) {
        const int r = idx >> 2, seg = (idx & 3) << 2;
        const float4 q = *(const float4*)&Qb[(size_t)r * NCT + col0 + seg];
        const float4 k = *(const float4*)&Kb[(size_t)r * NCT + col0 + seg];
        const float4 v = *(const float4*)&Vb[(size_t)r * NCT + col0 + seg];
        qs[r][seg]=q.x; qs[r][seg+1]=q.y; qs[r][seg+2]=q.z; qs[r][seg+3]=q.w;
        ks[r][seg]=k.x; ks[r][seg+1]=k.y; ks[r][seg+2]=k.z; ks[r][seg+3]=k.w;
        vs[r][seg]=v.x; vs[r][seg+1]=v.y; vs[r][seg+2]=v.z; vs[r][seg+3]=v.w;
    }
    __syncthreads();
    {
        const int g = tid >> 2, h = g >> 4, n = g & 15, mb = (tid & 3) << 2;
        float s[4] = {};
        #pragma unroll 4
        for (int hd = 0; hd < 64; ++hd) {
            const int c = hd*4 + h;
            const float q = qs[c][n];
            #pragma unroll
            for (int j = 0; j < 4; ++j) s[j] = fmaf(q, ks[c][mb + j], s[j]);
        }
        #pragma unroll
        for (int j = 0; j < 4; ++j) ps[h][n][mb + j] = s[j] * 0.125f;
    }
    __syncthreads();
    if (tid < 64) {
        const int hh = tid >> 4, nn = tid & 15;
        float mx = -INFINITY;
        for (int m = 0; m < 16; ++m) mx = fmaxf(mx, ps[hh][nn][m]);
        float sum = 0.f;
        for (int m = 0; m < 16; ++m) { const float p = expf(ps[hh][nn][m] - mx);
                                       ps[hh][nn][m] = p; sum += p; }
        const float inv = 1.f / sum;
        for (int m = 0; m < 16; ++m) ps[hh][nn][m] *= inv;
    }
    __syncthreads();
    {
        const int c = tid, hc = c & 3;
        float msg[16];
        #pragma unroll
        for (int n = 0; n < 16; ++n) {
            float a = 0.f;
            #pragma unroll
            for (int m = 0; m < 16; ++m) a = fmaf(ps[hc][n][m], vs[c][m], a);
            msg[n] = a;
        }
        __syncthreads();
        #pragma unroll
        for (int n = 0; n < 16; ++n) qs[c][n] = msg[n];
    }
    __syncthreads();
    for (int idx = tid; idx < 1024; idx += 256) {
        const int r = idx >> 2, seg = (idx & 3) << 2;
        *(float4*)&Ob[(size_t)r * NCT + col0 + seg] =
            make_float4(qs[r][seg], qs[r][seg+1], qs[r][seg+2], qs[r][seg+3]);
    }
}

// ---------------- GNN attention, flash-style online softmax ---------------
__global__ __launch_bounds__(256) void attn_kernel(
    const float* __restrict__ Qb, const float* __restrict__ Kb,
    const float* __restrict__ Vb, float* __restrict__ Ob,
    int nq, int nk, int NQ, int NK)
{
    __shared__ float Qs[64][65];
    __shared__ float KsS[64][65];
    __shared__ float Vs[64][65];
    __shared__ float rmax[64], rsum[64], ralpha[64];
    const int b = blockIdx.z, h = blockIdx.y, nt = blockIdx.x;
    const int tid = threadIdx.x;
    const int qcol = b * nq + nt * 64;
    for (int idx = tid; idx < 1024; idx += 256) {
        const int hd = idx >> 4, seg = (idx & 15) << 2;
        const float4 q = *(const float4*)&Qb[(size_t)(hd*4 + h) * NQ + qcol + seg];
        Qs[hd][seg]=q.x; Qs[hd][seg+1]=q.y; Qs[hd][seg+2]=q.z; Qs[hd][seg+3]=q.w;
    }
    if (tid < 64) { rmax[tid] = -INFINITY; rsum[tid] = 0.f; }
    float acc[4][4] = {};
    const int thd = (tid & 15) * 4, tn = (tid >> 4) * 4;
    const int mtiles = nk >> 6;
    for (int mt = 0; mt < mtiles; ++mt) {
        const int kcol = b * nk + mt * 64;
        __syncthreads();
        for (int idx = tid; idx < 1024; idx += 256) {
            const int hd = idx >> 4, seg = (idx & 15) << 2;
            const float4 k4 = *(const float4*)&Kb[(size_t)(hd*4 + h) * NK + kcol + seg];
            KsS[hd][seg]=k4.x; KsS[hd][seg+1]=k4.y; KsS[hd][seg+2]=k4.z; KsS[hd][seg+3]=k4.w;
            const float4 v4 = *(const float4*)&Vb[(size_t)(hd*4 + h) * NK + kcol + seg];
            Vs[hd][seg]=v4.x; Vs[hd][seg+1]=v4.y; Vs[hd][seg+2]=v4.z; Vs[hd][seg+3]=v4.w;
        }
        __syncthreads();
        float s[4][4] = {};
        const int tsm = (tid & 15) * 4, tsn = (tid >> 4) * 4;
        #pragma unroll 4
        for (int hd = 0; hd < 64; ++hd) {
            float qv[4], kv[4];
            #pragma unroll
            for (int i = 0; i < 4; ++i) { qv[i] = Qs[hd][tsn + i]; kv[i] = KsS[hd][tsm + i]; }
            #pragma unroll
            for (int i = 0; i < 4; ++i)
                #pragma unroll
                for (int j = 0; j < 4; ++j) s[i][j] = fmaf(qv[i], kv[j], s[i][j]);
        }
        __syncthreads();
        #pragma unroll
        for (int i = 0; i < 4; ++i)
            #pragma unroll
            for (int j = 0; j < 4; ++j) KsS[tsn + i][tsm + j] = s[i][j] * 0.125f;
        __syncthreads();
        if (tid < 64) {
            const float mo = rmax[tid];
            float mx = mo;
            for (int m = 0; m < 64; ++m) mx = fmaxf(mx, KsS[tid][m]);
            const float al = expf(mo - mx);
            float sum = 0.f;
            for (int m = 0; m < 64; ++m) { const float p = expf(KsS[tid][m] - mx);
                                           KsS[tid][m] = p; sum += p; }
            rsum[tid] = rsum[tid] * al + sum;
            rmax[tid] = mx; ralpha[tid] = al;
        }
        __syncthreads();
        float alj[4];
        #pragma unroll
        for (int j = 0; j < 4; ++j) alj[j] = ralpha[tn + j];
        #pragma unroll
        for (int i = 0; i < 4; ++i)
            #pragma unroll
            for (int j = 0; j < 4; ++j) acc[i][j] *= alj[j];
        for (int m = 0; m < 64; ++m) {
            float vv[4], pp[4];
            #pragma unroll
            for (int i = 0; i < 4; ++i) vv[i] = Vs[thd + i][m];
            #pragma unroll
            for (int j = 0; j < 4; ++j) pp[j] = KsS[tn + j][m];
            #pragma unroll
            for (int i = 0; i < 4; ++i)
                #pragma unroll
                for (int j = 0; j < 4; ++j) acc[i][j] = fmaf(vv[i], pp[j], acc[i][j]);
        }
    }
    __syncthreads();
    float rs[4];
    #pragma unroll
    for (int j = 0; j < 4; ++j) rs[j] = 1.f / rsum[tn + j];
    #pragma unroll
    for (int i = 0; i < 4; ++i)
        #pragma unroll
        for (int j = 0; j < 4; ++j)
            Ob[(size_t)((thd + i) * 4 + h) * NQ + qcol + tn + j] = acc[i][j] * rs[j];
}

// ---------------- mean pool over time (into combined cols [0,1024)) -------
__global__ void meanpool_kernel(const float* __restrict__ x, float* __restrict__ tr)
{
    const int trk = blockIdx.x * 256 + threadIdx.x;
    const int d = blockIdx.y;
    const float* p = x + (size_t)d * NCT + (size_t)trk * 16;
    float s = 0.f;
    #pragma unroll
    for (int t = 0; t < 16; ++t) s += p[t];
    tr[(size_t)d * NCB + trk] = s * 0.0625f;
}

// ---------------- scores = m0^T m1 / 16 into Z0 and Z0T -------------------
__global__ __launch_bounds__(256) void scores_kernel(
    const float* __restrict__ M, float* __restrict__ Z0, float* __restrict__ Z0T)
{
    __shared__ float As[8][68];
    __shared__ float Bs[8][68];
    const int bm = blockIdx.x, bn = blockIdx.y, b = blockIdx.z;
    const int tid = threadIdx.x;
    const int n0 = bn * 64, mm0 = bm * 64;
    const int tx = tid & 15, ty = tid >> 4;
    float acc[4][4] = {};
    for (int kb = 0; kb < 256; kb += 8) {
        __syncthreads();
        for (int idx = tid; idx < 512; idx += 256) {
            const int r = idx >> 6, cc = idx & 63;
            As[r][cc] = M[(size_t)(kb + r) * NCB + b * 256 + n0 + cc];
            Bs[r][cc] = M[(size_t)(kb + r) * NCB + 1024 + b * 1024 + mm0 + cc];
        }
        __syncthreads();
        #pragma unroll
        for (int kk = 0; kk < 8; ++kk) {
            float a[4], bv[4];
            #pragma unroll
            for (int i = 0; i < 4; ++i) { a[i] = As[kk][ty*4 + i]; bv[i] = Bs[kk][tx*4 + i]; }
            #pragma unroll
            for (int i = 0; i < 4; ++i)
                #pragma unroll
                for (int j = 0; j < 4; ++j) acc[i][j] = fmaf(a[i], bv[j], acc[i][j]);
        }
    }
    #pragma unroll
    for (int i = 0; i < 4; ++i)
        #pragma unroll
        for (int j = 0; j < 4; ++j) {
            const float s = acc[i][j] * 0.0625f;
            const int rr = n0 + ty*4 + i, cc = mm0 + tx*4 + j;
            Z0 [(size_t)b * ZBAT + (size_t)rr * ZCOL + cc] = s;
            Z0T[(size_t)b * ZBAT + (size_t)cc * ZROW + rr] = s;
        }
}

// ---------------- sinkhorn ------------------------------------------------
__global__ void sink_init_kernel(float* __restrict__ Z0, float* __restrict__ Z0T,
                                 float* __restrict__ v, const float* __restrict__ binp)
{
    const float alpha = binp[0];
    const int idx = blockIdx.x * 256 + threadIdx.x;
    if (idx < 4 * ZCOL) v[idx] = 0.f;
    if (idx < 4 * 1281) {
        const int b = idx / 1281, e = idx % 1281;
        if (e < 1025) Z0[(size_t)b * ZBAT + 256 * ZCOL + e] = alpha;
        else          Z0[(size_t)b * ZBAT + (size_t)(e - 1025) * ZCOL + 1024] = alpha;
    }
    if (idx < 4 * 1282) {
        const int b = idx / 1282, e = idx % 1282;
        if (e < 257) Z0T[(size_t)b * ZBAT + 1024 * ZROW + e] = alpha;
        else         Z0T[(size_t)b * ZBAT + (size_t)(e - 257) * ZROW + 256] = alpha;
    }
}

__global__ __launch_bounds__(256) void sink_u_kernel(
    const float* __restrict__ Z0, const float* __restrict__ v, float* __restrict__ u)
{
    const int w = threadIdx.x >> 6, lane = threadIdx.x & 63;
    const int row = blockIdx.x * 4 + w;          // 0..1027
    const int b = row / 257, i = row % 257;
    const float* z  = Z0 + (size_t)b * ZBAT + (size_t)i * ZCOL;
    const float* vb = v + b * ZCOL;
    float zz[17];
    float mx = -INFINITY;
    #pragma unroll
    for (int k = 0; k < 16; ++k) {
        zz[k] = z[lane + k*64] + vb[lane + k*64];
        mx = fmaxf(mx, zz[k]);
    }
    zz[16] = (lane == 0) ? (z[1024] + vb[1024]) : -INFINITY;
    mx = fmaxf(mx, zz[16]);
    #pragma unroll
    for (int off = 32; off; off >>= 1) mx = fmaxf(mx, __shfl_xor(mx, off));
    float s = 0.f;
    #pragma unroll
    for (int k = 0; k < 17; ++k) s += expf(zz[k] - mx);
    #pragma unroll
    for (int off = 32; off; off >>= 1) s += __shfl_xor(s, off);
    if (lane == 0) {
        const float lmu = (i < 256) ? NORM_C : (LOG_NS + NORM_C);
        u[b * 257 + i] = lmu - (mx + logf(s));
    }
}

__global__ __launch_bounds__(256) void sink_v_kernel(
    const float* __restrict__ Z0T, const float* __restrict__ u, float* __restrict__ v)
{
    const int w = threadIdx.x >> 6, lane = threadIdx.x & 63;
    const int row = blockIdx.x * 4 + w;          // 0..4099
    const int b = row / 1025, j = row - b * 1025;
    const float* z  = Z0T + (size_t)b * ZBAT + (size_t)j * ZROW;
    const float* ub = u + b * 257;
    float zz[5];
    float mx = -INFINITY;
    #pragma unroll
    for (int k = 0; k < 4; ++k) {
        zz[k] = z[lane + k*64] + ub[lane + k*64];
        mx = fmaxf(mx, zz[k]);
    }
    zz[4] = (lane == 0) ? (z[256] + ub[256]) : -INFINITY;
    mx = fmaxf(mx, zz[4]);
    #pragma unroll
    for (int off = 32; off; off >>= 1) mx = fmaxf(mx, __shfl_xor(mx, off));
    float s = 0.f;
    #pragma unroll
    for (int k = 0; k < 5; ++k) s += expf(zz[k] - mx);
    #pragma unroll
    for (int off = 32; off; off >>= 1) s += __shfl_xor(s, off);
    if (lane == 0) {
        const float lnu = (j < 1024) ? NORM_C : (LOG_MS + NORM_C);
        v[b * ZCOL + j] = lnu - (mx + logf(s));
    }
}

__global__ void sink_out_kernel(const float* __restrict__ Z0, const float* __restrict__ u,
                                const float* __restrict__ v, float* __restrict__ out)
{
    const int j = blockIdx.x * 256 + threadIdx.x;
    const int i = blockIdx.y, b = blockIdx.z;
    if (j < ZCOL) {
        const size_t idx = (size_t)b * ZBAT + (size_t)i * ZCOL + j;
        out[idx] = Z0[idx] + u[b * 257 + i] + v[b * ZCOL + j] + LOG_TOT;
    }
}

// ---------------------------------------------------------------------------
static inline void gemm(hipStream_t st, const float* W, const float* X0,
                        const float* X1, int C0, const float* bias,
                        const float* res, int Nr, float* out, int No,
                        int O, int C, int N, int relu)
{
    dim3 g(N / 128, O / 128);
    gemm_kernel<<<g, 256, 0, st>>>(W, X0, X1, bias, res, out, O, C, C0, N, Nr, No, relu);
}

static inline void gemm64(hipStream_t st, const float* W, const float* X0,
                          const float* X1, int C0, const float* bias,
                          const float* res, int Nr, float* out, int No,
                          int O, int C, int N, int relu)
{
    dim3 g(N / 128, O / 64);
    gemm64_kernel<<<g, 256, 0, st>>>(W, X0, X1, bias, res, out, O, C, C0, N, Nr, No, relu);
}

extern "C" void kernel_launch(void* const* d_in, const int* in_sizes, int n_in,
                              void* d_out, int out_size, void* d_ws, size_t ws_size,
                              hipStream_t stream)
{
    (void)in_sizes; (void)n_in; (void)out_size; (void)ws_size;
    const float* det_in = (const float*)d_in[0];
    const float* trk_in = (const float*)d_in[1];
    const float* enc_w1 = (const float*)d_in[2];
    const float* enc_b1 = (const float*)d_in[3];
    const float* enc_w2 = (const float*)d_in[4];
    const float* enc_b2 = (const float*)d_in[5];
    const float* fus_pw = (const float*)d_in[6];
    const float* fus_pb = (const float*)d_in[7];
    const float* fus_mw = (const float*)d_in[8];
    const float* fus_mb = (const float*)d_in[9];
    const float* fus_m1w = (const float*)d_in[10];
    const float* fus_m1b = (const float*)d_in[11];
    const float* fus_m2w = (const float*)d_in[12];
    const float* fus_m2b = (const float*)d_in[13];
    const float* gnn_pw = (const float*)d_in[14];
    const float* gnn_pb = (const float*)d_in[15];
    const float* gnn_mw = (const float*)d_in[16];
    const float* gnn_mb = (const float*)d_in[17];
    const float* gnn_m1w = (const float*)d_in[18];
    const float* gnn_m1b = (const float*)d_in[19];
    const float* gnn_m2w = (const float*)d_in[20];
    const float* gnn_m2b = (const float*)d_in[21];
    const float* final_w = (const float*)d_in[22];
    const float* final_b = (const float*)d_in[23];
    const float* bin_sc  = (const float*)d_in[24];
    float* out = (float*)d_out;

    float* ws = (float*)d_ws;
    float* XF   = ws;                      // 4,194,304  fuser state x [256][16384]
    float* R    = ws + 4194304;            // 16,777,216 temp arena
    float* COMB = ws + 20971520;           // 1,310,720  [256][5120] tr|det state
    float* Z0   = ws + 22282240;           // 1,053,700
    float* U    = ws + 23335940;           //     1,028
    float* V    = ws + 23336968;           //     4,100
    // arena aliases (fuser / det-enc): Q,K,V contiguous so qkv is one O=768 GEMM
    float* Qf = R;
    float* Kf = R + 4194304;
    float* Vf = R + 8388608;
    float* MS = R + 12582912;
    // arena aliases (GNN, combined N=5120):
    float* QKV = R;                       // [768][5120]
    float* H   = R + 1310720;             // [512][5120]
    float* MSG = R + 3932160;             // [256][5120]
    float* M   = R + 5242880;             // [256][5120]
    const float* Qt = QKV;
    const float* Kt = QKV + (size_t)256 * NCB;
    const float* Vt = QKV + (size_t)512 * NCB;
    const float* Qd = Qt + 1024;
    const float* Kd = Kt + 1024;
    const float* Vd = Vt + 1024;
    // arena alias (sinkhorn): Z0T at R base; M (R+5242880) still live during scores
    float* Z0T = R;                       // 1,053,700  [4][1025][257]

    // ================= encoder (tracks) + fuser ===========================
    pe_kernel<<<NCT/256, 256, 0, stream>>>(trk_in, MS, NCT, 4, 257*16);
    repack_kernel<<<dim3(NCT/256, 256), 256, 0, stream>>>(trk_in, Qf, NCT, 4, 257*16);
    gemm(stream, enc_w1, Qf, Qf, 256, enc_b1, nullptr, 0, Kf, NCT, 256, 256, NCT, 1);
    gemm(stream, enc_w2, Kf, Kf, 256, enc_b2, MS, NCT, XF, NCT, 256, 256, NCT, 0);

    for (int l = 0; l < 4; ++l) {
        gemm(stream, fus_pw + l*196608, XF, XF, 256, fus_pb + l*768,
             nullptr, 0, Qf, NCT, 768, 256, NCT, 0);
        fuser_attn_kernel<<<1024, 256, 0, stream>>>(Qf, Kf, Vf, MS);
        gemm(stream, fus_mw + l*65536, MS, MS, 256, fus_mb + l*256,
             nullptr, 0, Qf, NCT, 256, 256, NCT, 0);               // M -> Qf
        gemm(stream, fus_m1w + l*262144, XF, Qf, 256, fus_m1b + l*512,
             nullptr, 0, Kf, NCT, 512, 512, NCT, 1);               // H -> Kf..Vf
        gemm(stream, fus_m2w + l*131072, Kf, Kf, 512, fus_m2b + l*256,
             XF, NCT, XF, NCT, 256, 512, NCT, 0);                  // x += ...
    }
    meanpool_kernel<<<dim3(4, 256), 256, 0, stream>>>(XF, COMB);   // tr cols [0,1024)

    // ================= encoder (detections) -> COMB cols [1024,5120) ======
    pe_kernel<<<NCD/256, 256, 0, stream>>>(det_in, MS, NCD, 10, 257*1024);
    repack_kernel<<<dim3(NCD/256, 256), 256, 0, stream>>>(det_in, Qf, NCD, 10, 257*1024);
    gemm64(stream, enc_w1, Qf, Qf, 256, enc_b1, nullptr, 0, Kf, NCD, 256, 256, NCD, 1);
    gemm64(stream, enc_w2, Kf, Kf, 256, enc_b2, MS, NCD, COMB + 1024, NCB, 256, 256, NCD, 0);

    // ================= GNN (combined tr|det, N=5120) ======================
    for (int l = 0; l < 12; ++l) {
        const float* pw  = gnn_pw + l*196608;
        const float* pb  = gnn_pb + l*768;
        const float* mw  = gnn_mw + l*65536;
        const float* mb  = gnn_mb + l*256;
        const float* m1w = gnn_m1w + l*262144;
        const float* m1b = gnn_m1b + l*512;
        const float* m2w = gnn_m2w + l*131072;
        const float* m2b = gnn_m2b + l*256;
        const bool cross = (l & 1);

        gemm64(stream, pw, COMB, COMB, 256, pb, nullptr, 0, QKV, NCB, 768, 256, NCB, 0);

        attn_kernel<<<dim3(4, 4, 4), 256, 0, stream>>>(
            Qt, cross ? Kd : Kt, cross ? Vd : Vt, MSG,
            256, cross ? 1024 : 256, NCB, NCB);
        attn_kernel<<<dim3(16, 4, 4), 256, 0, stream>>>(
            Qd, cross ? Kt : Kd, cross ? Vt : Vd, MSG + 1024,
            1024, cross ? 256 : 1024, NCB, NCB);

        gemm64(stream, mw, MSG, MSG, 256, mb, nullptr, 0, M, NCB, 256, 256, NCB, 0);
        gemm64(stream, m1w, COMB, M, 256, m1b, nullptr, 0, H, NCB, 512, 512, NCB, 1);
        gemm64(stream, m2w, H, H, 512, m2b, COMB, NCB, COMB, NCB, 256, 512, NCB, 0);
    }

    // ================= final projection + scores + sinkhorn ===============
    gemm64(stream, final_w, COMB, COMB, 256, final_b, nullptr, 0, M, NCB, 256, 256, NCB, 0);
    scores_kernel<<<dim3(16, 4, 4), 256, 0, stream>>>(M, Z0, Z0T);
    sink_init_kernel<<<21, 256, 0, stream>>>(Z0, Z0T, V, bin_sc);
    for (int it = 0; it < 100; ++it) {
        sink_u_kernel<<<257, 256, 0, stream>>>(Z0, V, U);
        sink_v_kernel<<<1025, 256, 0, stream>>>(Z0T, U, V);
    }
    sink_out_kernel<<<dim3(5, 257, 4), 256, 0, stream>>>(Z0, U, V, out);
}

// Round 6
// 3704.076 us; speedup vs baseline: 1.9083x; 1.4145x over previous
//
#include <hip/hip_runtime.h>
#include <math.h>

// ---------------------------------------------------------------------------
// Associator forward. GEMMs + GNN attention: split-fp16 (hi+lo) MFMA, fp32 acc.
// Layouts: activations are [C][Ncols] row-major fp32.
//   trk cols: 16384 (track*16+t); GNN combined cols: 5120 = [tr: b*256+n | 1024 + det: b*1024+m]
// Sinkhorn: 200 graph-replayed micro-launches (measured cheaper than device-
// scope grid barriers on gfx950: barrier ~7µs vs launch gap ~2-3µs), with
// Z0T materialized so both LSE phases are coalesced wave-per-row.
// ---------------------------------------------------------------------------

#define NCT 16384
#define NCD 4096
#define NCB 5120
#define ZROW 257
#define ZCOL 1025
#define ZBAT (ZROW*ZCOL)   // 263425

#define NORM_C  (-7.1546153569f)   // -log(1280)
#define LOG_NS  (6.9314718056f)    // log(1024)
#define LOG_MS  (5.5451774445f)    // log(256)
#define LOG_TOT (7.1546153569f)    // +log(1280)

typedef _Float16 f16x8 __attribute__((ext_vector_type(8)));
typedef _Float16 f16x4 __attribute__((ext_vector_type(4)));
typedef float f32x4 __attribute__((ext_vector_type(4)));

#define APAD 40   // LDS row stride in halves (80 B: 16B-aligned rows)

// ---------------- GEMM 128x128: out = W @ [X0;X1] + bias (+res) (relu?) ---
__global__ __launch_bounds__(256) void gemm_kernel(
    const float* __restrict__ W, const float* __restrict__ X0,
    const float* __restrict__ X1, const float* __restrict__ bias,
    const float* __restrict__ res, float* __restrict__ out,
    int O, int C, int C0, int N, int Nr, int No, int relu)
{
    __shared__ _Float16 Ah[128][APAD], Al[128][APAD];
    __shared__ _Float16 Bh[128][APAD], Bl[128][APAD];
    const int tid = threadIdx.x;
    const int n0 = blockIdx.x * 128, m0 = blockIdx.y * 128;
    const int wave = tid >> 6, lane = tid & 63;
    const int wo = (wave >> 1) * 64, wn = (wave & 1) * 64;
    const int lm = lane & 15, lq = lane >> 4;
    const int ar = tid >> 1, akh = (tid & 1) << 4;
    const int bkg = tid & 7, bng = tid >> 3;

    f32x4 acc[4][4] = {};

    for (int kb = 0; kb < C; kb += 32) {
        float4 av[4];
        const float* wp = W + (size_t)(m0 + ar) * C + kb + akh;
        #pragma unroll
        for (int q = 0; q < 4; ++q) av[q] = *(const float4*)(wp + 4 * q);
        float4 xv[4];
        #pragma unroll
        for (int r = 0; r < 4; ++r) {
            const int krow = kb + bkg * 4 + r;
            const float* xs = (krow < C0) ? X0 + (size_t)krow * N
                                          : X1 + (size_t)(krow - C0) * N;
            xv[r] = *(const float4*)(xs + n0 + bng * 4);
        }
        __syncthreads();
        {
            _Float16 hbuf[16], lbuf[16];
            #pragma unroll
            for (int q = 0; q < 4; ++q) {
                const float* f = (const float*)&av[q];
                #pragma unroll
                for (int c = 0; c < 4; ++c) {
                    const float x = f[c];
                    const _Float16 h = (_Float16)x;
                    hbuf[q * 4 + c] = h;
                    lbuf[q * 4 + c] = (_Float16)(x - (float)h);
                }
            }
            *(f16x8*)&Ah[ar][akh]     = *(const f16x8*)&hbuf[0];
            *(f16x8*)&Ah[ar][akh + 8] = *(const f16x8*)&hbuf[8];
            *(f16x8*)&Al[ar][akh]     = *(const f16x8*)&lbuf[0];
            *(f16x8*)&Al[ar][akh + 8] = *(const f16x8*)&lbuf[8];
        }
        #pragma unroll
        for (int j = 0; j < 4; ++j) {
            _Float16 hb[4], lb[4];
            #pragma unroll
            for (int r = 0; r < 4; ++r) {
                const float x = ((const float*)&xv[r])[j];
                const _Float16 h = (_Float16)x;
                hb[r] = h;
                lb[r] = (_Float16)(x - (float)h);
            }
            *(f16x4*)&Bh[bng * 4 + j][bkg * 4] = *(const f16x4*)&hb[0];
            *(f16x4*)&Bl[bng * 4 + j][bkg * 4] = *(const f16x4*)&lb[0];
        }
        __syncthreads();
        f16x8 bh[4], bl[4];
        #pragma unroll
        for (int t = 0; t < 4; ++t) {
            bh[t] = *(const f16x8*)&Bh[wn + t * 16 + lm][lq * 8];
            bl[t] = *(const f16x8*)&Bl[wn + t * 16 + lm][lq * 8];
        }
        #pragma unroll
        for (int mt = 0; mt < 4; ++mt) {
            const f16x8 ah = *(const f16x8*)&Ah[wo + mt * 16 + lm][lq * 8];
            const f16x8 al = *(const f16x8*)&Al[wo + mt * 16 + lm][lq * 8];
            #pragma unroll
            for (int nt = 0; nt < 4; ++nt) {
                acc[mt][nt] = __builtin_amdgcn_mfma_f32_16x16x32_f16(ah, bh[nt], acc[mt][nt], 0, 0, 0);
                acc[mt][nt] = __builtin_amdgcn_mfma_f32_16x16x32_f16(ah, bl[nt], acc[mt][nt], 0, 0, 0);
                acc[mt][nt] = __builtin_amdgcn_mfma_f32_16x16x32_f16(al, bh[nt], acc[mt][nt], 0, 0, 0);
            }
        }
    }
    #pragma unroll
    for (int mt = 0; mt < 4; ++mt) {
        #pragma unroll
        for (int rg = 0; rg < 4; ++rg) {
            const int o = m0 + wo + mt * 16 + lq * 4 + rg;
            const float bs = bias[o];
            #pragma unroll
            for (int nt = 0; nt < 4; ++nt) {
                const int n = n0 + wn + nt * 16 + lm;
                float v = acc[mt][nt][rg] + bs;
                if (res) v += res[(size_t)o * Nr + n];
                if (relu) v = fmaxf(v, 0.f);
                out[(size_t)o * No + n] = v;
            }
        }
    }
}

// ---------------- GEMM 64x128 tile (for small grids: GNN/det/final) -------
__global__ __launch_bounds__(256) void gemm64_kernel(
    const float* __restrict__ W, const float* __restrict__ X0,
    const float* __restrict__ X1, const float* __restrict__ bias,
    const float* __restrict__ res, float* __restrict__ out,
    int O, int C, int C0, int N, int Nr, int No, int relu)
{
    __shared__ _Float16 Ah[64][APAD], Al[64][APAD];
    __shared__ _Float16 Bh[128][APAD], Bl[128][APAD];
    const int tid = threadIdx.x;
    const int n0 = blockIdx.x * 128, m0 = blockIdx.y * 64;
    const int wave = tid >> 6, lane = tid & 63;
    const int wo = (wave >> 1) * 32, wn = (wave & 1) * 64;
    const int lm = lane & 15, lq = lane >> 4;
    const int ar = tid >> 2, ak8 = (tid & 3) << 3;
    const int bkg = tid & 7, bng = tid >> 3;

    f32x4 acc[2][4] = {};

    for (int kb = 0; kb < C; kb += 32) {
        float4 av[2];
        const float* wp = W + (size_t)(m0 + ar) * C + kb + ak8;
        av[0] = *(const float4*)(wp);
        av[1] = *(const float4*)(wp + 4);
        float4 xv[4];
        #pragma unroll
        for (int r = 0; r < 4; ++r) {
            const int krow = kb + bkg * 4 + r;
            const float* xs = (krow < C0) ? X0 + (size_t)krow * N
                                          : X1 + (size_t)(krow - C0) * N;
            xv[r] = *(const float4*)(xs + n0 + bng * 4);
        }
        __syncthreads();
        {
            _Float16 hbuf[8], lbuf[8];
            #pragma unroll
            for (int q = 0; q < 2; ++q) {
                const float* f = (const float*)&av[q];
                #pragma unroll
                for (int c = 0; c < 4; ++c) {
                    const float x = f[c];
                    const _Float16 h = (_Float16)x;
                    hbuf[q * 4 + c] = h;
                    lbuf[q * 4 + c] = (_Float16)(x - (float)h);
                }
            }
            *(f16x8*)&Ah[ar][ak8] = *(const f16x8*)&hbuf[0];
            *(f16x8*)&Al[ar][ak8] = *(const f16x8*)&lbuf[0];
        }
        #pragma unroll
        for (int j = 0; j < 4; ++j) {
            _Float16 hb[4], lb[4];
            #pragma unroll
            for (int r = 0; r < 4; ++r) {
                const float x = ((const float*)&xv[r])[j];
                const _Float16 h = (_Float16)x;
                hb[r] = h;
                lb[r] = (_Float16)(x - (float)h);
            }
            *(f16x4*)&Bh[bng * 4 + j][bkg * 4] = *(const f16x4*)&hb[0];
            *(f16x4*)&Bl[bng * 4 + j][bkg * 4] = *(const f16x4*)&lb[0];
        }
        __syncthreads();
        f16x8 bh[4], bl[4];
        #pragma unroll
        for (int t = 0; t < 4; ++t) {
            bh[t] = *(const f16x8*)&Bh[wn + t * 16 + lm][lq * 8];
            bl[t] = *(const f16x8*)&Bl[wn + t * 16 + lm][lq * 8];
        }
        #pragma unroll
        for (int mt = 0; mt < 2; ++mt) {
            const f16x8 ah = *(const f16x8*)&Ah[wo + mt * 16 + lm][lq * 8];
            const f16x8 al = *(const f16x8*)&Al[wo + mt * 16 + lm][lq * 8];
            #pragma unroll
            for (int nt = 0; nt < 4; ++nt) {
                acc[mt][nt] = __builtin_amdgcn_mfma_f32_16x16x32_f16(ah, bh[nt], acc[mt][nt], 0, 0, 0);
                acc[mt][nt] = __builtin_amdgcn_mfma_f32_16x16x32_f16(ah, bl[nt], acc[mt][nt], 0, 0, 0);
                acc[mt][nt] = __builtin_amdgcn_mfma_f32_16x16x32_f16(al, bh[nt], acc[mt][nt], 0, 0, 0);
            }
        }
    }
    #pragma unroll
    for (int mt = 0; mt < 2; ++mt) {
        #pragma unroll
        for (int rg = 0; rg < 4; ++rg) {
            const int o = m0 + wo + mt * 16 + lq * 4 + rg;
            const float bs = bias[o];
            #pragma unroll
            for (int nt = 0; nt < 4; ++nt) {
                const int n = n0 + wn + nt * 16 + lm;
                float v = acc[mt][nt][rg] + bs;
                if (res) v += res[(size_t)o * Nr + n];
                if (relu) v = fmaxf(v, 0.f);
                out[(size_t)o * No + n] = v;
            }
        }
    }
}

// ---------------- positional encoding ------------------------------------
__global__ void pe_kernel(const float* __restrict__ src, float* __restrict__ pe,
                          int N, int shift, int cstride)
{
    const int col = blockIdx.x * 256 + threadIdx.x;
    if (col >= N) return;
    const int seg = 1 << shift;
    const float pos = src[(size_t)(col >> shift) * cstride + (col & (seg - 1))];
    #pragma unroll 4
    for (int i = 0; i < 128; ++i) {
        const float div = expf((float)i * -0.07195578415606394f); // -ln(10000)/128
        const float ang = pos * div;
        pe[(size_t)(2*i) * N + col]   = sinf(ang);
        pe[(size_t)(2*i+1) * N + col] = cosf(ang);
    }
}

// ---------------- input repack (drop channel 0) ---------------------------
__global__ void repack_kernel(const float* __restrict__ src, float* __restrict__ dst,
                              int N, int shift, int cstride)
{
    const int col = blockIdx.x * 256 + threadIdx.x;
    const int c = blockIdx.y;
    if (col >= N) return;
    const int seg = 1 << shift;
    dst[(size_t)c * N + col] =
        src[(size_t)(col >> shift) * cstride + (size_t)(c + 1) * seg + (col & (seg - 1))];
}

// ---------------- fuser self-attention over time (n=m=16 per track) -------
__global__ __launch_bounds__(256) void fuser_attn_kernel(
    const float* __restrict__ Qb, const float* __restrict__ Kb,
    const float* __restrict__ Vb, float* __restrict__ Ob)
{
    __shared__ float qs[256][17], ks[256][17], vs[256][17];
    __shared__ float ps[4][16][17];
    const int trk = blockIdx.x, tid = threadIdx.x;
    const int col0 = trk * 16;
    for (int idx = tid; idx < 1024; idx += 256) {
        const int r = idx >> 2, seg = (idx & 3) << 2;
        const float4 q = *(const float4*)&Qb[(size_t)r * NCT + col0 + seg];
        const float4 k = *(const float4*)&Kb[(size_t)r * NCT + col0 + seg];
        const float4 v = *(const float4*)&Vb[(size_t)r * NCT + col0 + seg];
        qs[r][seg]=q.x; qs[r][seg+1]=q.y; qs[r][seg+2]=q.z; qs[r][seg+3]=q.w;
        ks[r][seg]=k.x; ks[r][seg+1]=k.y; ks[r][seg+2]=k.z; ks[r][seg+3]=k.w;
        vs[r][seg]=v.x; vs[r][seg+1]=v.y; vs[r][seg+2]=v.z; vs[r][seg+3]=v.w;
    }
    __syncthreads();
    {
        const int g = tid >> 2, h = g >> 4, n = g & 15, mb = (tid & 3) << 2;
        float s[4] = {};
        #pragma unroll 4
        for (int hd = 0; hd < 64; ++hd) {
            const int c = hd*4 + h;
            const float q = qs[c][n];
            #pragma unroll
            for (int j = 0; j < 4; ++j) s[j] = fmaf(q, ks[c][mb + j], s[j]);
        }
        #pragma unroll
        for (int j = 0; j < 4; ++j) ps[h][n][mb + j] = s[j] * 0.125f;
    }
    __syncthreads();
    if (tid < 64) {
        const int hh = tid >> 4, nn = tid & 15;
        float mx = -INFINITY;
        for (int m = 0; m < 16; ++m) mx = fmaxf(mx, ps[hh][nn][m]);
        float sum = 0.f;
        for (int m = 0; m < 16; ++m) { const float p = expf(ps[hh][nn][m] - mx);
                                       ps[hh][nn][m] = p; sum += p; }
        const float inv = 1.f / sum;
        for (int m = 0; m < 16; ++m) ps[hh][nn][m] *= inv;
    }
    __syncthreads();
    {
        const int c = tid, hc = c & 3;
        float msg[16];
        #pragma unroll
        for (int n = 0; n < 16; ++n) {
            float a = 0.f;
            #pragma unroll
            for (int m = 0; m < 16; ++m) a = fmaf(ps[hc][n][m], vs[c][m], a);
            msg[n] = a;
        }
        __syncthreads();
        #pragma unroll
        for (int n = 0; n < 16; ++n) qs[c][n] = msg[n];
    }
    __syncthreads();
    for (int idx = tid; idx < 1024; idx += 256) {
        const int r = idx >> 2, seg = (idx & 3) << 2;
        *(float4*)&Ob[(size_t)r * NCT + col0 + seg] =
            make_float4(qs[r][seg], qs[r][seg+1], qs[r][seg+2], qs[r][seg+3]);
    }
}

// ---------------- GNN attention: split-fp16 MFMA flash ---------------------
// grid (nq/64, H=4, B=4), 256 thr = 4 waves; wave w owns q-rows [16w,16w+16).
// Q/K staged transposed [pos][d] hi/lo; V direct [d][pos] hi/lo.
// S and msg accumulate in MFMA C-layout (row=quad*4+reg -> per-lane row
// stats; softmax shuffles span the 16 lanes of a quad only).
// P (split hi/lo) overlays the K LDS region after all waves finish QK.
__global__ __launch_bounds__(256) void attn_kernel(
    const float* __restrict__ Qb, const float* __restrict__ Kb,
    const float* __restrict__ Vb, float* __restrict__ Ob,
    int nq, int nk, int NQ, int NK)
{
    __shared__ _Float16 Qh[64][72], Ql[64][72];   // [qpos][d]
    __shared__ _Float16 Kh[64][72], Kl[64][72];   // [kpos][d]; P after QK
    __shared__ _Float16 Vh[64][72], Vl[64][72];   // [d][mpos]
    const int b = blockIdx.z, h = blockIdx.y, nt = blockIdx.x;
    const int tid = threadIdx.x;
    const int wave = tid >> 6, lane = tid & 63;
    const int lm = lane & 15, quad = lane >> 4;
    const int qcol = b * nq + nt * 64;
    const int dg = tid & 15, qg = tid >> 4;       // transpose-stage mapping
    const int vd = tid >> 2, vseg = (tid & 3) * 16; // V-stage mapping

    // ---- stage Q (transposed 4x4 micro-tiles) ----
    {
        float4 xv[4];
        #pragma unroll
        for (int r = 0; r < 4; ++r) {
            const int chan = (dg * 4 + r) * 4 + h;
            xv[r] = *(const float4*)&Qb[(size_t)chan * NQ + qcol + qg * 4];
        }
        #pragma unroll
        for (int j = 0; j < 4; ++j) {
            _Float16 hb[4], lb[4];
            #pragma unroll
            for (int r = 0; r < 4; ++r) {
                const float x = ((const float*)&xv[r])[j];
                const _Float16 hh = (_Float16)x;
                hb[r] = hh; lb[r] = (_Float16)(x - (float)hh);
            }
            *(f16x4*)&Qh[qg * 4 + j][dg * 4] = *(const f16x4*)hb;
            *(f16x4*)&Ql[qg * 4 + j][dg * 4] = *(const f16x4*)lb;
        }
    }
    __syncthreads();
    f16x8 qh[2], ql[2];
    #pragma unroll
    for (int ks = 0; ks < 2; ++ks) {
        qh[ks] = *(const f16x8*)&Qh[wave * 16 + lm][ks * 32 + quad * 8];
        ql[ks] = *(const f16x8*)&Ql[wave * 16 + lm][ks * 32 + quad * 8];
    }

    float rmax[4], rsum[4];
    #pragma unroll
    for (int r = 0; r < 4; ++r) { rmax[r] = -INFINITY; rsum[r] = 0.f; }
    f32x4 acco[4] = {};   // [d-tile]; row=quad*4+reg (qrow), col=16*td+lm (d)

    const int mtiles = nk >> 6;
    for (int mt = 0; mt < mtiles; ++mt) {
        const int kcol = b * nk + mt * 64;
        __syncthreads();              // prior P/V readers done before restage
        {   // stage K (transposed) + V (direct)
            float4 xv[4];
            #pragma unroll
            for (int r = 0; r < 4; ++r) {
                const int chan = (dg * 4 + r) * 4 + h;
                xv[r] = *(const float4*)&Kb[(size_t)chan * NK + kcol + qg * 4];
            }
            #pragma unroll
            for (int j = 0; j < 4; ++j) {
                _Float16 hb[4], lb[4];
                #pragma unroll
                for (int r = 0; r < 4; ++r) {
                    const float x = ((const float*)&xv[r])[j];
                    const _Float16 hh = (_Float16)x;
                    hb[r] = hh; lb[r] = (_Float16)(x - (float)hh);
                }
                *(f16x4*)&Kh[qg * 4 + j][dg * 4] = *(const f16x4*)hb;
                *(f16x4*)&Kl[qg * 4 + j][dg * 4] = *(const f16x4*)lb;
            }
            const int vchan = vd * 4 + h;
            float4 v4[4];
            #pragma unroll
            for (int q = 0; q < 4; ++q)
                v4[q] = *(const float4*)&Vb[(size_t)vchan * NK + kcol + vseg + q * 4];
            _Float16 vh16[16], vl16[16];
            #pragma unroll
            for (int q = 0; q < 4; ++q) {
                const float* f = (const float*)&v4[q];
                #pragma unroll
                for (int c = 0; c < 4; ++c) {
                    const float x = f[c];
                    const _Float16 hh = (_Float16)x;
                    vh16[q*4+c] = hh; vl16[q*4+c] = (_Float16)(x - (float)hh);
                }
            }
            *(f16x8*)&Vh[vd][vseg]     = *(const f16x8*)&vh16[0];
            *(f16x8*)&Vh[vd][vseg + 8] = *(const f16x8*)&vh16[8];
            *(f16x8*)&Vl[vd][vseg]     = *(const f16x8*)&vl16[0];
            *(f16x8*)&Vl[vd][vseg + 8] = *(const f16x8*)&vl16[8];
        }
        __syncthreads();
        // ---- S = Q K^T / 8 (split: Qh*Kh + Qh*Kl + Ql*Kh) ----
        f32x4 accs[4] = {};
        #pragma unroll
        for (int t = 0; t < 4; ++t) {
            #pragma unroll
            for (int ks = 0; ks < 2; ++ks) {
                const f16x8 kh = *(const f16x8*)&Kh[t * 16 + lm][ks * 32 + quad * 8];
                const f16x8 kl = *(const f16x8*)&Kl[t * 16 + lm][ks * 32 + quad * 8];
                accs[t] = __builtin_amdgcn_mfma_f32_16x16x32_f16(qh[ks], kh, accs[t], 0,0,0);
                accs[t] = __builtin_amdgcn_mfma_f32_16x16x32_f16(qh[ks], kl, accs[t], 0,0,0);
                accs[t] = __builtin_amdgcn_mfma_f32_16x16x32_f16(ql[ks], kh, accs[t], 0,0,0);
            }
        }
        // ---- online softmax; row r_local = quad*4+r ----
        float alpha[4];
        float psv[4][4];
        #pragma unroll
        for (int r = 0; r < 4; ++r) {
            float mx = fmaxf(fmaxf(accs[0][r], accs[1][r]),
                             fmaxf(accs[2][r], accs[3][r])) * 0.125f;
            #pragma unroll
            for (int off = 1; off < 16; off <<= 1) mx = fmaxf(mx, __shfl_xor(mx, off));
            const float mnew = fmaxf(rmax[r], mx);
            alpha[r] = expf(rmax[r] - mnew);
            rmax[r] = mnew;
            float s = 0.f;
            #pragma unroll
            for (int t = 0; t < 4; ++t) {
                const float p = expf(accs[t][r] * 0.125f - mnew);
                psv[t][r] = p; s += p;
            }
            #pragma unroll
            for (int off = 1; off < 16; off <<= 1) s += __shfl_xor(s, off);
            rsum[r] = rsum[r] * alpha[r] + s;
        }
        __syncthreads();              // all waves done reading K -> overlay P
        #pragma unroll
        for (int t = 0; t < 4; ++t)
            #pragma unroll
            for (int r = 0; r < 4; ++r) {
                const float x = psv[t][r];
                const _Float16 hh = (_Float16)x;
                Kh[wave * 16 + quad * 4 + r][t * 16 + lm] = hh;
                Kl[wave * 16 + quad * 4 + r][t * 16 + lm] = (_Float16)(x - (float)hh);
            }
        __syncthreads();              // P strips visible (and lgkm drained)
        #pragma unroll
        for (int td = 0; td < 4; ++td)
            #pragma unroll
            for (int r = 0; r < 4; ++r) acco[td][r] *= alpha[r];
        // ---- msg += P V (split: Ph*Vh + Ph*Vl + Pl*Vh) ----
        #pragma unroll
        for (int ks = 0; ks < 2; ++ks) {
            const f16x8 ph = *(const f16x8*)&Kh[wave * 16 + lm][ks * 32 + quad * 8];
            const f16x8 pl = *(const f16x8*)&Kl[wave * 16 + lm][ks * 32 + quad * 8];
            #pragma unroll
            for (int td = 0; td < 4; ++td) {
                const f16x8 vh = *(const f16x8*)&Vh[td * 16 + lm][ks * 32 + quad * 8];
                const f16x8 vl = *(const f16x8*)&Vl[td * 16 + lm][ks * 32 + quad * 8];
                acco[td] = __builtin_amdgcn_mfma_f32_16x16x32_f16(ph, vh, acco[td], 0,0,0);
                acco[td] = __builtin_amdgcn_mfma_f32_16x16x32_f16(ph, vl, acco[td], 0,0,0);
                acco[td] = __builtin_amdgcn_mfma_f32_16x16x32_f16(pl, vh, acco[td], 0,0,0);
            }
        }
    }
    // ---- write msg: chan = d*4 + h, qpos = qcol + 16*wave + quad*4 + r ----
    float inv[4];
    #pragma unroll
    for (int r = 0; r < 4; ++r) inv[r] = 1.f / rsum[r];
    #pragma unroll
    for (int td = 0; td < 4; ++td)
        #pragma unroll
        for (int r = 0; r < 4; ++r) {
            const int chan = (td * 16 + lm) * 4 + h;
            const int qp = qcol + wave * 16 + quad * 4 + r;
            Ob[(size_t)chan * NQ + qp] = acco[td][r] * inv[r];
        }
}

// ---------------- mean pool over time (into combined cols [0,1024)) -------
__global__ void meanpool_kernel(const float* __restrict__ x, float* __restrict__ tr)
{
    const int trk = blockIdx.x * 256 + threadIdx.x;
    const int d = blockIdx.y;
    const float* p = x + (size_t)d * NCT + (size_t)trk * 16;
    float s = 0.f;
    #pragma unroll
    for (int t = 0; t < 16; ++t) s += p[t];
    tr[(size_t)d * NCB + trk] = s * 0.0625f;
}

// ---------------- scores = m0^T m1 / 16 into Z0 and Z0T -------------------
__global__ __launch_bounds__(256) void scores_kernel(
    const float* __restrict__ M, float* __restrict__ Z0, float* __restrict__ Z0T)
{
    __shared__ float As[8][68];
    __shared__ float Bs[8][68];
    const int bm = blockIdx.x, bn = blockIdx.y, b = blockIdx.z;
    const int tid = threadIdx.x;
    const int n0 = bn * 64, mm0 = bm * 64;
    const int tx = tid & 15, ty = tid >> 4;
    float acc[4][4] = {};
    for (int kb = 0; kb < 256; kb += 8) {
        __syncthreads();
        for (int idx = tid; idx < 512; idx += 256) {
            const int r = idx >> 6, cc = idx & 63;
            As[r][cc] = M[(size_t)(kb + r) * NCB + b * 256 + n0 + cc];
            Bs[r][cc] = M[(size_t)(kb + r) * NCB + 1024 + b * 1024 + mm0 + cc];
        }
        __syncthreads();
        #pragma unroll
        for (int kk = 0; kk < 8; ++kk) {
            float a[4], bv[4];
            #pragma unroll
            for (int i = 0; i < 4; ++i) { a[i] = As[kk][ty*4 + i]; bv[i] = Bs[kk][tx*4 + i]; }
            #pragma unroll
            for (int i = 0; i < 4; ++i)
                #pragma unroll
                for (int j = 0; j < 4; ++j) acc[i][j] = fmaf(a[i], bv[j], acc[i][j]);
        }
    }
    #pragma unroll
    for (int i = 0; i < 4; ++i)
        #pragma unroll
        for (int j = 0; j < 4; ++j) {
            const float s = acc[i][j] * 0.0625f;
            const int rr = n0 + ty*4 + i, cc = mm0 + tx*4 + j;
            Z0 [(size_t)b * ZBAT + (size_t)rr * ZCOL + cc] = s;
            Z0T[(size_t)b * ZBAT + (size_t)cc * ZROW + rr] = s;
        }
}

// ---------------- sinkhorn ------------------------------------------------
__global__ void sink_init_kernel(float* __restrict__ Z0, float* __restrict__ Z0T,
                                 float* __restrict__ v, const float* __restrict__ binp)
{
    const float alpha = binp[0];
    const int idx = blockIdx.x * 256 + threadIdx.x;
    if (idx < 4 * ZCOL) v[idx] = 0.f;
    if (idx < 4 * 1281) {
        const int b = idx / 1281, e = idx % 1281;
        if (e < 1025) Z0[(size_t)b * ZBAT + 256 * ZCOL + e] = alpha;
        else          Z0[(size_t)b * ZBAT + (size_t)(e - 1025) * ZCOL + 1024] = alpha;
    }
    if (idx < 4 * 1282) {
        const int b = idx / 1282, e = idx % 1282;
        if (e < 257) Z0T[(size_t)b * ZBAT + 1024 * ZROW + e] = alpha;
        else         Z0T[(size_t)b * ZBAT + (size_t)(e - 257) * ZROW + 256] = alpha;
    }
}

__global__ __launch_bounds__(256) void sink_u_kernel(
    const float* __restrict__ Z0, const float* __restrict__ v, float* __restrict__ u)
{
    const int w = threadIdx.x >> 6, lane = threadIdx.x & 63;
    const int row = blockIdx.x * 4 + w;          // 0..1027
    const int b = row / 257, i = row % 257;
    const float* z  = Z0 + (size_t)b * ZBAT + (size_t)i * ZCOL;
    const float* vb = v + b * ZCOL;
    float zz[17];
    float mx = -INFINITY;
    #pragma unroll
    for (int k = 0; k < 16; ++k) {
        zz[k] = z[lane + k*64] + vb[lane + k*64];
        mx = fmaxf(mx, zz[k]);
    }
    zz[16] = (lane == 0) ? (z[1024] + vb[1024]) : -INFINITY;
    mx = fmaxf(mx, zz[16]);
    #pragma unroll
    for (int off = 32; off; off >>= 1) mx = fmaxf(mx, __shfl_xor(mx, off));
    float s = 0.f;
    #pragma unroll
    for (int k = 0; k < 17; ++k) s += expf(zz[k] - mx);
    #pragma unroll
    for (int off = 32; off; off >>= 1) s += __shfl_xor(s, off);
    if (lane == 0) {
        const float lmu = (i < 256) ? NORM_C : (LOG_NS + NORM_C);
        u[b * 257 + i] = lmu - (mx + logf(s));
    }
}

__global__ __launch_bounds__(256) void sink_v_kernel(
    const float* __restrict__ Z0T, const float* __restrict__ u, float* __restrict__ v)
{
    const int w = threadIdx.x >> 6, lane = threadIdx.x & 63;
    const int row = blockIdx.x * 4 + w;          // 0..4099
    const int b = row / 1025, j = row - b * 1025;
    const float* z  = Z0T + (size_t)b * ZBAT + (size_t)j * ZROW;
    const float* ub = u + b * 257;
    float zz[5];
    float mx = -INFINITY;
    #pragma unroll
    for (int k = 0; k < 4; ++k) {
        zz[k] = z[lane + k*64] + ub[lane + k*64];
        mx = fmaxf(mx, zz[k]);
    }
    zz[4] = (lane == 0) ? (z[256] + ub[256]) : -INFINITY;
    mx = fmaxf(mx, zz[4]);
    #pragma unroll
    for (int off = 32; off; off >>= 1) mx = fmaxf(mx, __shfl_xor(mx, off));
    float s = 0.f;
    #pragma unroll
    for (int k = 0; k < 5; ++k) s += expf(zz[k] - mx);
    #pragma unroll
    for (int off = 32; off; off >>= 1) s += __shfl_xor(s, off);
    if (lane == 0) {
        const float lnu = (j < 1024) ? NORM_C : (LOG_MS + NORM_C);
        v[b * ZCOL + j] = lnu - (mx + logf(s));
    }
}

__global__ void sink_out_kernel(const float* __restrict__ Z0, const float* __restrict__ u,
                                const float* __restrict__ v, float* __restrict__ out)
{
    const int j = blockIdx.x * 256 + threadIdx.x;
    const int i = blockIdx.y, b = blockIdx.z;
    if (j < ZCOL) {
        const size_t idx = (size_t)b * ZBAT + (size_t)i * ZCOL + j;
        out[idx] = Z0[idx] + u[b * 257 + i] + v[b * ZCOL + j] + LOG_TOT;
    }
}

// ---------------------------------------------------------------------------
static inline void gemm(hipStream_t st, const float* W, const float* X0,
                        const float* X1, int C0, const float* bias,
                        const float* res, int Nr, float* out, int No,
                        int O, int C, int N, int relu)
{
    dim3 g(N / 128, O / 128);
    gemm_kernel<<<g, 256, 0, st>>>(W, X0, X1, bias, res, out, O, C, C0, N, Nr, No, relu);
}

static inline void gemm64(hipStream_t st, const float* W, const float* X0,
                          const float* X1, int C0, const float* bias,
                          const float* res, int Nr, float* out, int No,
                          int O, int C, int N, int relu)
{
    dim3 g(N / 128, O / 64);
    gemm64_kernel<<<g, 256, 0, st>>>(W, X0, X1, bias, res, out, O, C, C0, N, Nr, No, relu);
}

extern "C" void kernel_launch(void* const* d_in, const int* in_sizes, int n_in,
                              void* d_out, int out_size, void* d_ws, size_t ws_size,
                              hipStream_t stream)
{
    (void)in_sizes; (void)n_in; (void)out_size; (void)ws_size;
    const float* det_in = (const float*)d_in[0];
    const float* trk_in = (const float*)d_in[1];
    const float* enc_w1 = (const float*)d_in[2];
    const float* enc_b1 = (const float*)d_in[3];
    const float* enc_w2 = (const float*)d_in[4];
    const float* enc_b2 = (const float*)d_in[5];
    const float* fus_pw = (const float*)d_in[6];
    const float* fus_pb = (const float*)d_in[7];
    const float* fus_mw = (const float*)d_in[8];
    const float* fus_mb = (const float*)d_in[9];
    const float* fus_m1w = (const float*)d_in[10];
    const float* fus_m1b = (const float*)d_in[11];
    const float* fus_m2w = (const float*)d_in[12];
    const float* fus_m2b = (const float*)d_in[13];
    const float* gnn_pw = (const float*)d_in[14];
    const float* gnn_pb = (const float*)d_in[15];
    const float* gnn_mw = (const float*)d_in[16];
    const float* gnn_mb = (const float*)d_in[17];
    const float* gnn_m1w = (const float*)d_in[18];
    const float* gnn_m1b = (const float*)d_in[19];
    const float* gnn_m2w = (const float*)d_in[20];
    const float* gnn_m2b = (const float*)d_in[21];
    const float* final_w = (const float*)d_in[22];
    const float* final_b = (const float*)d_in[23];
    const float* bin_sc  = (const float*)d_in[24];
    float* out = (float*)d_out;

    float* ws = (float*)d_ws;
    float* XF   = ws;                      // 4,194,304  fuser state x [256][16384]
    float* R    = ws + 4194304;            // 16,777,216 temp arena
    float* COMB = ws + 20971520;           // 1,310,720  [256][5120] tr|det state
    float* Z0   = ws + 22282240;           // 1,053,700
    float* U    = ws + 23335940;           //     1,028
    float* V    = ws + 23336968;           //     4,100
    float* Qf = R;
    float* Kf = R + 4194304;
    float* Vf = R + 8388608;
    float* MS = R + 12582912;
    float* QKV = R;                       // [768][5120]
    float* H   = R + 1310720;             // [512][5120]
    float* MSG = R + 3932160;             // [256][5120]
    float* M   = R + 5242880;             // [256][5120]
    const float* Qt = QKV;
    const float* Kt = QKV + (size_t)256 * NCB;
    const float* Vt = QKV + (size_t)512 * NCB;
    const float* Qd = Qt + 1024;
    const float* Kd = Kt + 1024;
    const float* Vd = Vt + 1024;
    float* Z0T = R;                       // 1,053,700  [4][1025][257]

    // ================= encoder (tracks) + fuser ===========================
    pe_kernel<<<NCT/256, 256, 0, stream>>>(trk_in, MS, NCT, 4, 257*16);
    repack_kernel<<<dim3(NCT/256, 256), 256, 0, stream>>>(trk_in, Qf, NCT, 4, 257*16);
    gemm(stream, enc_w1, Qf, Qf, 256, enc_b1, nullptr, 0, Kf, NCT, 256, 256, NCT, 1);
    gemm(stream, enc_w2, Kf, Kf, 256, enc_b2, MS, NCT, XF, NCT, 256, 256, NCT, 0);

    for (int l = 0; l < 4; ++l) {
        gemm(stream, fus_pw + l*196608, XF, XF, 256, fus_pb + l*768,
             nullptr, 0, Qf, NCT, 768, 256, NCT, 0);
        fuser_attn_kernel<<<1024, 256, 0, stream>>>(Qf, Kf, Vf, MS);
        gemm(stream, fus_mw + l*65536, MS, MS, 256, fus_mb + l*256,
             nullptr, 0, Qf, NCT, 256, 256, NCT, 0);               // M -> Qf
        gemm(stream, fus_m1w + l*262144, XF, Qf, 256, fus_m1b + l*512,
             nullptr, 0, Kf, NCT, 512, 512, NCT, 1);               // H -> Kf..Vf
        gemm(stream, fus_m2w + l*131072, Kf, Kf, 512, fus_m2b + l*256,
             XF, NCT, XF, NCT, 256, 512, NCT, 0);                  // x += ...
    }
    meanpool_kernel<<<dim3(4, 256), 256, 0, stream>>>(XF, COMB);   // tr cols [0,1024)

    // ================= encoder (detections) -> COMB cols [1024,5120) ======
    pe_kernel<<<NCD/256, 256, 0, stream>>>(det_in, MS, NCD, 10, 257*1024);
    repack_kernel<<<dim3(NCD/256, 256), 256, 0, stream>>>(det_in, Qf, NCD, 10, 257*1024);
    gemm64(stream, enc_w1, Qf, Qf, 256, enc_b1, nullptr, 0, Kf, NCD, 256, 256, NCD, 1);
    gemm64(stream, enc_w2, Kf, Kf, 256, enc_b2, MS, NCD, COMB + 1024, NCB, 256, 256, NCD, 0);

    // ================= GNN (combined tr|det, N=5120) ======================
    for (int l = 0; l < 12; ++l) {
        const float* pw  = gnn_pw + l*196608;
        const float* pb  = gnn_pb + l*768;
        const float* mw  = gnn_mw + l*65536;
        const float* mb  = gnn_mb + l*256;
        const float* m1w = gnn_m1w + l*262144;
        const float* m1b = gnn_m1b + l*512;
        const float* m2w = gnn_m2w + l*131072;
        const float* m2b = gnn_m2b + l*256;
        const bool cross = (l & 1);

        gemm64(stream, pw, COMB, COMB, 256, pb, nullptr, 0, QKV, NCB, 768, 256, NCB, 0);

        attn_kernel<<<dim3(4, 4, 4), 256, 0, stream>>>(
            Qt, cross ? Kd : Kt, cross ? Vd : Vt, MSG,
            256, cross ? 1024 : 256, NCB, NCB);
        attn_kernel<<<dim3(16, 4, 4), 256, 0, stream>>>(
            Qd, cross ? Kt : Kd, cross ? Vt : Vd, MSG + 1024,
            1024, cross ? 256 : 1024, NCB, NCB);

        gemm64(stream, mw, MSG, MSG, 256, mb, nullptr, 0, M, NCB, 256, 256, NCB, 0);
        gemm64(stream, m1w, COMB, M, 256, m1b, nullptr, 0, H, NCB, 512, 512, NCB, 1);
        gemm64(stream, m2w, H, H, 512, m2b, COMB, NCB, COMB, NCB, 256, 512, NCB, 0);
    }

    // ================= final projection + scores + sinkhorn ===============
    gemm64(stream, final_w, COMB, COMB, 256, final_b, nullptr, 0, M, NCB, 256, 256, NCB, 0);
    scores_kernel<<<dim3(16, 4, 4), 256, 0, stream>>>(M, Z0, Z0T);
    sink_init_kernel<<<21, 256, 0, stream>>>(Z0, Z0T, V, bin_sc);
    for (int it = 0; it < 100; ++it) {
        sink_u_kernel<<<257, 256, 0, stream>>>(Z0, V, U);
        sink_v_kernel<<<1025, 256, 0, stream>>>(Z0T, U, V);
    }
    sink_out_kernel<<<dim3(5, 257, 4), 256, 0, stream>>>(Z0, U, V, out);
}

// Round 7
// 3412.436 us; speedup vs baseline: 2.0714x; 1.0855x over previous
//
#include <hip/hip_runtime.h>
#include <math.h>

// ---------------------------------------------------------------------------
// Associator forward. GEMMs + GNN attention: split-fp16 (hi+lo) MFMA, fp32 acc.
// Layouts: activations are [C][Ncols] row-major fp32.
//   trk cols: 16384 (track*16+t); GNN combined cols: 5120 = [tr: b*256+n | 1024 + det: b*1024+m]
// msg-projection GEMM folded into MLP GEMM via precomputed Wf = m1wB@mw,
// bc = m1wB@mb + m1b (GEMMs have dual-source A AND B sides).
// Sinkhorn: 200 graph-replayed micro-launches (cheaper than device-scope
// grid barriers on gfx950: barrier ~7µs vs launch gap ~2-3µs).
// ---------------------------------------------------------------------------

#define NCT 16384
#define NCD 4096
#define NCB 5120
#define ZROW 257
#define ZCOL 1025
#define ZBAT (ZROW*ZCOL)   // 263425

#define NORM_C  (-7.1546153569f)   // -log(1280)
#define LOG_NS  (6.9314718056f)    // log(1024)
#define LOG_MS  (5.5451774445f)    // log(256)
#define LOG_TOT (7.1546153569f)    // +log(1280)

typedef _Float16 f16x8 __attribute__((ext_vector_type(8)));
typedef _Float16 f16x4 __attribute__((ext_vector_type(4)));
typedef float f32x4 __attribute__((ext_vector_type(4)));

#define APAD 40   // LDS row stride in halves (80 B: 16B-aligned rows)

// ---------------- GEMM 128x128: out = [W0|W1] @ [X0;X1] + bias (+res) -----
// A-side k<C0 from W0 (stride S0), k>=C0 from W1 (stride S1). 16-wide A
// chunks never straddle C0 (C0%32==0). B-side as before.
__global__ __launch_bounds__(256) void gemm_kernel(
    const float* __restrict__ W0, const float* __restrict__ W1, int S0, int S1,
    const float* __restrict__ X0, const float* __restrict__ X1,
    const float* __restrict__ bias, const float* __restrict__ res,
    float* __restrict__ out,
    int O, int C, int C0, int N, int Nr, int No, int relu)
{
    __shared__ _Float16 Ah[128][APAD], Al[128][APAD];
    __shared__ _Float16 Bh[128][APAD], Bl[128][APAD];
    const int tid = threadIdx.x;
    const int n0 = blockIdx.x * 128, m0 = blockIdx.y * 128;
    const int wave = tid >> 6, lane = tid & 63;
    const int wo = (wave >> 1) * 64, wn = (wave & 1) * 64;
    const int lm = lane & 15, lq = lane >> 4;
    const int ar = tid >> 1, akh = (tid & 1) << 4;
    const int bkg = tid & 7, bng = tid >> 3;

    f32x4 acc[4][4] = {};

    for (int kb = 0; kb < C; kb += 32) {
        float4 av[4];
        const int kcol = kb + akh;
        const float* wp = (kcol < C0) ? W0 + (size_t)(m0 + ar) * S0 + kcol
                                      : W1 + (size_t)(m0 + ar) * S1 + (kcol - C0);
        #pragma unroll
        for (int q = 0; q < 4; ++q) av[q] = *(const float4*)(wp + 4 * q);
        float4 xv[4];
        #pragma unroll
        for (int r = 0; r < 4; ++r) {
            const int krow = kb + bkg * 4 + r;
            const float* xs = (krow < C0) ? X0 + (size_t)krow * N
                                          : X1 + (size_t)(krow - C0) * N;
            xv[r] = *(const float4*)(xs + n0 + bng * 4);
        }
        __syncthreads();
        {
            _Float16 hbuf[16], lbuf[16];
            #pragma unroll
            for (int q = 0; q < 4; ++q) {
                const float* f = (const float*)&av[q];
                #pragma unroll
                for (int c = 0; c < 4; ++c) {
                    const float x = f[c];
                    const _Float16 h = (_Float16)x;
                    hbuf[q * 4 + c] = h;
                    lbuf[q * 4 + c] = (_Float16)(x - (float)h);
                }
            }
            *(f16x8*)&Ah[ar][akh]     = *(const f16x8*)&hbuf[0];
            *(f16x8*)&Ah[ar][akh + 8] = *(const f16x8*)&hbuf[8];
            *(f16x8*)&Al[ar][akh]     = *(const f16x8*)&lbuf[0];
            *(f16x8*)&Al[ar][akh + 8] = *(const f16x8*)&lbuf[8];
        }
        #pragma unroll
        for (int j = 0; j < 4; ++j) {
            _Float16 hb[4], lb[4];
            #pragma unroll
            for (int r = 0; r < 4; ++r) {
                const float x = ((const float*)&xv[r])[j];
                const _Float16 h = (_Float16)x;
                hb[r] = h;
                lb[r] = (_Float16)(x - (float)h);
            }
            *(f16x4*)&Bh[bng * 4 + j][bkg * 4] = *(const f16x4*)&hb[0];
            *(f16x4*)&Bl[bng * 4 + j][bkg * 4] = *(const f16x4*)&lb[0];
        }
        __syncthreads();
        f16x8 bh[4], bl[4];
        #pragma unroll
        for (int t = 0; t < 4; ++t) {
            bh[t] = *(const f16x8*)&Bh[wn + t * 16 + lm][lq * 8];
            bl[t] = *(const f16x8*)&Bl[wn + t * 16 + lm][lq * 8];
        }
        #pragma unroll
        for (int mt = 0; mt < 4; ++mt) {
            const f16x8 ah = *(const f16x8*)&Ah[wo + mt * 16 + lm][lq * 8];
            const f16x8 al = *(const f16x8*)&Al[wo + mt * 16 + lm][lq * 8];
            #pragma unroll
            for (int nt = 0; nt < 4; ++nt) {
                acc[mt][nt] = __builtin_amdgcn_mfma_f32_16x16x32_f16(ah, bh[nt], acc[mt][nt], 0, 0, 0);
                acc[mt][nt] = __builtin_amdgcn_mfma_f32_16x16x32_f16(ah, bl[nt], acc[mt][nt], 0, 0, 0);
                acc[mt][nt] = __builtin_amdgcn_mfma_f32_16x16x32_f16(al, bh[nt], acc[mt][nt], 0, 0, 0);
            }
        }
    }
    #pragma unroll
    for (int mt = 0; mt < 4; ++mt) {
        #pragma unroll
        for (int rg = 0; rg < 4; ++rg) {
            const int o = m0 + wo + mt * 16 + lq * 4 + rg;
            const float bs = bias[o];
            #pragma unroll
            for (int nt = 0; nt < 4; ++nt) {
                const int n = n0 + wn + nt * 16 + lm;
                float v = acc[mt][nt][rg] + bs;
                if (res) v += res[(size_t)o * Nr + n];
                if (relu) v = fmaxf(v, 0.f);
                out[(size_t)o * No + n] = v;
            }
        }
    }
}

// ---------------- GEMM 64x128 tile (small grids: GNN/det/final) -----------
__global__ __launch_bounds__(256) void gemm64_kernel(
    const float* __restrict__ W0, const float* __restrict__ W1, int S0, int S1,
    const float* __restrict__ X0, const float* __restrict__ X1,
    const float* __restrict__ bias, const float* __restrict__ res,
    float* __restrict__ out,
    int O, int C, int C0, int N, int Nr, int No, int relu)
{
    __shared__ _Float16 Ah[64][APAD], Al[64][APAD];
    __shared__ _Float16 Bh[128][APAD], Bl[128][APAD];
    const int tid = threadIdx.x;
    const int n0 = blockIdx.x * 128, m0 = blockIdx.y * 64;
    const int wave = tid >> 6, lane = tid & 63;
    const int wo = (wave >> 1) * 32, wn = (wave & 1) * 64;
    const int lm = lane & 15, lq = lane >> 4;
    const int ar = tid >> 2, ak8 = (tid & 3) << 3;
    const int bkg = tid & 7, bng = tid >> 3;

    f32x4 acc[2][4] = {};

    for (int kb = 0; kb < C; kb += 32) {
        float4 av[2];
        const int kcol = kb + ak8;
        const float* wp = (kcol < C0) ? W0 + (size_t)(m0 + ar) * S0 + kcol
                                      : W1 + (size_t)(m0 + ar) * S1 + (kcol - C0);
        av[0] = *(const float4*)(wp);
        av[1] = *(const float4*)(wp + 4);
        float4 xv[4];
        #pragma unroll
        for (int r = 0; r < 4; ++r) {
            const int krow = kb + bkg * 4 + r;
            const float* xs = (krow < C0) ? X0 + (size_t)krow * N
                                          : X1 + (size_t)(krow - C0) * N;
            xv[r] = *(const float4*)(xs + n0 + bng * 4);
        }
        __syncthreads();
        {
            _Float16 hbuf[8], lbuf[8];
            #pragma unroll
            for (int q = 0; q < 2; ++q) {
                const float* f = (const float*)&av[q];
                #pragma unroll
                for (int c = 0; c < 4; ++c) {
                    const float x = f[c];
                    const _Float16 h = (_Float16)x;
                    hbuf[q * 4 + c] = h;
                    lbuf[q * 4 + c] = (_Float16)(x - (float)h);
                }
            }
            *(f16x8*)&Ah[ar][ak8] = *(const f16x8*)&hbuf[0];
            *(f16x8*)&Al[ar][ak8] = *(const f16x8*)&lbuf[0];
        }
        #pragma unroll
        for (int j = 0; j < 4; ++j) {
            _Float16 hb[4], lb[4];
            #pragma unroll
            for (int r = 0; r < 4; ++r) {
                const float x = ((const float*)&xv[r])[j];
                const _Float16 h = (_Float16)x;
                hb[r] = h;
                lb[r] = (_Float16)(x - (float)h);
            }
            *(f16x4*)&Bh[bng * 4 + j][bkg * 4] = *(const f16x4*)&hb[0];
            *(f16x4*)&Bl[bng * 4 + j][bkg * 4] = *(const f16x4*)&lb[0];
        }
        __syncthreads();
        f16x8 bh[4], bl[4];
        #pragma unroll
        for (int t = 0; t < 4; ++t) {
            bh[t] = *(const f16x8*)&Bh[wn + t * 16 + lm][lq * 8];
            bl[t] = *(const f16x8*)&Bl[wn + t * 16 + lm][lq * 8];
        }
        #pragma unroll
        for (int mt = 0; mt < 2; ++mt) {
            const f16x8 ah = *(const f16x8*)&Ah[wo + mt * 16 + lm][lq * 8];
            const f16x8 al = *(const f16x8*)&Al[wo + mt * 16 + lm][lq * 8];
            #pragma unroll
            for (int nt = 0; nt < 4; ++nt) {
                acc[mt][nt] = __builtin_amdgcn_mfma_f32_16x16x32_f16(ah, bh[nt], acc[mt][nt], 0, 0, 0);
                acc[mt][nt] = __builtin_amdgcn_mfma_f32_16x16x32_f16(ah, bl[nt], acc[mt][nt], 0, 0, 0);
                acc[mt][nt] = __builtin_amdgcn_mfma_f32_16x16x32_f16(al, bh[nt], acc[mt][nt], 0, 0, 0);
            }
        }
    }
    #pragma unroll
    for (int mt = 0; mt < 2; ++mt) {
        #pragma unroll
        for (int rg = 0; rg < 4; ++rg) {
            const int o = m0 + wo + mt * 16 + lq * 4 + rg;
            const float bs = bias[o];
            #pragma unroll
            for (int nt = 0; nt < 4; ++nt) {
                const int n = n0 + wn + nt * 16 + lm;
                float v = acc[mt][nt][rg] + bs;
                if (res) v += res[(size_t)o * Nr + n];
                if (relu) v = fmaxf(v, 0.f);
                out[(size_t)o * No + n] = v;
            }
        }
    }
}

// ---------------- batched Wf = m1wB @ mw  ([512][256] per layer) -----------
// grid (2, 8, nlayers). m1wB = m1w cols [256,512) (row stride 512).
__global__ __launch_bounds__(256) void fusew_kernel(
    const float* __restrict__ m1w_base, const float* __restrict__ mw_base,
    float* __restrict__ wf_base)
{
    const int z = blockIdx.z;
    const float* A = m1w_base + (size_t)z * 262144 + 256;
    const float* B = mw_base + (size_t)z * 65536;
    float* out = wf_base + (size_t)z * 131072;
    __shared__ _Float16 Ah[64][APAD], Al[64][APAD];
    __shared__ _Float16 Bh[128][APAD], Bl[128][APAD];
    const int tid = threadIdx.x;
    const int n0 = blockIdx.x * 128, m0 = blockIdx.y * 64;
    const int wave = tid >> 6, lane = tid & 63;
    const int wo = (wave >> 1) * 32, wn = (wave & 1) * 64;
    const int lm = lane & 15, lq = lane >> 4;
    const int ar = tid >> 2, ak8 = (tid & 3) << 3;
    const int bkg = tid & 7, bng = tid >> 3;

    f32x4 acc[2][4] = {};
    for (int kb = 0; kb < 256; kb += 32) {
        float4 av[2];
        const float* wp = A + (size_t)(m0 + ar) * 512 + kb + ak8;
        av[0] = *(const float4*)(wp);
        av[1] = *(const float4*)(wp + 4);
        float4 xv[4];
        #pragma unroll
        for (int r = 0; r < 4; ++r)
            xv[r] = *(const float4*)(B + (size_t)(kb + bkg * 4 + r) * 256 + n0 + bng * 4);
        __syncthreads();
        {
            _Float16 hbuf[8], lbuf[8];
            #pragma unroll
            for (int q = 0; q < 2; ++q) {
                const float* f = (const float*)&av[q];
                #pragma unroll
                for (int c = 0; c < 4; ++c) {
                    const float x = f[c];
                    const _Float16 h = (_Float16)x;
                    hbuf[q * 4 + c] = h;
                    lbuf[q * 4 + c] = (_Float16)(x - (float)h);
                }
            }
            *(f16x8*)&Ah[ar][ak8] = *(const f16x8*)&hbuf[0];
            *(f16x8*)&Al[ar][ak8] = *(const f16x8*)&lbuf[0];
        }
        #pragma unroll
        for (int j = 0; j < 4; ++j) {
            _Float16 hb[4], lb[4];
            #pragma unroll
            for (int r = 0; r < 4; ++r) {
                const float x = ((const float*)&xv[r])[j];
                const _Float16 h = (_Float16)x;
                hb[r] = h;
                lb[r] = (_Float16)(x - (float)h);
            }
            *(f16x4*)&Bh[bng * 4 + j][bkg * 4] = *(const f16x4*)&hb[0];
            *(f16x4*)&Bl[bng * 4 + j][bkg * 4] = *(const f16x4*)&lb[0];
        }
        __syncthreads();
        f16x8 bh[4], bl[4];
        #pragma unroll
        for (int t = 0; t < 4; ++t) {
            bh[t] = *(const f16x8*)&Bh[wn + t * 16 + lm][lq * 8];
            bl[t] = *(const f16x8*)&Bl[wn + t * 16 + lm][lq * 8];
        }
        #pragma unroll
        for (int mt = 0; mt < 2; ++mt) {
            const f16x8 ah = *(const f16x8*)&Ah[wo + mt * 16 + lm][lq * 8];
            const f16x8 al = *(const f16x8*)&Al[wo + mt * 16 + lm][lq * 8];
            #pragma unroll
            for (int nt = 0; nt < 4; ++nt) {
                acc[mt][nt] = __builtin_amdgcn_mfma_f32_16x16x32_f16(ah, bh[nt], acc[mt][nt], 0, 0, 0);
                acc[mt][nt] = __builtin_amdgcn_mfma_f32_16x16x32_f16(ah, bl[nt], acc[mt][nt], 0, 0, 0);
                acc[mt][nt] = __builtin_amdgcn_mfma_f32_16x16x32_f16(al, bh[nt], acc[mt][nt], 0, 0, 0);
            }
        }
    }
    #pragma unroll
    for (int mt = 0; mt < 2; ++mt)
        #pragma unroll
        for (int rg = 0; rg < 4; ++rg) {
            const int o = m0 + wo + mt * 16 + lq * 4 + rg;
            #pragma unroll
            for (int nt = 0; nt < 4; ++nt)
                out[(size_t)o * 256 + n0 + wn + nt * 16 + lm] = acc[mt][nt][rg];
        }
}

// ---------------- batched bc = m1wB @ mb + m1b -----------------------------
__global__ void fusebias_kernel(const float* __restrict__ m1w_base,
                                const float* __restrict__ mb_base,
                                const float* __restrict__ m1b_base,
                                float* __restrict__ bc_base)
{
    const int z = blockIdx.y;
    const int o = blockIdx.x * 256 + threadIdx.x;   // 0..511
    const float* A = m1w_base + (size_t)z * 262144 + (size_t)o * 512 + 256;
    const float* mb = mb_base + z * 256;
    float s = m1b_base[z * 512 + o];
    for (int c = 0; c < 256; ++c) s = fmaf(A[c], mb[c], s);
    bc_base[z * 512 + o] = s;
}

// ---------------- positional encoding (grid.y splits the 128 i's) ---------
__global__ void pe_kernel(const float* __restrict__ src, float* __restrict__ pe,
                          int N, int shift, int cstride)
{
    const int col = blockIdx.x * 256 + threadIdx.x;
    if (col >= N) return;
    const int seg = 1 << shift;
    const int i0 = blockIdx.y * 32;
    const float pos = src[(size_t)(col >> shift) * cstride + (col & (seg - 1))];
    #pragma unroll 4
    for (int i = i0; i < i0 + 32; ++i) {
        const float div = expf((float)i * -0.07195578415606394f); // -ln(10000)/128
        const float ang = pos * div;
        pe[(size_t)(2*i) * N + col]   = sinf(ang);
        pe[(size_t)(2*i+1) * N + col] = cosf(ang);
    }
}

// ---------------- input repack (drop channel 0) ---------------------------
__global__ void repack_kernel(const float* __restrict__ src, float* __restrict__ dst,
                              int N, int shift, int cstride)
{
    const int col = blockIdx.x * 256 + threadIdx.x;
    const int c = blockIdx.y;
    if (col >= N) return;
    const int seg = 1 << shift;
    dst[(size_t)c * N + col] =
        src[(size_t)(col >> shift) * cstride + (size_t)(c + 1) * seg + (col & (seg - 1))];
}

// ---------------- fuser self-attention over time (n=m=16 per track) -------
__global__ __launch_bounds__(256) void fuser_attn_kernel(
    const float* __restrict__ Qb, const float* __restrict__ Kb,
    const float* __restrict__ Vb, float* __restrict__ Ob)
{
    __shared__ float qs[256][17], ks[256][17], vs[256][17];
    __shared__ float ps[4][16][17];
    const int trk = blockIdx.x, tid = threadIdx.x;
    const int col0 = trk * 16;
    for (int idx = tid; idx < 1024; idx += 256) {
        const int r = idx >> 2, seg = (idx & 3) << 2;
        const float4 q = *(const float4*)&Qb[(size_t)r * NCT + col0 + seg];
        const float4 k = *(const float4*)&Kb[(size_t)r * NCT + col0 + seg];
        const float4 v = *(const float4*)&Vb[(size_t)r * NCT + col0 + seg];
        qs[r][seg]=q.x; qs[r][seg+1]=q.y; qs[r][seg+2]=q.z; qs[r][seg+3]=q.w;
        ks[r][seg]=k.x; ks[r][seg+1]=k.y; ks[r][seg+2]=k.z; ks[r][seg+3]=k.w;
        vs[r][seg]=v.x; vs[r][seg+1]=v.y; vs[r][seg+2]=v.z; vs[r][seg+3]=v.w;
    }
    __syncthreads();
    {
        const int g = tid >> 2, h = g >> 4, n = g & 15, mb = (tid & 3) << 2;
        float s[4] = {};
        #pragma unroll 4
        for (int hd = 0; hd < 64; ++hd) {
            const int c = hd*4 + h;
            const float q = qs[c][n];
            #pragma unroll
            for (int j = 0; j < 4; ++j) s[j] = fmaf(q, ks[c][mb + j], s[j]);
        }
        #pragma unroll
        for (int j = 0; j < 4; ++j) ps[h][n][mb + j] = s[j] * 0.125f;
    }
    __syncthreads();
    if (tid < 64) {
        const int hh = tid >> 4, nn = tid & 15;
        float mx = -INFINITY;
        for (int m = 0; m < 16; ++m) mx = fmaxf(mx, ps[hh][nn][m]);
        float sum = 0.f;
        for (int m = 0; m < 16; ++m) { const float p = expf(ps[hh][nn][m] - mx);
                                       ps[hh][nn][m] = p; sum += p; }
        const float inv = 1.f / sum;
        for (int m = 0; m < 16; ++m) ps[hh][nn][m] *= inv;
    }
    __syncthreads();
    {
        const int c = tid, hc = c & 3;
        float msg[16];
        #pragma unroll
        for (int n = 0; n < 16; ++n) {
            float a = 0.f;
            #pragma unroll
            for (int m = 0; m < 16; ++m) a = fmaf(ps[hc][n][m], vs[c][m], a);
            msg[n] = a;
        }
        __syncthreads();
        #pragma unroll
        for (int n = 0; n < 16; ++n) qs[c][n] = msg[n];
    }
    __syncthreads();
    for (int idx = tid; idx < 1024; idx += 256) {
        const int r = idx >> 2, seg = (idx & 3) << 2;
        *(float4*)&Ob[(size_t)r * NCT + col0 + seg] =
            make_float4(qs[r][seg], qs[r][seg+1], qs[r][seg+2], qs[r][seg+3]);
    }
}

// ---------------- GNN attention (merged tr+det): split-fp16 MFMA flash -----
// grid (20, H=4, B=4): nt 0-3 tr-side, 4-19 det-side. Strides all NCB.
__global__ __launch_bounds__(256) void attn2_kernel(
    const float* __restrict__ QKV, float* __restrict__ MSG, int cross)
{
    __shared__ _Float16 Qh[64][72], Ql[64][72];   // [qpos][d]
    __shared__ _Float16 Kh[64][72], Kl[64][72];   // [kpos][d]; P after QK
    __shared__ _Float16 Vh[64][72], Vl[64][72];   // [d][mpos]
    const int b = blockIdx.z, h = blockIdx.y, nt = blockIdx.x;
    const float* Qb = QKV;
    const float* Kb = QKV + (size_t)256 * NCB;
    const float* Vb = QKV + (size_t)512 * NCB;
    int qcol, kbase, nk;
    if (nt < 4) {   // tr side
        qcol = b * 256 + nt * 64;
        if (cross) { kbase = 1024 + b * 1024; nk = 1024; }
        else       { kbase = b * 256;         nk = 256;  }
    } else {        // det side
        qcol = 1024 + b * 1024 + (nt - 4) * 64;
        if (cross) { kbase = b * 256;         nk = 256;  }
        else       { kbase = 1024 + b * 1024; nk = 1024; }
    }
    const int tid = threadIdx.x;
    const int wave = tid >> 6, lane = tid & 63;
    const int lm = lane & 15, quad = lane >> 4;
    const int dg = tid & 15, qg = tid >> 4;
    const int vd = tid >> 2, vseg = (tid & 3) * 16;

    {   // stage Q (transposed 4x4 micro-tiles)
        float4 xv[4];
        #pragma unroll
        for (int r = 0; r < 4; ++r) {
            const int chan = (dg * 4 + r) * 4 + h;
            xv[r] = *(const float4*)&Qb[(size_t)chan * NCB + qcol + qg * 4];
        }
        #pragma unroll
        for (int j = 0; j < 4; ++j) {
            _Float16 hb[4], lb[4];
            #pragma unroll
            for (int r = 0; r < 4; ++r) {
                const float x = ((const float*)&xv[r])[j];
                const _Float16 hh = (_Float16)x;
                hb[r] = hh; lb[r] = (_Float16)(x - (float)hh);
            }
            *(f16x4*)&Qh[qg * 4 + j][dg * 4] = *(const f16x4*)hb;
            *(f16x4*)&Ql[qg * 4 + j][dg * 4] = *(const f16x4*)lb;
        }
    }
    __syncthreads();
    f16x8 qh[2], ql[2];
    #pragma unroll
    for (int ks = 0; ks < 2; ++ks) {
        qh[ks] = *(const f16x8*)&Qh[wave * 16 + lm][ks * 32 + quad * 8];
        ql[ks] = *(const f16x8*)&Ql[wave * 16 + lm][ks * 32 + quad * 8];
    }

    float rmax[4], rsum[4];
    #pragma unroll
    for (int r = 0; r < 4; ++r) { rmax[r] = -INFINITY; rsum[r] = 0.f; }
    f32x4 acco[4] = {};

    const int mtiles = nk >> 6;
    for (int mt = 0; mt < mtiles; ++mt) {
        const int kcol = kbase + mt * 64;
        __syncthreads();
        {   // stage K (transposed) + V (direct)
            float4 xv[4];
            #pragma unroll
            for (int r = 0; r < 4; ++r) {
                const int chan = (dg * 4 + r) * 4 + h;
                xv[r] = *(const float4*)&Kb[(size_t)chan * NCB + kcol + qg * 4];
            }
            #pragma unroll
            for (int j = 0; j < 4; ++j) {
                _Float16 hb[4], lb[4];
                #pragma unroll
                for (int r = 0; r < 4; ++r) {
                    const float x = ((const float*)&xv[r])[j];
                    const _Float16 hh = (_Float16)x;
                    hb[r] = hh; lb[r] = (_Float16)(x - (float)hh);
                }
                *(f16x4*)&Kh[qg * 4 + j][dg * 4] = *(const f16x4*)hb;
                *(f16x4*)&Kl[qg * 4 + j][dg * 4] = *(const f16x4*)lb;
            }
            const int vchan = vd * 4 + h;
            float4 v4[4];
            #pragma unroll
            for (int q = 0; q < 4; ++q)
                v4[q] = *(const float4*)&Vb[(size_t)vchan * NCB + kcol + vseg + q * 4];
            _Float16 vh16[16], vl16[16];
            #pragma unroll
            for (int q = 0; q < 4; ++q) {
                const float* f = (const float*)&v4[q];
                #pragma unroll
                for (int c = 0; c < 4; ++c) {
                    const float x = f[c];
                    const _Float16 hh = (_Float16)x;
                    vh16[q*4+c] = hh; vl16[q*4+c] = (_Float16)(x - (float)hh);
                }
            }
            *(f16x8*)&Vh[vd][vseg]     = *(const f16x8*)&vh16[0];
            *(f16x8*)&Vh[vd][vseg + 8] = *(const f16x8*)&vh16[8];
            *(f16x8*)&Vl[vd][vseg]     = *(const f16x8*)&vl16[0];
            *(f16x8*)&Vl[vd][vseg + 8] = *(const f16x8*)&vl16[8];
        }
        __syncthreads();
        f32x4 accs[4] = {};
        #pragma unroll
        for (int t = 0; t < 4; ++t) {
            #pragma unroll
            for (int ks = 0; ks < 2; ++ks) {
                const f16x8 kh = *(const f16x8*)&Kh[t * 16 + lm][ks * 32 + quad * 8];
                const f16x8 kl = *(const f16x8*)&Kl[t * 16 + lm][ks * 32 + quad * 8];
                accs[t] = __builtin_amdgcn_mfma_f32_16x16x32_f16(qh[ks], kh, accs[t], 0,0,0);
                accs[t] = __builtin_amdgcn_mfma_f32_16x16x32_f16(qh[ks], kl, accs[t], 0,0,0);
                accs[t] = __builtin_amdgcn_mfma_f32_16x16x32_f16(ql[ks], kh, accs[t], 0,0,0);
            }
        }
        float alpha[4];
        float psv[4][4];
        #pragma unroll
        for (int r = 0; r < 4; ++r) {
            float mx = fmaxf(fmaxf(accs[0][r], accs[1][r]),
                             fmaxf(accs[2][r], accs[3][r])) * 0.125f;
            #pragma unroll
            for (int off = 1; off < 16; off <<= 1) mx = fmaxf(mx, __shfl_xor(mx, off));
            const float mnew = fmaxf(rmax[r], mx);
            alpha[r] = expf(rmax[r] - mnew);
            rmax[r] = mnew;
            float s = 0.f;
            #pragma unroll
            for (int t = 0; t < 4; ++t) {
                const float p = expf(accs[t][r] * 0.125f - mnew);
                psv[t][r] = p; s += p;
            }
            #pragma unroll
            for (int off = 1; off < 16; off <<= 1) s += __shfl_xor(s, off);
            rsum[r] = rsum[r] * alpha[r] + s;
        }
        __syncthreads();
        #pragma unroll
        for (int t = 0; t < 4; ++t)
            #pragma unroll
            for (int r = 0; r < 4; ++r) {
                const float x = psv[t][r];
                const _Float16 hh = (_Float16)x;
                Kh[wave * 16 + quad * 4 + r][t * 16 + lm] = hh;
                Kl[wave * 16 + quad * 4 + r][t * 16 + lm] = (_Float16)(x - (float)hh);
            }
        __syncthreads();
        #pragma unroll
        for (int td = 0; td < 4; ++td)
            #pragma unroll
            for (int r = 0; r < 4; ++r) acco[td][r] *= alpha[r];
        #pragma unroll
        for (int ks = 0; ks < 2; ++ks) {
            const f16x8 ph = *(const f16x8*)&Kh[wave * 16 + lm][ks * 32 + quad * 8];
            const f16x8 pl = *(const f16x8*)&Kl[wave * 16 + lm][ks * 32 + quad * 8];
            #pragma unroll
            for (int td = 0; td < 4; ++td) {
                const f16x8 vh = *(const f16x8*)&Vh[td * 16 + lm][ks * 32 + quad * 8];
                const f16x8 vl = *(const f16x8*)&Vl[td * 16 + lm][ks * 32 + quad * 8];
                acco[td] = __builtin_amdgcn_mfma_f32_16x16x32_f16(ph, vh, acco[td], 0,0,0);
                acco[td] = __builtin_amdgcn_mfma_f32_16x16x32_f16(ph, vl, acco[td], 0,0,0);
                acco[td] = __builtin_amdgcn_mfma_f32_16x16x32_f16(pl, vh, acco[td], 0,0,0);
            }
        }
    }
    float inv[4];
    #pragma unroll
    for (int r = 0; r < 4; ++r) inv[r] = 1.f / rsum[r];
    #pragma unroll
    for (int td = 0; td < 4; ++td)
        #pragma unroll
        for (int r = 0; r < 4; ++r) {
            const int chan = (td * 16 + lm) * 4 + h;
            const int qp = qcol + wave * 16 + quad * 4 + r;
            MSG[(size_t)chan * NCB + qp] = acco[td][r] * inv[r];
        }
}

// ---------------- mean pool over time (into combined cols [0,1024)) -------
__global__ void meanpool_kernel(const float* __restrict__ x, float* __restrict__ tr)
{
    const int trk = blockIdx.x * 256 + threadIdx.x;
    const int d = blockIdx.y;
    const float* p = x + (size_t)d * NCT + (size_t)trk * 16;
    float s = 0.f;
    #pragma unroll
    for (int t = 0; t < 16; ++t) s += p[t];
    tr[(size_t)d * NCB + trk] = s * 0.0625f;
}

// ---------------- scores = m0^T m1 / 16 into Z0 and Z0T -------------------
__global__ __launch_bounds__(256) void scores_kernel(
    const float* __restrict__ M, float* __restrict__ Z0, float* __restrict__ Z0T)
{
    __shared__ float As[8][68];
    __shared__ float Bs[8][68];
    const int bm = blockIdx.x, bn = blockIdx.y, b = blockIdx.z;
    const int tid = threadIdx.x;
    const int n0 = bn * 64, mm0 = bm * 64;
    const int tx = tid & 15, ty = tid >> 4;
    float acc[4][4] = {};
    for (int kb = 0; kb < 256; kb += 8) {
        __syncthreads();
        for (int idx = tid; idx < 512; idx += 256) {
            const int r = idx >> 6, cc = idx & 63;
            As[r][cc] = M[(size_t)(kb + r) * NCB + b * 256 + n0 + cc];
            Bs[r][cc] = M[(size_t)(kb + r) * NCB + 1024 + b * 1024 + mm0 + cc];
        }
        __syncthreads();
        #pragma unroll
        for (int kk = 0; kk < 8; ++kk) {
            float a[4], bv[4];
            #pragma unroll
            for (int i = 0; i < 4; ++i) { a[i] = As[kk][ty*4 + i]; bv[i] = Bs[kk][tx*4 + i]; }
            #pragma unroll
            for (int i = 0; i < 4; ++i)
                #pragma unroll
                for (int j = 0; j < 4; ++j) acc[i][j] = fmaf(a[i], bv[j], acc[i][j]);
        }
    }
    #pragma unroll
    for (int i = 0; i < 4; ++i)
        #pragma unroll
        for (int j = 0; j < 4; ++j) {
            const float s = acc[i][j] * 0.0625f;
            const int rr = n0 + ty*4 + i, cc = mm0 + tx*4 + j;
            Z0 [(size_t)b * ZBAT + (size_t)rr * ZCOL + cc] = s;
            Z0T[(size_t)b * ZBAT + (size_t)cc * ZROW + rr] = s;
        }
}

// ---------------- sinkhorn ------------------------------------------------
__global__ void sink_init_kernel(float* __restrict__ Z0, float* __restrict__ Z0T,
                                 float* __restrict__ v, const float* __restrict__ binp)
{
    const float alpha = binp[0];
    const int idx = blockIdx.x * 256 + threadIdx.x;
    if (idx < 4 * ZCOL) v[idx] = 0.f;
    if (idx < 4 * 1281) {
        const int b = idx / 1281, e = idx % 1281;
        if (e < 1025) Z0[(size_t)b * ZBAT + 256 * ZCOL + e] = alpha;
        else          Z0[(size_t)b * ZBAT + (size_t)(e - 1025) * ZCOL + 1024] = alpha;
    }
    if (idx < 4 * 1282) {
        const int b = idx / 1282, e = idx % 1282;
        if (e < 257) Z0T[(size_t)b * ZBAT + 1024 * ZROW + e] = alpha;
        else         Z0T[(size_t)b * ZBAT + (size_t)(e - 257) * ZROW + 256] = alpha;
    }
}

__global__ __launch_bounds__(256) void sink_u_kernel(
    const float* __restrict__ Z0, const float* __restrict__ v, float* __restrict__ u)
{
    const int w = threadIdx.x >> 6, lane = threadIdx.x & 63;
    const int row = blockIdx.x * 4 + w;          // 0..1027
    const int b = row / 257, i = row % 257;
    const float* z  = Z0 + (size_t)b * ZBAT + (size_t)i * ZCOL;
    const float* vb = v + b * ZCOL;
    float zz[17];
    float mx = -INFINITY;
    #pragma unroll
    for (int k = 0; k < 16; ++k) {
        zz[k] = z[lane + k*64] + vb[lane + k*64];
        mx = fmaxf(mx, zz[k]);
    }
    zz[16] = (lane == 0) ? (z[1024] + vb[1024]) : -INFINITY;
    mx = fmaxf(mx, zz[16]);
    #pragma unroll
    for (int off = 32; off; off >>= 1) mx = fmaxf(mx, __shfl_xor(mx, off));
    float s = 0.f;
    #pragma unroll
    for (int k = 0; k < 17; ++k) s += expf(zz[k] - mx);
    #pragma unroll
    for (int off = 32; off; off >>= 1) s += __shfl_xor(s, off);
    if (lane == 0) {
        const float lmu = (i < 256) ? NORM_C : (LOG_NS + NORM_C);
        u[b * 257 + i] = lmu - (mx + logf(s));
    }
}

__global__ __launch_bounds__(256) void sink_v_kernel(
    const float* __restrict__ Z0T, const float* __restrict__ u, float* __restrict__ v)
{
    const int w = threadIdx.x >> 6, lane = threadIdx.x & 63;
    const int row = blockIdx.x * 4 + w;          // 0..4099
    const int b = row / 1025, j = row - b * 1025;
    const float* z  = Z0T + (size_t)b * ZBAT + (size_t)j * ZROW;
    const float* ub = u + b * 257;
    float zz[5];
    float mx = -INFINITY;
    #pragma unroll
    for (int k = 0; k < 4; ++k) {
        zz[k] = z[lane + k*64] + ub[lane + k*64];
        mx = fmaxf(mx, zz[k]);
    }
    zz[4] = (lane == 0) ? (z[256] + ub[256]) : -INFINITY;
    mx = fmaxf(mx, zz[4]);
    #pragma unroll
    for (int off = 32; off; off >>= 1) mx = fmaxf(mx, __shfl_xor(mx, off));
    float s = 0.f;
    #pragma unroll
    for (int k = 0; k < 5; ++k) s += expf(zz[k] - mx);
    #pragma unroll
    for (int off = 32; off; off >>= 1) s += __shfl_xor(s, off);
    if (lane == 0) {
        const float lnu = (j < 1024) ? NORM_C : (LOG_MS + NORM_C);
        v[b * ZCOL + j] = lnu - (mx + logf(s));
    }
}

__global__ void sink_out_kernel(const float* __restrict__ Z0, const float* __restrict__ u,
                                const float* __restrict__ v, float* __restrict__ out)
{
    const int j = blockIdx.x * 256 + threadIdx.x;
    const int i = blockIdx.y, b = blockIdx.z;
    if (j < ZCOL) {
        const size_t idx = (size_t)b * ZBAT + (size_t)i * ZCOL + j;
        out[idx] = Z0[idx] + u[b * 257 + i] + v[b * ZCOL + j] + LOG_TOT;
    }
}

// ---------------------------------------------------------------------------
static inline void gemm(hipStream_t st, const float* W, const float* X0,
                        const float* X1, int C0, const float* bias,
                        const float* res, int Nr, float* out, int No,
                        int O, int C, int N, int relu,
                        const float* W1 = nullptr, int S1 = 0)
{
    if (!W1) { W1 = W + C0; S1 = C; }
    dim3 g(N / 128, O / 128);
    gemm_kernel<<<g, 256, 0, st>>>(W, W1, C, S1, X0, X1, bias, res, out, O, C, C0, N, Nr, No, relu);
}

static inline void gemm64(hipStream_t st, const float* W, const float* X0,
                          const float* X1, int C0, const float* bias,
                          const float* res, int Nr, float* out, int No,
                          int O, int C, int N, int relu,
                          const float* W1 = nullptr, int S1 = 0)
{
    if (!W1) { W1 = W + C0; S1 = C; }
    dim3 g(N / 128, O / 64);
    gemm64_kernel<<<g, 256, 0, st>>>(W, W1, C, S1, X0, X1, bias, res, out, O, C, C0, N, Nr, No, relu);
}

extern "C" void kernel_launch(void* const* d_in, const int* in_sizes, int n_in,
                              void* d_out, int out_size, void* d_ws, size_t ws_size,
                              hipStream_t stream)
{
    (void)in_sizes; (void)n_in; (void)out_size; (void)ws_size;
    const float* det_in = (const float*)d_in[0];
    const float* trk_in = (const float*)d_in[1];
    const float* enc_w1 = (const float*)d_in[2];
    const float* enc_b1 = (const float*)d_in[3];
    const float* enc_w2 = (const float*)d_in[4];
    const float* enc_b2 = (const float*)d_in[5];
    const float* fus_pw = (const float*)d_in[6];
    const float* fus_pb = (const float*)d_in[7];
    const float* fus_mw = (const float*)d_in[8];
    const float* fus_mb = (const float*)d_in[9];
    const float* fus_m1w = (const float*)d_in[10];
    const float* fus_m1b = (const float*)d_in[11];
    const float* fus_m2w = (const float*)d_in[12];
    const float* fus_m2b = (const float*)d_in[13];
    const float* gnn_pw = (const float*)d_in[14];
    const float* gnn_pb = (const float*)d_in[15];
    const float* gnn_mw = (const float*)d_in[16];
    const float* gnn_mb = (const float*)d_in[17];
    const float* gnn_m1w = (const float*)d_in[18];
    const float* gnn_m1b = (const float*)d_in[19];
    const float* gnn_m2w = (const float*)d_in[20];
    const float* gnn_m2b = (const float*)d_in[21];
    const float* final_w = (const float*)d_in[22];
    const float* final_b = (const float*)d_in[23];
    const float* bin_sc  = (const float*)d_in[24];
    float* out = (float*)d_out;

    float* ws = (float*)d_ws;
    float* XF   = ws;                      // 4,194,304  fuser state x [256][16384]
    float* R    = ws + 4194304;            // 16,777,216 temp arena
    float* COMB = ws + 20971520;           // 1,310,720  [256][5120] tr|det state
    float* Z0   = ws + 22282240;           // 1,053,700
    float* U    = ws + 23335940;           //     1,028
    float* V    = ws + 23336968;           //     4,100
    // fuser / det-enc arena:
    float* Qf = R;                        // 0 .. 4,194,304
    float* Kf = R + 4194304;              // .. 8,388,608
    float* Vf = R + 8388608;              // .. 12,582,912
    float* MS = R + 12582912;             // .. 16,777,216
    // GNN arena (N=5120): QKV 0..3.93M; H overlays K,V rows; MSG; M (final proj)
    float* QKV = R;                       // [768][5120]
    float* H   = R + 1310720;             // [512][5120]
    float* MSG = R + 3932160;             // [256][5120]
    float* M   = R + 5242880;             // [256][5120]
    // fused msg-proj weights:
    //   fuser: in COMB region (dead until meanpool)
    float* Wff = COMB;                    // [4][512][256] = 524,288
    float* bcf = COMB + 524288;           // [4][512] = 2,048
    //   GNN: in old-Vf region (free after fuser; untouched by det-enc & GNN)
    float* Wfg = R + 8388608;             // [12][512][256] = 1,572,864
    float* bcg = R + 10000000;            // [12][512] = 6,144
    float* Z0T = R;                       // sinkhorn transpose (end phase)

    // ===== fuser fused-weight precompute (before encoder; COMB is free) ===
    fusew_kernel<<<dim3(2, 8, 4), 256, 0, stream>>>(fus_m1w, fus_mw, Wff);
    fusebias_kernel<<<dim3(2, 4), 256, 0, stream>>>(fus_m1w, fus_mb, fus_m1b, bcf);

    // ================= encoder (tracks) + fuser ===========================
    pe_kernel<<<dim3(NCT/256, 4), 256, 0, stream>>>(trk_in, MS, NCT, 4, 257*16);
    repack_kernel<<<dim3(NCT/256, 256), 256, 0, stream>>>(trk_in, Qf, NCT, 4, 257*16);
    gemm(stream, enc_w1, Qf, Qf, 256, enc_b1, nullptr, 0, Kf, NCT, 256, 256, NCT, 1);
    gemm(stream, enc_w2, Kf, Kf, 256, enc_b2, MS, NCT, XF, NCT, 256, 256, NCT, 0);

    for (int l = 0; l < 4; ++l) {
        gemm(stream, fus_pw + l*196608, XF, XF, 256, fus_pb + l*768,
             nullptr, 0, Qf, NCT, 768, 256, NCT, 0);
        fuser_attn_kernel<<<1024, 256, 0, stream>>>(Qf, Kf, Vf, MS);
        // h = relu([m1wA | Wf] @ [x; attn_msg] + bc)  -> Kf..Vf
        gemm(stream, fus_m1w + l*262144, XF, MS, 256, bcf + l*512,
             nullptr, 0, Kf, NCT, 512, 512, NCT, 1, Wff + l*131072, 256);
        gemm(stream, fus_m2w + l*131072, Kf, Kf, 512, fus_m2b + l*256,
             XF, NCT, XF, NCT, 256, 512, NCT, 0);
    }

    // ===== GNN fused-weight precompute (old-Vf region now free) ===========
    fusew_kernel<<<dim3(2, 8, 12), 256, 0, stream>>>(gnn_m1w, gnn_mw, Wfg);
    fusebias_kernel<<<dim3(2, 12), 256, 0, stream>>>(gnn_m1w, gnn_mb, gnn_m1b, bcg);

    meanpool_kernel<<<dim3(4, 256), 256, 0, stream>>>(XF, COMB);   // tr cols [0,1024)

    // ================= encoder (detections) -> COMB cols [1024,5120) ======
    pe_kernel<<<dim3(NCD/256, 4), 256, 0, stream>>>(det_in, MS, NCD, 10, 257*1024);
    repack_kernel<<<dim3(NCD/256, 256), 256, 0, stream>>>(det_in, Qf, NCD, 10, 257*1024);
    gemm64(stream, enc_w1, Qf, Qf, 256, enc_b1, nullptr, 0, Kf, NCD, 256, 256, NCD, 1);
    gemm64(stream, enc_w2, Kf, Kf, 256, enc_b2, MS, NCD, COMB + 1024, NCB, 256, 256, NCD, 0);

    // ================= GNN (combined tr|det, N=5120) ======================
    for (int l = 0; l < 12; ++l) {
        const float* pw  = gnn_pw + l*196608;
        const float* pb  = gnn_pb + l*768;
        const float* m1w = gnn_m1w + l*262144;
        const float* m2w = gnn_m2w + l*131072;
        const float* m2b = gnn_m2b + l*256;
        const int cross = (l & 1);

        gemm64(stream, pw, COMB, COMB, 256, pb, nullptr, 0, QKV, NCB, 768, 256, NCB, 0);
        attn2_kernel<<<dim3(20, 4, 4), 256, 0, stream>>>(QKV, MSG, cross);
        gemm64(stream, m1w, COMB, MSG, 256, bcg + l*512,
               nullptr, 0, H, NCB, 512, 512, NCB, 1, Wfg + l*131072, 256);
        gemm64(stream, m2w, H, H, 512, m2b, COMB, NCB, COMB, NCB, 256, 512, NCB, 0);
    }

    // ================= final projection + scores + sinkhorn ===============
    gemm64(stream, final_w, COMB, COMB, 256, final_b, nullptr, 0, M, NCB, 256, 256, NCB, 0);
    scores_kernel<<<dim3(16, 4, 4), 256, 0, stream>>>(M, Z0, Z0T);
    sink_init_kernel<<<21, 256, 0, stream>>>(Z0, Z0T, V, bin_sc);
    for (int it = 0; it < 100; ++it) {
        sink_u_kernel<<<257, 256, 0, stream>>>(Z0, V, U);
        sink_v_kernel<<<1025, 256, 0, stream>>>(Z0T, U, V);
    }
    sink_out_kernel<<<dim3(5, 257, 4), 256, 0, stream>>>(Z0, U, V, out);
}

// Round 8
// 3411.362 us; speedup vs baseline: 2.0721x; 1.0003x over previous
//
#include <hip/hip_runtime.h>
#include <math.h>

// ---------------------------------------------------------------------------
// Associator forward. GEMMs + GNN attention: split-fp16 (hi+lo) MFMA, fp32 acc.
// Layouts: activations are [C][Ncols] row-major fp32.
//   trk cols: 16384 (track*16+t); GNN combined cols: 5120 = [tr: b*256+n | 1024 + det: b*1024+m]
// Fuser-path GEMMs (gemm_kernel): A-side = precomputed fp16 hi/lo weight
// planes staged via global_load_lds (16B DMA, no VGPR roundtrip / convert).
// GNN GEMMs (gemm64): launch-bound, keep fp32 A-side convert path.
// Sinkhorn: 200 graph-replayed micro-launches (cheaper than device-scope
// grid barriers on gfx950: barrier ~7µs vs launch gap ~2-3µs).
// ---------------------------------------------------------------------------

#define NCT 16384
#define NCD 4096
#define NCB 5120
#define ZROW 257
#define ZCOL 1025
#define ZBAT (ZROW*ZCOL)   // 263425

#define NORM_C  (-7.1546153569f)   // -log(1280)
#define LOG_NS  (6.9314718056f)    // log(1024)
#define LOG_MS  (5.5451774445f)    // log(256)
#define LOG_TOT (7.1546153569f)    // +log(1280)

typedef _Float16 f16x8 __attribute__((ext_vector_type(8)));
typedef _Float16 f16x4 __attribute__((ext_vector_type(4)));
typedef float f32x4 __attribute__((ext_vector_type(4)));

#define APAD 40   // LDS row stride in halves for B tiles (80 B)

// 16B global->LDS stage. DMA path: per-lane global addr g, wave-uniform LDS
// base; HW places lane i at base + 16i. Fallback reproduces the placement.
__device__ __forceinline__ void stage16(const _Float16* g, _Float16* ldsbase, int lane)
{
#if __has_builtin(__builtin_amdgcn_global_load_lds)
    __builtin_amdgcn_global_load_lds(
        (const __attribute__((address_space(1))) unsigned int*)(const void*)g,
        (__attribute__((address_space(3))) unsigned int*)(void*)ldsbase, 16, 0, 0);
#else
    *(f16x8*)(ldsbase + lane * 8) = *(const f16x8*)g;
#endif
}

// ---------------- GEMM 128x128 (fuser path, plane A-side) ------------------
// out = [W0|W1] @ [X0;X1] + bias (+res) (relu?). A-side from fp16 hi/lo
// planes: k<C0 from P*0 (stride S0 halves), k>=C0 from P*1 (stride S1).
// C0%32==0 so a 32-wide k-tile never straddles.
__global__ __launch_bounds__(256) void gemm_kernel(
    const _Float16* __restrict__ Ph0, const _Float16* __restrict__ Pl0, int S0,
    const _Float16* __restrict__ Ph1, const _Float16* __restrict__ Pl1, int S1,
    const float* __restrict__ X0, const float* __restrict__ X1,
    const float* __restrict__ bias, const float* __restrict__ res,
    float* __restrict__ out,
    int O, int C, int C0, int N, int Nr, int No, int relu)
{
    __shared__ _Float16 Ah[128][32], Al[128][32];
    __shared__ _Float16 Bh[128][APAD], Bl[128][APAD];
    const int tid = threadIdx.x;
    const int n0 = blockIdx.x * 128, m0 = blockIdx.y * 128;
    const int wave = tid >> 6, lane = tid & 63;
    const int wo = (wave >> 1) * 64, wn = (wave & 1) * 64;
    const int lm = lane & 15, lq = lane >> 4;
    const int sar = lane >> 2, sak = (lane & 3) * 8;   // A DMA: row-in-16, k-chunk
    const int bkg = tid & 7, bng = tid >> 3;

    f32x4 acc[4][4] = {};

    for (int kb = 0; kb < C; kb += 32) {
        // B-side fp32 global loads (VGPR; issued before barrier)
        float4 xv[4];
        #pragma unroll
        for (int r = 0; r < 4; ++r) {
            const int krow = kb + bkg * 4 + r;
            const float* xs = (krow < C0) ? X0 + (size_t)krow * N
                                          : X1 + (size_t)(krow - C0) * N;
            xv[r] = *(const float4*)(xs + n0 + bng * 4);
        }
        const bool s0 = (kb < C0);
        const _Float16* ph = s0 ? Ph0 : Ph1;
        const _Float16* pl = s0 ? Pl0 : Pl1;
        const int S = s0 ? S0 : S1;
        const int kc = s0 ? kb : kb - C0;
        __syncthreads();   // prior iteration's fragment reads complete
        // ---- A: 16B DMA of hi/lo planes (overlaps B convert below) ----
        #pragma unroll
        for (int inst = 0; inst < 2; ++inst) {
            const int r0 = wave * 32 + inst * 16;
            const size_t go = (size_t)(m0 + r0 + sar) * S + kc + sak;
            stage16(ph + go, &Ah[r0][0], lane);
            stage16(pl + go, &Al[r0][0], lane);
        }
        // ---- B: convert + transposed store (Bs[n][k], k contiguous) ----
        #pragma unroll
        for (int j = 0; j < 4; ++j) {
            _Float16 hb[4], lb[4];
            #pragma unroll
            for (int r = 0; r < 4; ++r) {
                const float x = ((const float*)&xv[r])[j];
                const _Float16 h = (_Float16)x;
                hb[r] = h;
                lb[r] = (_Float16)(x - (float)h);
            }
            *(f16x4*)&Bh[bng * 4 + j][bkg * 4] = *(const f16x4*)&hb[0];
            *(f16x4*)&Bl[bng * 4 + j][bkg * 4] = *(const f16x4*)&lb[0];
        }
        __syncthreads();   // drains DMA (vmcnt) + LDS stores
        f16x8 bh[4], bl[4];
        #pragma unroll
        for (int t = 0; t < 4; ++t) {
            bh[t] = *(const f16x8*)&Bh[wn + t * 16 + lm][lq * 8];
            bl[t] = *(const f16x8*)&Bl[wn + t * 16 + lm][lq * 8];
        }
        #pragma unroll
        for (int mt = 0; mt < 4; ++mt) {
            const f16x8 ah = *(const f16x8*)&Ah[wo + mt * 16 + lm][lq * 8];
            const f16x8 al = *(const f16x8*)&Al[wo + mt * 16 + lm][lq * 8];
            #pragma unroll
            for (int nt = 0; nt < 4; ++nt) {
                acc[mt][nt] = __builtin_amdgcn_mfma_f32_16x16x32_f16(ah, bh[nt], acc[mt][nt], 0, 0, 0);
                acc[mt][nt] = __builtin_amdgcn_mfma_f32_16x16x32_f16(ah, bl[nt], acc[mt][nt], 0, 0, 0);
                acc[mt][nt] = __builtin_amdgcn_mfma_f32_16x16x32_f16(al, bh[nt], acc[mt][nt], 0, 0, 0);
            }
        }
    }
    #pragma unroll
    for (int mt = 0; mt < 4; ++mt) {
        #pragma unroll
        for (int rg = 0; rg < 4; ++rg) {
            const int o = m0 + wo + mt * 16 + lq * 4 + rg;
            const float bs = bias[o];
            #pragma unroll
            for (int nt = 0; nt < 4; ++nt) {
                const int n = n0 + wn + nt * 16 + lm;
                float v = acc[mt][nt][rg] + bs;
                if (res) v += res[(size_t)o * Nr + n];
                if (relu) v = fmaxf(v, 0.f);
                out[(size_t)o * No + n] = v;
            }
        }
    }
}

// ---------------- GEMM 64x128 tile (GNN/det/final; fp32 weights) ----------
__global__ __launch_bounds__(256) void gemm64_kernel(
    const float* __restrict__ W0, const float* __restrict__ W1, int S0, int S1,
    const float* __restrict__ X0, const float* __restrict__ X1,
    const float* __restrict__ bias, const float* __restrict__ res,
    float* __restrict__ out,
    int O, int C, int C0, int N, int Nr, int No, int relu)
{
    __shared__ _Float16 Ah[64][APAD], Al[64][APAD];
    __shared__ _Float16 Bh[128][APAD], Bl[128][APAD];
    const int tid = threadIdx.x;
    const int n0 = blockIdx.x * 128, m0 = blockIdx.y * 64;
    const int wave = tid >> 6, lane = tid & 63;
    const int wo = (wave >> 1) * 32, wn = (wave & 1) * 64;
    const int lm = lane & 15, lq = lane >> 4;
    const int ar = tid >> 2, ak8 = (tid & 3) << 3;
    const int bkg = tid & 7, bng = tid >> 3;

    f32x4 acc[2][4] = {};

    for (int kb = 0; kb < C; kb += 32) {
        float4 av[2];
        const int kcol = kb + ak8;
        const float* wp = (kcol < C0) ? W0 + (size_t)(m0 + ar) * S0 + kcol
                                      : W1 + (size_t)(m0 + ar) * S1 + (kcol - C0);
        av[0] = *(const float4*)(wp);
        av[1] = *(const float4*)(wp + 4);
        float4 xv[4];
        #pragma unroll
        for (int r = 0; r < 4; ++r) {
            const int krow = kb + bkg * 4 + r;
            const float* xs = (krow < C0) ? X0 + (size_t)krow * N
                                          : X1 + (size_t)(krow - C0) * N;
            xv[r] = *(const float4*)(xs + n0 + bng * 4);
        }
        __syncthreads();
        {
            _Float16 hbuf[8], lbuf[8];
            #pragma unroll
            for (int q = 0; q < 2; ++q) {
                const float* f = (const float*)&av[q];
                #pragma unroll
                for (int c = 0; c < 4; ++c) {
                    const float x = f[c];
                    const _Float16 h = (_Float16)x;
                    hbuf[q * 4 + c] = h;
                    lbuf[q * 4 + c] = (_Float16)(x - (float)h);
                }
            }
            *(f16x8*)&Ah[ar][ak8] = *(const f16x8*)&hbuf[0];
            *(f16x8*)&Al[ar][ak8] = *(const f16x8*)&lbuf[0];
        }
        #pragma unroll
        for (int j = 0; j < 4; ++j) {
            _Float16 hb[4], lb[4];
            #pragma unroll
            for (int r = 0; r < 4; ++r) {
                const float x = ((const float*)&xv[r])[j];
                const _Float16 h = (_Float16)x;
                hb[r] = h;
                lb[r] = (_Float16)(x - (float)h);
            }
            *(f16x4*)&Bh[bng * 4 + j][bkg * 4] = *(const f16x4*)&hb[0];
            *(f16x4*)&Bl[bng * 4 + j][bkg * 4] = *(const f16x4*)&lb[0];
        }
        __syncthreads();
        f16x8 bh[4], bl[4];
        #pragma unroll
        for (int t = 0; t < 4; ++t) {
            bh[t] = *(const f16x8*)&Bh[wn + t * 16 + lm][lq * 8];
            bl[t] = *(const f16x8*)&Bl[wn + t * 16 + lm][lq * 8];
        }
        #pragma unroll
        for (int mt = 0; mt < 2; ++mt) {
            const f16x8 ah = *(const f16x8*)&Ah[wo + mt * 16 + lm][lq * 8];
            const f16x8 al = *(const f16x8*)&Al[wo + mt * 16 + lm][lq * 8];
            #pragma unroll
            for (int nt = 0; nt < 4; ++nt) {
                acc[mt][nt] = __builtin_amdgcn_mfma_f32_16x16x32_f16(ah, bh[nt], acc[mt][nt], 0, 0, 0);
                acc[mt][nt] = __builtin_amdgcn_mfma_f32_16x16x32_f16(ah, bl[nt], acc[mt][nt], 0, 0, 0);
                acc[mt][nt] = __builtin_amdgcn_mfma_f32_16x16x32_f16(al, bh[nt], acc[mt][nt], 0, 0, 0);
            }
        }
    }
    #pragma unroll
    for (int mt = 0; mt < 2; ++mt) {
        #pragma unroll
        for (int rg = 0; rg < 4; ++rg) {
            const int o = m0 + wo + mt * 16 + lq * 4 + rg;
            const float bs = bias[o];
            #pragma unroll
            for (int nt = 0; nt < 4; ++nt) {
                const int n = n0 + wn + nt * 16 + lm;
                float v = acc[mt][nt][rg] + bs;
                if (res) v += res[(size_t)o * Nr + n];
                if (relu) v = fmaxf(v, 0.f);
                out[(size_t)o * No + n] = v;
            }
        }
    }
}

// ---------------- weight split: fp32 -> fp16 hi/lo planes ------------------
__global__ void split_kernel(const float* __restrict__ src, _Float16* __restrict__ h,
                             _Float16* __restrict__ l, int n)
{
    const int i = blockIdx.x * 256 + threadIdx.x;
    if (i < n) {
        const float x = src[i];
        const _Float16 hh = (_Float16)x;
        h[i] = hh;
        l[i] = (_Float16)(x - (float)hh);
    }
}

// ---------------- batched Wf = m1wB @ mw, fp32 out (GNN) -------------------
__global__ __launch_bounds__(256) void fusew_kernel(
    const float* __restrict__ m1w_base, const float* __restrict__ mw_base,
    float* __restrict__ wf_base)
{
    const int z = blockIdx.z;
    const float* A = m1w_base + (size_t)z * 262144 + 256;
    const float* B = mw_base + (size_t)z * 65536;
    float* outp = wf_base + (size_t)z * 131072;
    __shared__ _Float16 Ah[64][APAD], Al[64][APAD];
    __shared__ _Float16 Bh[128][APAD], Bl[128][APAD];
    const int tid = threadIdx.x;
    const int n0 = blockIdx.x * 128, m0 = blockIdx.y * 64;
    const int wave = tid >> 6, lane = tid & 63;
    const int wo = (wave >> 1) * 32, wn = (wave & 1) * 64;
    const int lm = lane & 15, lq = lane >> 4;
    const int ar = tid >> 2, ak8 = (tid & 3) << 3;
    const int bkg = tid & 7, bng = tid >> 3;

    f32x4 acc[2][4] = {};
    for (int kb = 0; kb < 256; kb += 32) {
        float4 av[2];
        const float* wp = A + (size_t)(m0 + ar) * 512 + kb + ak8;
        av[0] = *(const float4*)(wp);
        av[1] = *(const float4*)(wp + 4);
        float4 xv[4];
        #pragma unroll
        for (int r = 0; r < 4; ++r)
            xv[r] = *(const float4*)(B + (size_t)(kb + bkg * 4 + r) * 256 + n0 + bng * 4);
        __syncthreads();
        {
            _Float16 hbuf[8], lbuf[8];
            #pragma unroll
            for (int q = 0; q < 2; ++q) {
                const float* f = (const float*)&av[q];
                #pragma unroll
                for (int c = 0; c < 4; ++c) {
                    const float x = f[c];
                    const _Float16 h = (_Float16)x;
                    hbuf[q * 4 + c] = h;
                    lbuf[q * 4 + c] = (_Float16)(x - (float)h);
                }
            }
            *(f16x8*)&Ah[ar][ak8] = *(const f16x8*)&hbuf[0];
            *(f16x8*)&Al[ar][ak8] = *(const f16x8*)&lbuf[0];
        }
        #pragma unroll
        for (int j = 0; j < 4; ++j) {
            _Float16 hb[4], lb[4];
            #pragma unroll
            for (int r = 0; r < 4; ++r) {
                const float x = ((const float*)&xv[r])[j];
                const _Float16 h = (_Float16)x;
                hb[r] = h;
                lb[r] = (_Float16)(x - (float)h);
            }
            *(f16x4*)&Bh[bng * 4 + j][bkg * 4] = *(const f16x4*)&hb[0];
            *(f16x4*)&Bl[bng * 4 + j][bkg * 4] = *(const f16x4*)&lb[0];
        }
        __syncthreads();
        f16x8 bh[4], bl[4];
        #pragma unroll
        for (int t = 0; t < 4; ++t) {
            bh[t] = *(const f16x8*)&Bh[wn + t * 16 + lm][lq * 8];
            bl[t] = *(const f16x8*)&Bl[wn + t * 16 + lm][lq * 8];
        }
        #pragma unroll
        for (int mt = 0; mt < 2; ++mt) {
            const f16x8 ah = *(const f16x8*)&Ah[wo + mt * 16 + lm][lq * 8];
            const f16x8 al = *(const f16x8*)&Al[wo + mt * 16 + lm][lq * 8];
            #pragma unroll
            for (int nt = 0; nt < 4; ++nt) {
                acc[mt][nt] = __builtin_amdgcn_mfma_f32_16x16x32_f16(ah, bh[nt], acc[mt][nt], 0, 0, 0);
                acc[mt][nt] = __builtin_amdgcn_mfma_f32_16x16x32_f16(ah, bl[nt], acc[mt][nt], 0, 0, 0);
                acc[mt][nt] = __builtin_amdgcn_mfma_f32_16x16x32_f16(al, bh[nt], acc[mt][nt], 0, 0, 0);
            }
        }
    }
    #pragma unroll
    for (int mt = 0; mt < 2; ++mt)
        #pragma unroll
        for (int rg = 0; rg < 4; ++rg) {
            const int o = m0 + wo + mt * 16 + lq * 4 + rg;
            #pragma unroll
            for (int nt = 0; nt < 4; ++nt)
                outp[(size_t)o * 256 + n0 + wn + nt * 16 + lm] = acc[mt][nt][rg];
        }
}

// ---------------- batched Wf = m1wB @ mw, fp16-plane out (fuser) -----------
__global__ __launch_bounds__(256) void fusewh_kernel(
    const float* __restrict__ m1w_base, const float* __restrict__ mw_base,
    _Float16* __restrict__ wfh_base, _Float16* __restrict__ wfl_base)
{
    const int z = blockIdx.z;
    const float* A = m1w_base + (size_t)z * 262144 + 256;
    const float* B = mw_base + (size_t)z * 65536;
    _Float16* oh = wfh_base + (size_t)z * 131072;
    _Float16* ol = wfl_base + (size_t)z * 131072;
    __shared__ _Float16 Ah[64][APAD], Al[64][APAD];
    __shared__ _Float16 Bh[128][APAD], Bl[128][APAD];
    const int tid = threadIdx.x;
    const int n0 = blockIdx.x * 128, m0 = blockIdx.y * 64;
    const int wave = tid >> 6, lane = tid & 63;
    const int wo = (wave >> 1) * 32, wn = (wave & 1) * 64;
    const int lm = lane & 15, lq = lane >> 4;
    const int ar = tid >> 2, ak8 = (tid & 3) << 3;
    const int bkg = tid & 7, bng = tid >> 3;

    f32x4 acc[2][4] = {};
    for (int kb = 0; kb < 256; kb += 32) {
        float4 av[2];
        const float* wp = A + (size_t)(m0 + ar) * 512 + kb + ak8;
        av[0] = *(const float4*)(wp);
        av[1] = *(const float4*)(wp + 4);
        float4 xv[4];
        #pragma unroll
        for (int r = 0; r < 4; ++r)
            xv[r] = *(const float4*)(B + (size_t)(kb + bkg * 4 + r) * 256 + n0 + bng * 4);
        __syncthreads();
        {
            _Float16 hbuf[8], lbuf[8];
            #pragma unroll
            for (int q = 0; q < 2; ++q) {
                const float* f = (const float*)&av[q];
                #pragma unroll
                for (int c = 0; c < 4; ++c) {
                    const float x = f[c];
                    const _Float16 h = (_Float16)x;
                    hbuf[q * 4 + c] = h;
                    lbuf[q * 4 + c] = (_Float16)(x - (float)h);
                }
            }
            *(f16x8*)&Ah[ar][ak8] = *(const f16x8*)&hbuf[0];
            *(f16x8*)&Al[ar][ak8] = *(const f16x8*)&lbuf[0];
        }
        #pragma unroll
        for (int j = 0; j < 4; ++j) {
            _Float16 hb[4], lb[4];
            #pragma unroll
            for (int r = 0; r < 4; ++r) {
                const float x = ((const float*)&xv[r])[j];
                const _Float16 h = (_Float16)x;
                hb[r] = h;
                lb[r] = (_Float16)(x - (float)h);
            }
            *(f16x4*)&Bh[bng * 4 + j][bkg * 4] = *(const f16x4*)&hb[0];
            *(f16x4*)&Bl[bng * 4 + j][bkg * 4] = *(const f16x4*)&lb[0];
        }
        __syncthreads();
        f16x8 bh[4], bl[4];
        #pragma unroll
        for (int t = 0; t < 4; ++t) {
            bh[t] = *(const f16x8*)&Bh[wn + t * 16 + lm][lq * 8];
            bl[t] = *(const f16x8*)&Bl[wn + t * 16 + lm][lq * 8];
        }
        #pragma unroll
        for (int mt = 0; mt < 2; ++mt) {
            const f16x8 ah = *(const f16x8*)&Ah[wo + mt * 16 + lm][lq * 8];
            const f16x8 al = *(const f16x8*)&Al[wo + mt * 16 + lm][lq * 8];
            #pragma unroll
            for (int nt = 0; nt < 4; ++nt) {
                acc[mt][nt] = __builtin_amdgcn_mfma_f32_16x16x32_f16(ah, bh[nt], acc[mt][nt], 0, 0, 0);
                acc[mt][nt] = __builtin_amdgcn_mfma_f32_16x16x32_f16(ah, bl[nt], acc[mt][nt], 0, 0, 0);
                acc[mt][nt] = __builtin_amdgcn_mfma_f32_16x16x32_f16(al, bh[nt], acc[mt][nt], 0, 0, 0);
            }
        }
    }
    #pragma unroll
    for (int mt = 0; mt < 2; ++mt)
        #pragma unroll
        for (int rg = 0; rg < 4; ++rg) {
            const int o = m0 + wo + mt * 16 + lq * 4 + rg;
            #pragma unroll
            for (int nt = 0; nt < 4; ++nt) {
                const float v = acc[mt][nt][rg];
                const _Float16 hh = (_Float16)v;
                oh[(size_t)o * 256 + n0 + wn + nt * 16 + lm] = hh;
                ol[(size_t)o * 256 + n0 + wn + nt * 16 + lm] = (_Float16)(v - (float)hh);
            }
        }
}

// ---------------- batched bc = m1wB @ mb + m1b -----------------------------
__global__ void fusebias_kernel(const float* __restrict__ m1w_base,
                                const float* __restrict__ mb_base,
                                const float* __restrict__ m1b_base,
                                float* __restrict__ bc_base)
{
    const int z = blockIdx.y;
    const int o = blockIdx.x * 256 + threadIdx.x;   // 0..511
    const float* A = m1w_base + (size_t)z * 262144 + (size_t)o * 512 + 256;
    const float* mb = mb_base + z * 256;
    float s = m1b_base[z * 512 + o];
    for (int c = 0; c < 256; ++c) s = fmaf(A[c], mb[c], s);
    bc_base[z * 512 + o] = s;
}

// ---------------- positional encoding (grid.y splits the 128 i's) ---------
__global__ void pe_kernel(const float* __restrict__ src, float* __restrict__ pe,
                          int N, int shift, int cstride)
{
    const int col = blockIdx.x * 256 + threadIdx.x;
    if (col >= N) return;
    const int seg = 1 << shift;
    const int i0 = blockIdx.y * 32;
    const float pos = src[(size_t)(col >> shift) * cstride + (col & (seg - 1))];
    #pragma unroll 4
    for (int i = i0; i < i0 + 32; ++i) {
        const float div = expf((float)i * -0.07195578415606394f); // -ln(10000)/128
        const float ang = pos * div;
        pe[(size_t)(2*i) * N + col]   = sinf(ang);
        pe[(size_t)(2*i+1) * N + col] = cosf(ang);
    }
}

// ---------------- input repack (drop channel 0) ---------------------------
__global__ void repack_kernel(const float* __restrict__ src, float* __restrict__ dst,
                              int N, int shift, int cstride)
{
    const int col = blockIdx.x * 256 + threadIdx.x;
    const int c = blockIdx.y;
    if (col >= N) return;
    const int seg = 1 << shift;
    dst[(size_t)c * N + col] =
        src[(size_t)(col >> shift) * cstride + (size_t)(c + 1) * seg + (col & (seg - 1))];
}

// ---------------- fuser self-attention over time (n=m=16 per track) -------
__global__ __launch_bounds__(256) void fuser_attn_kernel(
    const float* __restrict__ Qb, const float* __restrict__ Kb,
    const float* __restrict__ Vb, float* __restrict__ Ob)
{
    __shared__ float qs[256][17], ks[256][17], vs[256][17];
    __shared__ float ps[4][16][17];
    const int trk = blockIdx.x, tid = threadIdx.x;
    const int col0 = trk * 16;
    for (int idx = tid; idx < 1024; idx += 256) {
        const int r = idx >> 2, seg = (idx & 3) << 2;
        const float4 q = *(const float4*)&Qb[(size_t)r * NCT + col0 + seg];
        const float4 k = *(const float4*)&Kb[(size_t)r * NCT + col0 + seg];
        const float4 v = *(const float4*)&Vb[(size_t)r * NCT + col0 + seg];
        qs[r][seg]=q.x; qs[r][seg+1]=q.y; qs[r][seg+2]=q.z; qs[r][seg+3]=q.w;
        ks[r][seg]=k.x; ks[r][seg+1]=k.y; ks[r][seg+2]=k.z; ks[r][seg+3]=k.w;
        vs[r][seg]=v.x; vs[r][seg+1]=v.y; vs[r][seg+2]=v.z; vs[r][seg+3]=v.w;
    }
    __syncthreads();
    {
        const int g = tid >> 2, h = g >> 4, n = g & 15, mb = (tid & 3) << 2;
        float s[4] = {};
        #pragma unroll 4
        for (int hd = 0; hd < 64; ++hd) {
            const int c = hd*4 + h;
            const float q = qs[c][n];
            #pragma unroll
            for (int j = 0; j < 4; ++j) s[j] = fmaf(q, ks[c][mb + j], s[j]);
        }
        #pragma unroll
        for (int j = 0; j < 4; ++j) ps[h][n][mb + j] = s[j] * 0.125f;
    }
    __syncthreads();
    if (tid < 64) {
        const int hh = tid >> 4, nn = tid & 15;
        float mx = -INFINITY;
        for (int m = 0; m < 16; ++m) mx = fmaxf(mx, ps[hh][nn][m]);
        float sum = 0.f;
        for (int m = 0; m < 16; ++m) { const float p = expf(ps[hh][nn][m] - mx);
                                       ps[hh][nn][m] = p; sum += p; }
        const float inv = 1.f / sum;
        for (int m = 0; m < 16; ++m) ps[hh][nn][m] *= inv;
    }
    __syncthreads();
    {
        const int c = tid, hc = c & 3;
        float msg[16];
        #pragma unroll
        for (int n = 0; n < 16; ++n) {
            float a = 0.f;
            #pragma unroll
            for (int m = 0; m < 16; ++m) a = fmaf(ps[hc][n][m], vs[c][m], a);
            msg[n] = a;
        }
        __syncthreads();
        #pragma unroll
        for (int n = 0; n < 16; ++n) qs[c][n] = msg[n];
    }
    __syncthreads();
    for (int idx = tid; idx < 1024; idx += 256) {
        const int r = idx >> 2, seg = (idx & 3) << 2;
        *(float4*)&Ob[(size_t)r * NCT + col0 + seg] =
            make_float4(qs[r][seg], qs[r][seg+1], qs[r][seg+2], qs[r][seg+3]);
    }
}

// ---------------- GNN attention (merged tr+det): split-fp16 MFMA flash -----
__global__ __launch_bounds__(256) void attn2_kernel(
    const float* __restrict__ QKV, float* __restrict__ MSG, int cross)
{
    __shared__ _Float16 Qh[64][72], Ql[64][72];   // [qpos][d]
    __shared__ _Float16 Kh[64][72], Kl[64][72];   // [kpos][d]; P after QK
    __shared__ _Float16 Vh[64][72], Vl[64][72];   // [d][mpos]
    const int b = blockIdx.z, h = blockIdx.y, nt = blockIdx.x;
    const float* Qb = QKV;
    const float* Kb = QKV + (size_t)256 * NCB;
    const float* Vb = QKV + (size_t)512 * NCB;
    int qcol, kbase, nk;
    if (nt < 4) {
        qcol = b * 256 + nt * 64;
        if (cross) { kbase = 1024 + b * 1024; nk = 1024; }
        else       { kbase = b * 256;         nk = 256;  }
    } else {
        qcol = 1024 + b * 1024 + (nt - 4) * 64;
        if (cross) { kbase = b * 256;         nk = 256;  }
        else       { kbase = 1024 + b * 1024; nk = 1024; }
    }
    const int tid = threadIdx.x;
    const int wave = tid >> 6, lane = tid & 63;
    const int lm = lane & 15, quad = lane >> 4;
    const int dg = tid & 15, qg = tid >> 4;
    const int vd = tid >> 2, vseg = (tid & 3) * 16;

    {
        float4 xv[4];
        #pragma unroll
        for (int r = 0; r < 4; ++r) {
            const int chan = (dg * 4 + r) * 4 + h;
            xv[r] = *(const float4*)&Qb[(size_t)chan * NCB + qcol + qg * 4];
        }
        #pragma unroll
        for (int j = 0; j < 4; ++j) {
            _Float16 hb[4], lb[4];
            #pragma unroll
            for (int r = 0; r < 4; ++r) {
                const float x = ((const float*)&xv[r])[j];
                const _Float16 hh = (_Float16)x;
                hb[r] = hh; lb[r] = (_Float16)(x - (float)hh);
            }
            *(f16x4*)&Qh[qg * 4 + j][dg * 4] = *(const f16x4*)hb;
            *(f16x4*)&Ql[qg * 4 + j][dg * 4] = *(const f16x4*)lb;
        }
    }
    __syncthreads();
    f16x8 qh[2], ql[2];
    #pragma unroll
    for (int ks = 0; ks < 2; ++ks) {
        qh[ks] = *(const f16x8*)&Qh[wave * 16 + lm][ks * 32 + quad * 8];
        ql[ks] = *(const f16x8*)&Ql[wave * 16 + lm][ks * 32 + quad * 8];
    }

    float rmax[4], rsum[4];
    #pragma unroll
    for (int r = 0; r < 4; ++r) { rmax[r] = -INFINITY; rsum[r] = 0.f; }
    f32x4 acco[4] = {};

    const int mtiles = nk >> 6;
    for (int mt = 0; mt < mtiles; ++mt) {
        const int kcol = kbase + mt * 64;
        __syncthreads();
        {
            float4 xv[4];
            #pragma unroll
            for (int r = 0; r < 4; ++r) {
                const int chan = (dg * 4 + r) * 4 + h;
                xv[r] = *(const float4*)&Kb[(size_t)chan * NCB + kcol + qg * 4];
            }
            #pragma unroll
            for (int j = 0; j < 4; ++j) {
                _Float16 hb[4], lb[4];
                #pragma unroll
                for (int r = 0; r < 4; ++r) {
                    const float x = ((const float*)&xv[r])[j];
                    const _Float16 hh = (_Float16)x;
                    hb[r] = hh; lb[r] = (_Float16)(x - (float)hh);
                }
                *(f16x4*)&Kh[qg * 4 + j][dg * 4] = *(const f16x4*)hb;
                *(f16x4*)&Kl[qg * 4 + j][dg * 4] = *(const f16x4*)lb;
            }
            const int vchan = vd * 4 + h;
            float4 v4[4];
            #pragma unroll
            for (int q = 0; q < 4; ++q)
                v4[q] = *(const float4*)&Vb[(size_t)vchan * NCB + kcol + vseg + q * 4];
            _Float16 vh16[16], vl16[16];
            #pragma unroll
            for (int q = 0; q < 4; ++q) {
                const float* f = (const float*)&v4[q];
                #pragma unroll
                for (int c = 0; c < 4; ++c) {
                    const float x = f[c];
                    const _Float16 hh = (_Float16)x;
                    vh16[q*4+c] = hh; vl16[q*4+c] = (_Float16)(x - (float)hh);
                }
            }
            *(f16x8*)&Vh[vd][vseg]     = *(const f16x8*)&vh16[0];
            *(f16x8*)&Vh[vd][vseg + 8] = *(const f16x8*)&vh16[8];
            *(f16x8*)&Vl[vd][vseg]     = *(const f16x8*)&vl16[0];
            *(f16x8*)&Vl[vd][vseg + 8] = *(const f16x8*)&vl16[8];
        }
        __syncthreads();
        f32x4 accs[4] = {};
        #pragma unroll
        for (int t = 0; t < 4; ++t) {
            #pragma unroll
            for (int ks = 0; ks < 2; ++ks) {
                const f16x8 kh = *(const f16x8*)&Kh[t * 16 + lm][ks * 32 + quad * 8];
                const f16x8 kl = *(const f16x8*)&Kl[t * 16 + lm][ks * 32 + quad * 8];
                accs[t] = __builtin_amdgcn_mfma_f32_16x16x32_f16(qh[ks], kh, accs[t], 0,0,0);
                accs[t] = __builtin_amdgcn_mfma_f32_16x16x32_f16(qh[ks], kl, accs[t], 0,0,0);
                accs[t] = __builtin_amdgcn_mfma_f32_16x16x32_f16(ql[ks], kh, accs[t], 0,0,0);
            }
        }
        float alpha[4];
        float psv[4][4];
        #pragma unroll
        for (int r = 0; r < 4; ++r) {
            float mx = fmaxf(fmaxf(accs[0][r], accs[1][r]),
                             fmaxf(accs[2][r], accs[3][r])) * 0.125f;
            #pragma unroll
            for (int off = 1; off < 16; off <<= 1) mx = fmaxf(mx, __shfl_xor(mx, off));
            const float mnew = fmaxf(rmax[r], mx);
            alpha[r] = expf(rmax[r] - mnew);
            rmax[r] = mnew;
            float s = 0.f;
            #pragma unroll
            for (int t = 0; t < 4; ++t) {
                const float p = expf(accs[t][r] * 0.125f - mnew);
                psv[t][r] = p; s += p;
            }
            #pragma unroll
            for (int off = 1; off < 16; off <<= 1) s += __shfl_xor(s, off);
            rsum[r] = rsum[r] * alpha[r] + s;
        }
        __syncthreads();
        #pragma unroll
        for (int t = 0; t < 4; ++t)
            #pragma unroll
            for (int r = 0; r < 4; ++r) {
                const float x = psv[t][r];
                const _Float16 hh = (_Float16)x;
                Kh[wave * 16 + quad * 4 + r][t * 16 + lm] = hh;
                Kl[wave * 16 + quad * 4 + r][t * 16 + lm] = (_Float16)(x - (float)hh);
            }
        __syncthreads();
        #pragma unroll
        for (int td = 0; td < 4; ++td)
            #pragma unroll
            for (int r = 0; r < 4; ++r) acco[td][r] *= alpha[r];
        #pragma unroll
        for (int ks = 0; ks < 2; ++ks) {
            const f16x8 ph = *(const f16x8*)&Kh[wave * 16 + lm][ks * 32 + quad * 8];
            const f16x8 pl = *(const f16x8*)&Kl[wave * 16 + lm][ks * 32 + quad * 8];
            #pragma unroll
            for (int td = 0; td < 4; ++td) {
                const f16x8 vh = *(const f16x8*)&Vh[td * 16 + lm][ks * 32 + quad * 8];
                const f16x8 vl = *(const f16x8*)&Vl[td * 16 + lm][ks * 32 + quad * 8];
                acco[td] = __builtin_amdgcn_mfma_f32_16x16x32_f16(ph, vh, acco[td], 0,0,0);
                acco[td] = __builtin_amdgcn_mfma_f32_16x16x32_f16(ph, vl, acco[td], 0,0,0);
                acco[td] = __builtin_amdgcn_mfma_f32_16x16x32_f16(pl, vh, acco[td], 0,0,0);
            }
        }
    }
    float inv[4];
    #pragma unroll
    for (int r = 0; r < 4; ++r) inv[r] = 1.f / rsum[r];
    #pragma unroll
    for (int td = 0; td < 4; ++td)
        #pragma unroll
        for (int r = 0; r < 4; ++r) {
            const int chan = (td * 16 + lm) * 4 + h;
            const int qp = qcol + wave * 16 + quad * 4 + r;
            MSG[(size_t)chan * NCB + qp] = acco[td][r] * inv[r];
        }
}

// ---------------- mean pool over time (into combined cols [0,1024)) -------
__global__ void meanpool_kernel(const float* __restrict__ x, float* __restrict__ tr)
{
    const int trk = blockIdx.x * 256 + threadIdx.x;
    const int d = blockIdx.y;
    const float* p = x + (size_t)d * NCT + (size_t)trk * 16;
    float s = 0.f;
    #pragma unroll
    for (int t = 0; t < 16; ++t) s += p[t];
    tr[(size_t)d * NCB + trk] = s * 0.0625f;
}

// ---------------- scores = m0^T m1 / 16 into Z0 and Z0T -------------------
__global__ __launch_bounds__(256) void scores_kernel(
    const float* __restrict__ M, float* __restrict__ Z0, float* __restrict__ Z0T)
{
    __shared__ float As[8][68];
    __shared__ float Bs[8][68];
    const int bm = blockIdx.x, bn = blockIdx.y, b = blockIdx.z;
    const int tid = threadIdx.x;
    const int n0 = bn * 64, mm0 = bm * 64;
    const int tx = tid & 15, ty = tid >> 4;
    float acc[4][4] = {};
    for (int kb = 0; kb < 256; kb += 8) {
        __syncthreads();
        for (int idx = tid; idx < 512; idx += 256) {
            const int r = idx >> 6, cc = idx & 63;
            As[r][cc] = M[(size_t)(kb + r) * NCB + b * 256 + n0 + cc];
            Bs[r][cc] = M[(size_t)(kb + r) * NCB + 1024 + b * 1024 + mm0 + cc];
        }
        __syncthreads();
        #pragma unroll
        for (int kk = 0; kk < 8; ++kk) {
            float a[4], bv[4];
            #pragma unroll
            for (int i = 0; i < 4; ++i) { a[i] = As[kk][ty*4 + i]; bv[i] = Bs[kk][tx*4 + i]; }
            #pragma unroll
            for (int i = 0; i < 4; ++i)
                #pragma unroll
                for (int j = 0; j < 4; ++j) acc[i][j] = fmaf(a[i], bv[j], acc[i][j]);
        }
    }
    #pragma unroll
    for (int i = 0; i < 4; ++i)
        #pragma unroll
        for (int j = 0; j < 4; ++j) {
            const float s = acc[i][j] * 0.0625f;
            const int rr = n0 + ty*4 + i, cc = mm0 + tx*4 + j;
            Z0 [(size_t)b * ZBAT + (size_t)rr * ZCOL + cc] = s;
            Z0T[(size_t)b * ZBAT + (size_t)cc * ZROW + rr] = s;
        }
}

// ---------------- sinkhorn ------------------------------------------------
__global__ void sink_init_kernel(float* __restrict__ Z0, float* __restrict__ Z0T,
                                 float* __restrict__ v, const float* __restrict__ binp)
{
    const float alpha = binp[0];
    const int idx = blockIdx.x * 256 + threadIdx.x;
    if (idx < 4 * ZCOL) v[idx] = 0.f;
    if (idx < 4 * 1281) {
        const int b = idx / 1281, e = idx % 1281;
        if (e < 1025) Z0[(size_t)b * ZBAT + 256 * ZCOL + e] = alpha;
        else          Z0[(size_t)b * ZBAT + (size_t)(e - 1025) * ZCOL + 1024] = alpha;
    }
    if (idx < 4 * 1282) {
        const int b = idx / 1282, e = idx % 1282;
        if (e < 257) Z0T[(size_t)b * ZBAT + 1024 * ZROW + e] = alpha;
        else         Z0T[(size_t)b * ZBAT + (size_t)(e - 257) * ZROW + 256] = alpha;
    }
}

__global__ __launch_bounds__(256) void sink_u_kernel(
    const float* __restrict__ Z0, const float* __restrict__ v, float* __restrict__ u)
{
    const int w = threadIdx.x >> 6, lane = threadIdx.x & 63;
    const int row = blockIdx.x * 4 + w;          // 0..1027
    const int b = row / 257, i = row % 257;
    const float* z  = Z0 + (size_t)b * ZBAT + (size_t)i * ZCOL;
    const float* vb = v + b * ZCOL;
    float zz[17];
    float mx = -INFINITY;
    #pragma unroll
    for (int k = 0; k < 16; ++k) {
        zz[k] = z[lane + k*64] + vb[lane + k*64];
        mx = fmaxf(mx, zz[k]);
    }
    zz[16] = (lane == 0) ? (z[1024] + vb[1024]) : -INFINITY;
    mx = fmaxf(mx, zz[16]);
    #pragma unroll
    for (int off = 32; off; off >>= 1) mx = fmaxf(mx, __shfl_xor(mx, off));
    float s = 0.f;
    #pragma unroll
    for (int k = 0; k < 17; ++k) s += expf(zz[k] - mx);
    #pragma unroll
    for (int off = 32; off; off >>= 1) s += __shfl_xor(s, off);
    if (lane == 0) {
        const float lmu = (i < 256) ? NORM_C : (LOG_NS + NORM_C);
        u[b * 257 + i] = lmu - (mx + logf(s));
    }
}

__global__ __launch_bounds__(256) void sink_v_kernel(
    const float* __restrict__ Z0T, const float* __restrict__ u, float* __restrict__ v)
{
    const int w = threadIdx.x >> 6, lane = threadIdx.x & 63;
    const int row = blockIdx.x * 4 + w;          // 0..4099
    const int b = row / 1025, j = row - b * 1025;
    const float* z  = Z0T + (size_t)b * ZBAT + (size_t)j * ZROW;
    const float* ub = u + b * 257;
    float zz[5];
    float mx = -INFINITY;
    #pragma unroll
    for (int k = 0; k < 4; ++k) {
        zz[k] = z[lane + k*64] + ub[lane + k*64];
        mx = fmaxf(mx, zz[k]);
    }
    zz[4] = (lane == 0) ? (z[256] + ub[256]) : -INFINITY;
    mx = fmaxf(mx, zz[4]);
    #pragma unroll
    for (int off = 32; off; off >>= 1) mx = fmaxf(mx, __shfl_xor(mx, off));
    float s = 0.f;
    #pragma unroll
    for (int k = 0; k < 5; ++k) s += expf(zz[k] - mx);
    #pragma unroll
    for (int off = 32; off; off >>= 1) s += __shfl_xor(s, off);
    if (lane == 0) {
        const float lnu = (j < 1024) ? NORM_C : (LOG_MS + NORM_C);
        v[b * ZCOL + j] = lnu - (mx + logf(s));
    }
}

__global__ void sink_out_kernel(const float* __restrict__ Z0, const float* __restrict__ u,
                                const float* __restrict__ v, float* __restrict__ out)
{
    const int j = blockIdx.x * 256 + threadIdx.x;
    const int i = blockIdx.y, b = blockIdx.z;
    if (j < ZCOL) {
        const size_t idx = (size_t)b * ZBAT + (size_t)i * ZCOL + j;
        out[idx] = Z0[idx] + u[b * 257 + i] + v[b * ZCOL + j] + LOG_TOT;
    }
}

// ---------------------------------------------------------------------------
static inline void gemmP(hipStream_t st,
                         const _Float16* Ph0, const _Float16* Pl0, int S0,
                         const _Float16* Ph1, const _Float16* Pl1, int S1,
                         const float* X0, const float* X1, int C0,
                         const float* bias, const float* res, int Nr,
                         float* out, int No, int O, int C, int N, int relu)
{
    dim3 g(N / 128, O / 128);
    gemm_kernel<<<g, 256, 0, st>>>(Ph0, Pl0, S0, Ph1, Pl1, S1, X0, X1,
                                   bias, res, out, O, C, C0, N, Nr, No, relu);
}

static inline void gemm64(hipStream_t st, const float* W, const float* X0,
                          const float* X1, int C0, const float* bias,
                          const float* res, int Nr, float* out, int No,
                          int O, int C, int N, int relu,
                          const float* W1 = nullptr, int S1 = 0)
{
    if (!W1) { W1 = W + C0; S1 = C; }
    dim3 g(N / 128, O / 64);
    gemm64_kernel<<<g, 256, 0, st>>>(W, W1, C, S1, X0, X1, bias, res, out, O, C, C0, N, Nr, No, relu);
}

extern "C" void kernel_launch(void* const* d_in, const int* in_sizes, int n_in,
                              void* d_out, int out_size, void* d_ws, size_t ws_size,
                              hipStream_t stream)
{
    (void)in_sizes; (void)n_in; (void)out_size; (void)ws_size;
    const float* det_in = (const float*)d_in[0];
    const float* trk_in = (const float*)d_in[1];
    const float* enc_w1 = (const float*)d_in[2];
    const float* enc_b1 = (const float*)d_in[3];
    const float* enc_w2 = (const float*)d_in[4];
    const float* enc_b2 = (const float*)d_in[5];
    const float* fus_pw = (const float*)d_in[6];
    const float* fus_pb = (const float*)d_in[7];
    const float* fus_mw = (const float*)d_in[8];
    const float* fus_mb = (const float*)d_in[9];
    const float* fus_m1w = (const float*)d_in[10];
    const float* fus_m1b = (const float*)d_in[11];
    const float* fus_m2w = (const float*)d_in[12];
    const float* fus_m2b = (const float*)d_in[13];
    const float* gnn_pw = (const float*)d_in[14];
    const float* gnn_pb = (const float*)d_in[15];
    const float* gnn_mw = (const float*)d_in[16];
    const float* gnn_mb = (const float*)d_in[17];
    const float* gnn_m1w = (const float*)d_in[18];
    const float* gnn_m1b = (const float*)d_in[19];
    const float* gnn_m2w = (const float*)d_in[20];
    const float* gnn_m2b = (const float*)d_in[21];
    const float* final_w = (const float*)d_in[22];
    const float* final_b = (const float*)d_in[23];
    const float* bin_sc  = (const float*)d_in[24];
    float* out = (float*)d_out;

    float* ws = (float*)d_ws;
    float* XF   = ws;                      // 4,194,304  fuser state x [256][16384]
    float* R    = ws + 4194304;            // 16,777,216 temp arena
    float* COMB = ws + 20971520;           // 1,310,720  [256][5120] tr|det state
    float* Z0   = ws + 22282240;           // 1,053,700
    float* U    = ws + 23335940;           //     1,028
    float* V    = ws + 23336968;           //     4,100
    // fuser / det-enc arena:
    float* Qf = R;
    float* Kf = R + 4194304;
    float* Vf = R + 8388608;
    float* MS = R + 12582912;
    // GNN arena (N=5120):
    float* QKV = R;                       // [768][5120]
    float* H   = R + 1310720;             // [512][5120]
    float* MSG = R + 3932160;             // [256][5120]
    float* M   = R + 5242880;             // [256][5120]
    // fused msg-proj weights:
    //   fuser: fp16 planes in COMB region (dead until meanpool)
    _Float16* Whff = (_Float16*)COMB;             // [4][512][256] halves
    _Float16* Wlff = (_Float16*)(COMB + 262144);  // [4][512][256] halves
    float* bcf = COMB + 524288;                   // [4][512]
    //   GNN: fp32 in old-Vf region (free after fuser; untouched later)
    float* Wfg = R + 8388608;             // [12][512][256]
    float* bcg = R + 10000000;            // [12][512]
    float* Z0T = R;                       // sinkhorn transpose (end phase)
    // fp16 hi/lo weight-plane arena (fuser path), in HALVES from base:
    _Float16* PB = (_Float16*)(ws + 23400000);
    _Float16* e1h = PB;              _Float16* e1l = PB + 65536;
    _Float16* e2h = PB + 131072;     _Float16* e2l = PB + 196608;
    _Float16* pwh = PB + 262144;     _Float16* pwl = PB + 1048576;   // 4x196608
    _Float16* m1h = PB + 1835008;    _Float16* m1l = PB + 2883584;   // 4x262144 (full 512-wide)
    _Float16* m2h = PB + 3932160;    _Float16* m2l = PB + 4456448;   // 4x131072

    // ===== weight-plane precompute (independent; before everything) =======
    split_kernel<<<256, 256, 0, stream>>>(enc_w1, e1h, e1l, 65536);
    split_kernel<<<256, 256, 0, stream>>>(enc_w2, e2h, e2l, 65536);
    split_kernel<<<3072, 256, 0, stream>>>(fus_pw, pwh, pwl, 786432);
    split_kernel<<<4096, 256, 0, stream>>>(fus_m1w, m1h, m1l, 1048576);
    split_kernel<<<2048, 256, 0, stream>>>(fus_m2w, m2h, m2l, 524288);
    fusewh_kernel<<<dim3(2, 8, 4), 256, 0, stream>>>(fus_m1w, fus_mw, Whff, Wlff);
    fusebias_kernel<<<dim3(2, 4), 256, 0, stream>>>(fus_m1w, fus_mb, fus_m1b, bcf);

    // ================= encoder (tracks) + fuser ===========================
    pe_kernel<<<dim3(NCT/256, 4), 256, 0, stream>>>(trk_in, MS, NCT, 4, 257*16);
    repack_kernel<<<dim3(NCT/256, 256), 256, 0, stream>>>(trk_in, Qf, NCT, 4, 257*16);
    gemmP(stream, e1h, e1l, 256, e1h, e1l, 256, Qf, Qf, 256,
          enc_b1, nullptr, 0, Kf, NCT, 256, 256, NCT, 1);
    gemmP(stream, e2h, e2l, 256, e2h, e2l, 256, Kf, Kf, 256,
          enc_b2, MS, NCT, XF, NCT, 256, 256, NCT, 0);

    for (int l = 0; l < 4; ++l) {
        gemmP(stream, pwh + l*196608, pwl + l*196608, 256,
              pwh, pwl, 256, XF, XF, 256,
              fus_pb + l*768, nullptr, 0, Qf, NCT, 768, 256, NCT, 0);
        fuser_attn_kernel<<<1024, 256, 0, stream>>>(Qf, Kf, Vf, MS);
        // h = relu([m1wA | Wf] @ [x; attn_msg] + bc)  -> Kf..Vf
        gemmP(stream, m1h + l*262144, m1l + l*262144, 512,
              Whff + l*131072, Wlff + l*131072, 256, XF, MS, 256,
              bcf + l*512, nullptr, 0, Kf, NCT, 512, 512, NCT, 1);
        gemmP(stream, m2h + l*131072, m2l + l*131072, 512,
              m2h, m2l, 512, Kf, Kf, 512,
              fus_m2b + l*256, XF, NCT, XF, NCT, 256, 512, NCT, 0);
    }

    // ===== GNN fused-weight precompute (old-Vf region now free) ===========
    fusew_kernel<<<dim3(2, 8, 12), 256, 0, stream>>>(gnn_m1w, gnn_mw, Wfg);
    fusebias_kernel<<<dim3(2, 12), 256, 0, stream>>>(gnn_m1w, gnn_mb, gnn_m1b, bcg);

    meanpool_kernel<<<dim3(4, 256), 256, 0, stream>>>(XF, COMB);   // tr cols [0,1024)

    // ================= encoder (detections) -> COMB cols [1024,5120) ======
    pe_kernel<<<dim3(NCD/256, 4), 256, 0, stream>>>(det_in, MS, NCD, 10, 257*1024);
    repack_kernel<<<dim3(NCD/256, 256), 256, 0, stream>>>(det_in, Qf, NCD, 10, 257*1024);
    gemm64(stream, enc_w1, Qf, Qf, 256, enc_b1, nullptr, 0, Kf, NCD, 256, 256, NCD, 1);
    gemm64(stream, enc_w2, Kf, Kf, 256, enc_b2, MS, NCD, COMB + 1024, NCB, 256, 256, NCD, 0);

    // ================= GNN (combined tr|det, N=5120) ======================
    for (int l = 0; l < 12; ++l) {
        const float* pw  = gnn_pw + l*196608;
        const float* pb  = gnn_pb + l*768;
        const float* m1w = gnn_m1w + l*262144;
        const float* m2w = gnn_m2w + l*131072;
        const float* m2b = gnn_m2b + l*256;
        const int cross = (l & 1);

        gemm64(stream, pw, COMB, COMB, 256, pb, nullptr, 0, QKV, NCB, 768, 256, NCB, 0);
        attn2_kernel<<<dim3(20, 4, 4), 256, 0, stream>>>(QKV, MSG, cross);
        gemm64(stream, m1w, COMB, MSG, 256, bcg + l*512,
               nullptr, 0, H, NCB, 512, 512, NCB, 1, Wfg + l*131072, 256);
        gemm64(stream, m2w, H, H, 512, m2b, COMB, NCB, COMB, NCB, 256, 512, NCB, 0);
    }

    // ================= final projection + scores + sinkhorn ===============
    gemm64(stream, final_w, COMB, COMB, 256, final_b, nullptr, 0, M, NCB, 256, 256, NCB, 0);
    scores_kernel<<<dim3(16, 4, 4), 256, 0, stream>>>(M, Z0, Z0T);
    sink_init_kernel<<<21, 256, 0, stream>>>(Z0, Z0T, V, bin_sc);
    for (int it = 0; it < 100; ++it) {
        sink_u_kernel<<<257, 256, 0, stream>>>(Z0, V, U);
        sink_v_kernel<<<1025, 256, 0, stream>>>(Z0T, U, V);
    }
    sink_out_kernel<<<dim3(5, 257, 4), 256, 0, stream>>>(Z0, U, V, out);
}